// Round 1
// baseline (4653.422 us; speedup 1.0000x reference)
//
#include <hip/hip_runtime.h>

// DGCNN forward: knn(3d) -> EdgeConv(6->64->64->64,BN) -> knn(64d) ->
// EdgeConv(128->128,BN) -> Lin(192->1024)+BN+maxpool -> head MLP -> [32,2]
// All BN stats are global (training mode) => per-layer kernels with
// deterministic double-precision two-stage reductions; BN folded into
// per-channel affine applied on load by the consumer kernel.

#define NB 32
#define NP 1024
#define NPT 32768       // NB*NP
#define KNN 5
#define NE 163840       // NPT*KNN

#define FINF 3.402823466e+38f

__device__ __forceinline__ bool lex_less(float da, int ja, float db, int jb) {
  return (da < db) || (da == db && ja < jb);
}

__device__ __forceinline__ float f4c(const float4& v, int q) {
  return q == 0 ? v.x : (q == 1 ? v.y : (q == 2 ? v.z : v.w));
}

// ---------------------------------------------------------------- knn (3-d)
__global__ __launch_bounds__(256) void knn1_kernel(const float* __restrict__ pos,
                                                   int* __restrict__ knn_idx) {
  __shared__ float xs[NP * 3];
  __shared__ float sq[NP];
  const int b = blockIdx.x >> 2;
  const int qtr = blockIdx.x & 3;
  const int t = threadIdx.x;
  for (int i = t; i < NP * 3; i += 256) xs[i] = pos[(size_t)b * NP * 3 + i];
  __syncthreads();
  for (int i = t; i < NP; i += 256) {
    float x0 = xs[i*3+0], x1 = xs[i*3+1], x2 = xs[i*3+2];
    sq[i] = __fadd_rn(__fadd_rn(__fmul_rn(x0,x0), __fmul_rn(x1,x1)), __fmul_rn(x2,x2));
  }
  __syncthreads();
  const int i = qtr * 256 + t;
  const float xi0 = xs[i*3+0], xi1 = xs[i*3+1], xi2 = xs[i*3+2];
  const float sqi = sq[i];
  float d0=FINF,d1=FINF,d2=FINF,d3=FINF,d4=FINF;
  int j0=0x7fffffff,j1=0x7fffffff,j2=0x7fffffff,j3=0x7fffffff,j4=0x7fffffff;
  for (int j = 0; j < NP; ++j) {
    float y0 = xs[j*3+0], y1 = xs[j*3+1], y2 = xs[j*3+2];
    float dot = __fadd_rn(__fadd_rn(__fmul_rn(xi0,y0), __fmul_rn(xi1,y1)), __fmul_rn(xi2,y2));
    float dd = __fsub_rn(__fadd_rn(sqi, sq[j]), __fmul_rn(2.0f, dot));
    if (lex_less(dd, j, d4, j4)) {
      bool L0 = lex_less(dd,j,d0,j0), L1 = lex_less(dd,j,d1,j1),
           L2 = lex_less(dd,j,d2,j2), L3 = lex_less(dd,j,d3,j3);
      d4 = L3 ? d3 : dd;              j4 = L3 ? j3 : j;
      d3 = L3 ? (L2 ? d2 : dd) : d3;  j3 = L3 ? (L2 ? j2 : j) : j3;
      d2 = L2 ? (L1 ? d1 : dd) : d2;  j2 = L2 ? (L1 ? j1 : j) : j2;
      d1 = L1 ? (L0 ? d0 : dd) : d1;  j1 = L1 ? (L0 ? j0 : j) : j1;
      d0 = L0 ? dd : d0;              j0 = L0 ? j : j0;
    }
  }
  const size_t row = (size_t)b * NP + i;
  knn_idx[row*KNN+0] = b*NP + j0;
  knn_idx[row*KNN+1] = b*NP + j1;
  knn_idx[row*KNN+2] = b*NP + j2;
  knn_idx[row*KNN+3] = b*NP + j3;
  knn_idx[row*KNN+4] = b*NP + j4;
}

// ------------------------------------------- EdgeConv1 layer1 (6 -> 64) + stats
__global__ __launch_bounds__(256) void ec1_l1_kernel(const float* __restrict__ pos,
    const int* __restrict__ knn_idx, const float* __restrict__ W,
    const float* __restrict__ bias, float* __restrict__ hout,
    double* __restrict__ psum, double* __restrict__ psq) {
  __shared__ float ef[64][6];
  __shared__ float Wl[6][64];
  __shared__ float bl[64];
  __shared__ double red[256];
  const int blk = blockIdx.x, t = threadIdx.x;
  const int ebase = blk * 64;
  if (t < 64) {
    int e = ebase + t;
    int ip = e / KNN;
    int jp = knn_idx[e];
    float a0 = pos[(size_t)ip*3+0], a1 = pos[(size_t)ip*3+1], a2 = pos[(size_t)ip*3+2];
    float c0 = pos[(size_t)jp*3+0], c1 = pos[(size_t)jp*3+1], c2 = pos[(size_t)jp*3+2];
    ef[t][0] = a0; ef[t][1] = a1; ef[t][2] = a2;
    ef[t][3] = c0 - a0; ef[t][4] = c1 - a1; ef[t][5] = c2 - a2;
    bl[t] = bias[t];
  }
  for (int idx = t; idx < 6*64; idx += 256) Wl[idx>>6][idx&63] = W[idx];
  __syncthreads();
  const int c = t & 63, rs = t >> 6;
  double s = 0.0, ss = 0.0;
  for (int r = rs; r < 64; r += 4) {
    float acc = bl[c];
    #pragma unroll
    for (int q = 0; q < 6; ++q) acc = fmaf(ef[r][q], Wl[q][c], acc);
    acc = fmaxf(acc, 0.0f);
    hout[(size_t)(ebase + r)*64 + c] = acc;
    s += acc; ss += (double)acc * (double)acc;
  }
  red[t] = s; __syncthreads();
  if (t < 64) psum[(size_t)blk*64 + t] = red[t] + red[t+64] + red[t+128] + red[t+192];
  __syncthreads();
  red[t] = ss; __syncthreads();
  if (t < 64) psq[(size_t)blk*64 + t] = red[t] + red[t+64] + red[t+128] + red[t+192];
}

// ---------------------------------------------- BN stats -> per-channel affine
__global__ void stats_reduce_kernel(const double* __restrict__ psum,
    const double* __restrict__ psq, int nblk, int C, double invN,
    const float* __restrict__ g, const float* __restrict__ be,
    float2* __restrict__ aff) {
  int c = blockIdx.x * 256 + threadIdx.x;
  if (c >= C) return;
  double s = 0.0, ss = 0.0;
  for (int i = 0; i < nblk; ++i) { s += psum[(size_t)i*C + c]; ss += psq[(size_t)i*C + c]; }
  double mean = s * invN;
  double var = ss * invN - mean*mean;
  var = var < 0.0 ? 0.0 : var;
  double inv = 1.0 / sqrt(var + 1e-5);
  float a = (float)((double)g[c] * inv);
  float off = (float)((double)be[c] - (double)g[c] * mean * inv);
  aff[c] = make_float2(a, off);
}

// -------------------------------- EdgeConv1 layers 2/3 (64 -> 64) + stats
__global__ __launch_bounds__(256) void ec_l64_kernel(const float* __restrict__ hin,
    const float2* __restrict__ affprev, const float* __restrict__ W,
    const float* __restrict__ bias, float* __restrict__ hout,
    double* __restrict__ psum, double* __restrict__ psq) {
  __shared__ float ein[64][68];
  __shared__ float Wl[64][64];
  __shared__ float2 affl[64];
  __shared__ float bl[64];
  __shared__ double redS[16][64];
  __shared__ double redQ[16][64];
  const int blk = blockIdx.x, t = threadIdx.x;
  const size_t ebase = (size_t)blk * 64;
  if (t < 64) { affl[t] = affprev[t]; bl[t] = bias[t]; }
  __syncthreads();
  for (int idx = t; idx < 64*64; idx += 256) {
    int r = idx >> 6, c = idx & 63;
    float2 ac = affl[c];
    ein[r][c] = fmaf(hin[ebase*64 + idx], ac.x, ac.y);
    Wl[r][c] = W[idx];
  }
  __syncthreads();
  const int c4 = t & 15, rs = t >> 4;
  const int cbase = c4 * 4;
  const int rbase = rs * 4;
  float acc[4][4];
  #pragma unroll
  for (int ii = 0; ii < 4; ++ii) {
    #pragma unroll
    for (int jj = 0; jj < 4; ++jj) acc[ii][jj] = bl[cbase + jj];
  }
  for (int cin = 0; cin < 64; cin += 4) {
    float4 fi[4];
    #pragma unroll
    for (int ii = 0; ii < 4; ++ii) fi[ii] = *(const float4*)&ein[rbase+ii][cin];
    #pragma unroll
    for (int q = 0; q < 4; ++q) {
      float4 wv = *(const float4*)&Wl[cin+q][cbase];
      #pragma unroll
      for (int ii = 0; ii < 4; ++ii) {
        float f = f4c(fi[ii], q);
        acc[ii][0] = fmaf(f, wv.x, acc[ii][0]);
        acc[ii][1] = fmaf(f, wv.y, acc[ii][1]);
        acc[ii][2] = fmaf(f, wv.z, acc[ii][2]);
        acc[ii][3] = fmaf(f, wv.w, acc[ii][3]);
      }
    }
  }
  double s[4] = {0,0,0,0}, ss[4] = {0,0,0,0};
  #pragma unroll
  for (int ii = 0; ii < 4; ++ii) {
    float4 h;
    h.x = fmaxf(acc[ii][0], 0.f); h.y = fmaxf(acc[ii][1], 0.f);
    h.z = fmaxf(acc[ii][2], 0.f); h.w = fmaxf(acc[ii][3], 0.f);
    *(float4*)&hout[(ebase + rbase + ii)*64 + cbase] = h;
    s[0]+=h.x; s[1]+=h.y; s[2]+=h.z; s[3]+=h.w;
    ss[0]+=(double)h.x*h.x; ss[1]+=(double)h.y*h.y;
    ss[2]+=(double)h.z*h.z; ss[3]+=(double)h.w*h.w;
  }
  #pragma unroll
  for (int jj = 0; jj < 4; ++jj) { redS[rs][cbase+jj] = s[jj]; redQ[rs][cbase+jj] = ss[jj]; }
  __syncthreads();
  if (t < 64) {
    double a = 0, bq = 0;
    #pragma unroll
    for (int r = 0; r < 16; ++r) { a += redS[r][t]; bq += redQ[r][t]; }
    psum[(size_t)blk*64 + t] = a;
    psq[(size_t)blk*64 + t] = bq;
  }
}

// ------------------------------------ max over k with BN affine (monotone)
__global__ void ec1_reduce_kernel(const float* __restrict__ h3,
    const float2* __restrict__ aff, float* __restrict__ x1) {
  int idx = blockIdx.x * 256 + threadIdx.x;
  if (idx >= NPT * 64) return;
  int p = idx >> 6, c = idx & 63;
  float mx = -FINF, mn = FINF;
  #pragma unroll
  for (int kk = 0; kk < KNN; ++kk) {
    float v = h3[((size_t)p*KNN + kk)*64 + c];
    mx = fmaxf(mx, v); mn = fminf(mn, v);
  }
  float2 ac = aff[c];
  x1[idx] = (ac.x >= 0.f) ? fmaf(ac.x, mx, ac.y) : fmaf(ac.x, mn, ac.y);
}

// ---------------------------------------------------------------- knn (64-d)
__global__ __launch_bounds__(256) void knn2_kernel(const float* __restrict__ x1,
                                                   int* __restrict__ knn_idx) {
  __shared__ float xi[64][68];
  __shared__ float xj[64][68];
  __shared__ float sqi[64];
  __shared__ float sqj[64];
  const int b = blockIdx.x >> 4;
  const int it = blockIdx.x & 15;
  const int t = threadIdx.x;
  const int ibase = it * 64;  // within batch
  for (int idx = t; idx < 64*64; idx += 256) {
    int r = idx >> 6, c = idx & 63;
    xi[r][c] = x1[((size_t)b*NP + ibase + r)*64 + c];
  }
  __syncthreads();
  if (t < 64) {
    float s = 0.f;
    #pragma unroll
    for (int c = 0; c < 64; ++c) s = fmaf(xi[t][c], xi[t][c], s);
    sqi[t] = s;
  }
  __syncthreads();
  const int il = t >> 4, jl = t & 15;
  float bd[4][5];
  int bj[4][5];
  #pragma unroll
  for (int ii = 0; ii < 4; ++ii) {
    #pragma unroll
    for (int s = 0; s < 5; ++s) { bd[ii][s] = FINF; bj[ii][s] = 0x7fffffff; }
  }
  float si[4];
  #pragma unroll
  for (int ii = 0; ii < 4; ++ii) si[ii] = sqi[il*4 + ii];

  for (int jt = 0; jt < 16; ++jt) {
    __syncthreads();
    for (int idx = t; idx < 64*64; idx += 256) {
      int r = idx >> 6, c = idx & 63;
      xj[r][c] = x1[((size_t)b*NP + jt*64 + r)*64 + c];
    }
    __syncthreads();
    if (t < 64) {
      float s = 0.f;
      #pragma unroll
      for (int c = 0; c < 64; ++c) s = fmaf(xj[t][c], xj[t][c], s);
      sqj[t] = s;
    }
    __syncthreads();
    float acc[4][4];
    #pragma unroll
    for (int ii = 0; ii < 4; ++ii) {
      #pragma unroll
      for (int jj = 0; jj < 4; ++jj) acc[ii][jj] = 0.f;
    }
    for (int cin = 0; cin < 64; cin += 4) {
      float4 fi[4], fj[4];
      #pragma unroll
      for (int ii = 0; ii < 4; ++ii) fi[ii] = *(const float4*)&xi[il*4+ii][cin];
      #pragma unroll
      for (int jj = 0; jj < 4; ++jj) fj[jj] = *(const float4*)&xj[jl + 16*jj][cin];
      #pragma unroll
      for (int q = 0; q < 4; ++q) {
        #pragma unroll
        for (int ii = 0; ii < 4; ++ii) {
          float f = f4c(fi[ii], q);
          acc[ii][0] = fmaf(f, f4c(fj[0],q), acc[ii][0]);
          acc[ii][1] = fmaf(f, f4c(fj[1],q), acc[ii][1]);
          acc[ii][2] = fmaf(f, f4c(fj[2],q), acc[ii][2]);
          acc[ii][3] = fmaf(f, f4c(fj[3],q), acc[ii][3]);
        }
      }
    }
    #pragma unroll
    for (int jj = 0; jj < 4; ++jj) {
      int jloc = jl + 16*jj;
      int jg = jt*64 + jloc;
      float sj = sqj[jloc];
      #pragma unroll
      for (int ii = 0; ii < 4; ++ii) {
        float dd = fmaf(-2.f, acc[ii][jj], si[ii] + sj);
        if (lex_less(dd, jg, bd[ii][4], bj[ii][4])) {
          bool L0 = lex_less(dd,jg,bd[ii][0],bj[ii][0]);
          bool L1 = lex_less(dd,jg,bd[ii][1],bj[ii][1]);
          bool L2 = lex_less(dd,jg,bd[ii][2],bj[ii][2]);
          bool L3 = lex_less(dd,jg,bd[ii][3],bj[ii][3]);
          bd[ii][4] = L3 ? bd[ii][3] : dd;  bj[ii][4] = L3 ? bj[ii][3] : jg;
          bd[ii][3] = L3 ? (L2 ? bd[ii][2] : dd) : bd[ii][3];
          bj[ii][3] = L3 ? (L2 ? bj[ii][2] : jg) : bj[ii][3];
          bd[ii][2] = L2 ? (L1 ? bd[ii][1] : dd) : bd[ii][2];
          bj[ii][2] = L2 ? (L1 ? bj[ii][1] : jg) : bj[ii][2];
          bd[ii][1] = L1 ? (L0 ? bd[ii][0] : dd) : bd[ii][1];
          bj[ii][1] = L1 ? (L0 ? bj[ii][0] : jg) : bj[ii][1];
          bd[ii][0] = L0 ? dd : bd[ii][0];  bj[ii][0] = L0 ? jg : bj[ii][0];
        }
      }
    }
  }
  // merge sorted top-5 lists across the 16 j-lanes
  #pragma unroll
  for (int ii = 0; ii < 4; ++ii) {
    #pragma unroll
    for (int s = 0; s < 5; ++s) {
      float md = bd[ii][0]; int mj = bj[ii][0];
      #pragma unroll
      for (int off = 1; off <= 8; off <<= 1) {
        float od = __shfl_xor(md, off, 16);
        int oj = __shfl_xor(mj, off, 16);
        if (lex_less(od, oj, md, mj)) { md = od; mj = oj; }
      }
      if (md == bd[ii][0] && mj == bj[ii][0]) {
        bd[ii][0]=bd[ii][1]; bj[ii][0]=bj[ii][1];
        bd[ii][1]=bd[ii][2]; bj[ii][1]=bj[ii][2];
        bd[ii][2]=bd[ii][3]; bj[ii][2]=bj[ii][3];
        bd[ii][3]=bd[ii][4]; bj[ii][3]=bj[ii][4];
        bd[ii][4]=FINF; bj[ii][4]=0x7fffffff;
      }
      if (jl == 0) knn_idx[((size_t)b*NP + ibase + il*4 + ii)*KNN + s] = b*NP + mj;
    }
  }
}

// --------------------- EdgeConv2 (128 -> 128) fused with k-max/min + stats
__global__ __launch_bounds__(256) void ec2_kernel(const float* __restrict__ x1,
    const int* __restrict__ knn_idx, const float* __restrict__ W,
    const float* __restrict__ bias, float* __restrict__ x2max,
    float* __restrict__ x2min, double* __restrict__ psum, double* __restrict__ psq) {
  __shared__ float e2[40][128];
  __shared__ double redS[8][128];
  __shared__ double redQ[8][128];
  const int blk = blockIdx.x, t = threadIdx.x;
  const int pbase = blk * 8;
  for (int idx = t; idx < 40*128; idx += 256) {
    int r = idx >> 7, c = idx & 127;
    int p = pbase + r / KNN;
    int kk = r % KNN;
    int j = knn_idx[(size_t)p*KNN + kk];
    float v;
    if (c < 64) v = x1[(size_t)p*64 + c];
    else {
      int cc = c - 64;
      v = x1[(size_t)j*64 + cc] - x1[(size_t)p*64 + cc];
    }
    e2[r][c] = v;
  }
  __syncthreads();
  const int c4 = t & 31, rs = t >> 5;
  const int cbase = c4 * 4;
  float4 bv = *(const float4*)&bias[cbase];
  float acc[5][4];
  #pragma unroll
  for (int kk = 0; kk < 5; ++kk) {
    acc[kk][0]=bv.x; acc[kk][1]=bv.y; acc[kk][2]=bv.z; acc[kk][3]=bv.w;
  }
  for (int cin = 0; cin < 128; cin += 4) {
    float4 fi[5];
    #pragma unroll
    for (int kk = 0; kk < 5; ++kk) fi[kk] = *(const float4*)&e2[rs*5+kk][cin];
    #pragma unroll
    for (int q = 0; q < 4; ++q) {
      float4 wv = *(const float4*)&W[(size_t)(cin+q)*128 + cbase];
      #pragma unroll
      for (int kk = 0; kk < 5; ++kk) {
        float f = f4c(fi[kk], q);
        acc[kk][0] = fmaf(f, wv.x, acc[kk][0]);
        acc[kk][1] = fmaf(f, wv.y, acc[kk][1]);
        acc[kk][2] = fmaf(f, wv.z, acc[kk][2]);
        acc[kk][3] = fmaf(f, wv.w, acc[kk][3]);
      }
    }
  }
  float mx[4] = {-FINF,-FINF,-FINF,-FINF}, mn[4] = {FINF,FINF,FINF,FINF};
  double s[4] = {0,0,0,0}, ss[4] = {0,0,0,0};
  #pragma unroll
  for (int kk = 0; kk < 5; ++kk) {
    #pragma unroll
    for (int jj = 0; jj < 4; ++jj) {
      float h = fmaxf(acc[kk][jj], 0.f);
      mx[jj] = fmaxf(mx[jj], h); mn[jj] = fminf(mn[jj], h);
      s[jj] += h; ss[jj] += (double)h * h;
    }
  }
  *(float4*)&x2max[((size_t)pbase + rs)*128 + cbase] = make_float4(mx[0],mx[1],mx[2],mx[3]);
  *(float4*)&x2min[((size_t)pbase + rs)*128 + cbase] = make_float4(mn[0],mn[1],mn[2],mn[3]);
  #pragma unroll
  for (int jj = 0; jj < 4; ++jj) { redS[rs][cbase+jj] = s[jj]; redQ[rs][cbase+jj] = ss[jj]; }
  __syncthreads();
  if (t < 128) {
    double a = 0, q2 = 0;
    #pragma unroll
    for (int r = 0; r < 8; ++r) { a += redS[r][t]; q2 += redQ[r][t]; }
    psum[(size_t)blk*128 + t] = a;
    psq[(size_t)blk*128 + t] = q2;
  }
}

__global__ void ec2_fin_kernel(const float* __restrict__ x2max,
    const float* __restrict__ x2min, const float2* __restrict__ aff,
    float* __restrict__ x2) {
  int idx = blockIdx.x*256 + threadIdx.x;
  if (idx >= NPT*128) return;
  int c = idx & 127;
  float2 ac = aff[c];
  x2[idx] = (ac.x >= 0.f) ? fmaf(ac.x, x2max[idx], ac.y) : fmaf(ac.x, x2min[idx], ac.y);
}

// ------------- Lin1 (192 -> 1024) fused with ReLU + stats + per-batch max/min
__global__ __launch_bounds__(256) void lin1_kernel(const float* __restrict__ x1,
    const float* __restrict__ x2, const float* __restrict__ W,
    const float* __restrict__ bias, double* __restrict__ psum,
    double* __restrict__ psq, float* __restrict__ pmax, float* __restrict__ pmin) {
  __shared__ float fin[64][192];
  const int blk = blockIdx.x, t = threadIdx.x;
  const int pbase = blk * 64;
  for (int idx = t; idx < 64*192; idx += 256) {
    int r = idx / 192, c = idx % 192;
    int p = pbase + r;
    fin[r][c] = (c < 64) ? x1[(size_t)p*64 + c] : x2[(size_t)p*128 + (c - 64)];
  }
  __syncthreads();
  const int c0 = t * 4;
  float4 bv = *(const float4*)&bias[c0];
  double s[4] = {0,0,0,0}, ss[4] = {0,0,0,0};
  float mx[4] = {-FINF,-FINF,-FINF,-FINF}, mn[4] = {FINF,FINF,FINF,FINF};
  for (int pass = 0; pass < 4; ++pass) {
    const int rbase = pass * 16;
    float4 acc[16];
    #pragma unroll
    for (int rr = 0; rr < 16; ++rr) acc[rr] = bv;
    for (int cin = 0; cin < 192; cin += 4) {
      float4 wv0 = *(const float4*)&W[(size_t)(cin+0)*1024 + c0];
      float4 wv1 = *(const float4*)&W[(size_t)(cin+1)*1024 + c0];
      float4 wv2 = *(const float4*)&W[(size_t)(cin+2)*1024 + c0];
      float4 wv3 = *(const float4*)&W[(size_t)(cin+3)*1024 + c0];
      #pragma unroll
      for (int rr = 0; rr < 16; ++rr) {
        float4 f = *(const float4*)&fin[rbase+rr][cin];
        acc[rr].x = fmaf(f.x, wv0.x, acc[rr].x);
        acc[rr].y = fmaf(f.x, wv0.y, acc[rr].y);
        acc[rr].z = fmaf(f.x, wv0.z, acc[rr].z);
        acc[rr].w = fmaf(f.x, wv0.w, acc[rr].w);
        acc[rr].x = fmaf(f.y, wv1.x, acc[rr].x);
        acc[rr].y = fmaf(f.y, wv1.y, acc[rr].y);
        acc[rr].z = fmaf(f.y, wv1.z, acc[rr].z);
        acc[rr].w = fmaf(f.y, wv1.w, acc[rr].w);
        acc[rr].x = fmaf(f.z, wv2.x, acc[rr].x);
        acc[rr].y = fmaf(f.z, wv2.y, acc[rr].y);
        acc[rr].z = fmaf(f.z, wv2.z, acc[rr].z);
        acc[rr].w = fmaf(f.z, wv2.w, acc[rr].w);
        acc[rr].x = fmaf(f.w, wv3.x, acc[rr].x);
        acc[rr].y = fmaf(f.w, wv3.y, acc[rr].y);
        acc[rr].z = fmaf(f.w, wv3.z, acc[rr].z);
        acc[rr].w = fmaf(f.w, wv3.w, acc[rr].w);
      }
    }
    #pragma unroll
    for (int rr = 0; rr < 16; ++rr) {
      float h0 = fmaxf(acc[rr].x, 0.f), h1 = fmaxf(acc[rr].y, 0.f);
      float h2 = fmaxf(acc[rr].z, 0.f), h3 = fmaxf(acc[rr].w, 0.f);
      s[0]+=h0; ss[0]+=(double)h0*h0; mx[0]=fmaxf(mx[0],h0); mn[0]=fminf(mn[0],h0);
      s[1]+=h1; ss[1]+=(double)h1*h1; mx[1]=fmaxf(mx[1],h1); mn[1]=fminf(mn[1],h1);
      s[2]+=h2; ss[2]+=(double)h2*h2; mx[2]=fmaxf(mx[2],h2); mn[2]=fminf(mn[2],h2);
      s[3]+=h3; ss[3]+=(double)h3*h3; mx[3]=fmaxf(mx[3],h3); mn[3]=fminf(mn[3],h3);
    }
  }
  #pragma unroll
  for (int jj = 0; jj < 4; ++jj) {
    psum[(size_t)blk*1024 + c0 + jj] = s[jj];
    psq[(size_t)blk*1024 + c0 + jj] = ss[jj];
    pmax[(size_t)blk*1024 + c0 + jj] = mx[jj];
    pmin[(size_t)blk*1024 + c0 + jj] = mn[jj];
  }
}

__global__ void lin1_fin_kernel(const double* __restrict__ psum,
    const double* __restrict__ psq, const float* __restrict__ pmax,
    const float* __restrict__ pmin, const float* __restrict__ g,
    const float* __restrict__ be, float* __restrict__ y) {
  int c = blockIdx.x*256 + threadIdx.x;
  if (c >= 1024) return;
  double s = 0, ss = 0;
  for (int i = 0; i < 512; ++i) {
    s += psum[(size_t)i*1024 + c];
    ss += psq[(size_t)i*1024 + c];
  }
  double mean = s / 32768.0;
  double var = ss / 32768.0 - mean*mean;
  var = var < 0.0 ? 0.0 : var;
  double inv = 1.0 / sqrt(var + 1e-5);
  float a = (float)((double)g[c] * inv);
  float off = (float)((double)be[c] - (double)g[c]*mean*inv);
  for (int b = 0; b < NB; ++b) {
    float mxv = -FINF, mnv = FINF;
    for (int i = 0; i < 16; ++i) {
      mxv = fmaxf(mxv, pmax[(size_t)(b*16+i)*1024 + c]);
      mnv = fminf(mnv, pmin[(size_t)(b*16+i)*1024 + c]);
    }
    y[(size_t)b*1024 + c] = (a >= 0.f) ? fmaf(a, mxv, off) : fmaf(a, mnv, off);
  }
}

// ---------------------------------------------------------------- head MLP
__global__ void head1_kernel(const float* __restrict__ y, const float* __restrict__ W,
    const float* __restrict__ bias, float* __restrict__ h5) {
  int idx = blockIdx.x*256 + threadIdx.x;   // 32*512
  int r = idx >> 9, c = idx & 511;
  float acc = bias[c];
  for (int cin = 0; cin < 1024; ++cin)
    acc = fmaf(y[(size_t)r*1024 + cin], W[(size_t)cin*512 + c], acc);
  h5[idx] = fmaxf(acc, 0.f);
}

__global__ void bn_rows_kernel(const float* __restrict__ h, int C, int R,
    const float* __restrict__ g, const float* __restrict__ be, float2* __restrict__ aff) {
  int c = blockIdx.x*256 + threadIdx.x;
  if (c >= C) return;
  double s = 0, ss = 0;
  for (int r = 0; r < R; ++r) {
    double v = (double)h[(size_t)r*C + c];
    s += v; ss += v*v;
  }
  double mean = s / (double)R;
  double var = ss / (double)R - mean*mean;
  var = var < 0.0 ? 0.0 : var;
  double inv = 1.0 / sqrt(var + 1e-5);
  float a = (float)((double)g[c] * inv);
  float off = (float)((double)be[c] - (double)g[c]*mean*inv);
  aff[c] = make_float2(a, off);
}

__global__ void head2_kernel(const float* __restrict__ h5, const float2* __restrict__ aff,
    const float* __restrict__ W, const float* __restrict__ bias, float* __restrict__ h6) {
  int idx = blockIdx.x*256 + threadIdx.x;   // 32*256
  int r = idx >> 8, c = idx & 255;
  float acc = bias[c];
  for (int cin = 0; cin < 512; ++cin) {
    float2 a = aff[cin];
    acc = fmaf(fmaf(a.x, h5[(size_t)r*512 + cin], a.y), W[(size_t)cin*256 + c], acc);
  }
  h6[idx] = fmaxf(acc, 0.f);
}

__global__ void head3_kernel(const float* __restrict__ h6, const float2* __restrict__ aff,
    const float* __restrict__ W, const float* __restrict__ bias, float* __restrict__ out) {
  int t = threadIdx.x;
  if (t >= 64) return;
  int r = t >> 1, c = t & 1;
  float acc = bias[c];
  for (int cin = 0; cin < 256; ++cin) {
    float2 a = aff[cin];
    acc = fmaf(fmaf(a.x, h6[(size_t)r*256 + cin], a.y), W[(size_t)cin*2 + c], acc);
  }
  out[(size_t)r*2 + c] = acc;
}

// ------------------------------------------------------------------ launcher
extern "C" void kernel_launch(void* const* d_in, const int* in_sizes, int n_in,
                              void* d_out, int out_size, void* d_ws, size_t ws_size,
                              hipStream_t stream) {
  (void)in_sizes; (void)n_in; (void)out_size; (void)ws_size;
  const float* pos    = (const float*)d_in[0];
  const float* c1_w1  = (const float*)d_in[2];
  const float* c1_b1  = (const float*)d_in[3];
  const float* c1_g1  = (const float*)d_in[4];
  const float* c1_be1 = (const float*)d_in[5];
  const float* c1_w2  = (const float*)d_in[6];
  const float* c1_b2  = (const float*)d_in[7];
  const float* c1_g2  = (const float*)d_in[8];
  const float* c1_be2 = (const float*)d_in[9];
  const float* c1_w3  = (const float*)d_in[10];
  const float* c1_b3  = (const float*)d_in[11];
  const float* c1_g3  = (const float*)d_in[12];
  const float* c1_be3 = (const float*)d_in[13];
  const float* c2_w1  = (const float*)d_in[14];
  const float* c2_b1  = (const float*)d_in[15];
  const float* c2_g1  = (const float*)d_in[16];
  const float* c2_be1 = (const float*)d_in[17];
  const float* l1_w   = (const float*)d_in[18];
  const float* l1_b   = (const float*)d_in[19];
  const float* l1_g   = (const float*)d_in[20];
  const float* l1_be  = (const float*)d_in[21];
  const float* m1_w   = (const float*)d_in[22];
  const float* m1_b   = (const float*)d_in[23];
  const float* m1_g   = (const float*)d_in[24];
  const float* m1_be  = (const float*)d_in[25];
  const float* m2_w   = (const float*)d_in[26];
  const float* m2_b   = (const float*)d_in[27];
  const float* m2_g   = (const float*)d_in[28];
  const float* m2_be  = (const float*)d_in[29];
  const float* m3_w   = (const float*)d_in[30];
  const float* m3_b   = (const float*)d_in[31];

  char* ws = (char*)d_ws;
  size_t off = 0;
  auto alloc = [&](size_t bytes) -> void* {
    void* p = ws + off;
    off += (bytes + 255) & ~(size_t)255;
    return p;
  };
  int*    idx1 = (int*)alloc((size_t)NE * 4);
  int*    idx2 = (int*)alloc((size_t)NE * 4);
  float*  x1   = (float*)alloc((size_t)NPT * 64 * 4);
  float*  x2   = (float*)alloc((size_t)NPT * 128 * 4);
  float*  hA   = (float*)alloc((size_t)NE * 64 * 4);
  float*  hB   = (float*)alloc((size_t)NE * 64 * 4);
  double* psum = (double*)alloc((size_t)524288 * 8);
  double* psq  = (double*)alloc((size_t)524288 * 8);
  float*  pmax = (float*)alloc((size_t)524288 * 4);
  float*  pmin = (float*)alloc((size_t)524288 * 4);
  float2* affA = (float2*)alloc(64 * 8);
  float2* affB = (float2*)alloc(64 * 8);
  float2* affC = (float2*)alloc(64 * 8);
  float2* aff2 = (float2*)alloc(128 * 8);
  float2* affM1 = (float2*)alloc(512 * 8);
  float2* affM2 = (float2*)alloc(256 * 8);
  float*  y    = (float*)alloc((size_t)NB * 1024 * 4);
  float*  h5   = (float*)alloc((size_t)NB * 512 * 4);
  float*  h6   = (float*)alloc((size_t)NB * 256 * 4);
  // x2max/x2min reuse hA (h3 dead by then): 2 * 16.78MB <= 41.9MB
  float* x2max = hA;
  float* x2min = hA + (size_t)NPT * 128;

  // 1. knn on positions
  knn1_kernel<<<dim3(NB*4), dim3(256), 0, stream>>>(pos, idx1);
  // 2. EdgeConv1 layer1
  ec1_l1_kernel<<<dim3(NE/64), dim3(256), 0, stream>>>(pos, idx1, c1_w1, c1_b1, hA, psum, psq);
  stats_reduce_kernel<<<dim3(1), dim3(256), 0, stream>>>(psum, psq, NE/64, 64, 1.0/NE, c1_g1, c1_be1, affA);
  // 3. layer2
  ec_l64_kernel<<<dim3(NE/64), dim3(256), 0, stream>>>(hA, affA, c1_w2, c1_b2, hB, psum, psq);
  stats_reduce_kernel<<<dim3(1), dim3(256), 0, stream>>>(psum, psq, NE/64, 64, 1.0/NE, c1_g2, c1_be2, affB);
  // 4. layer3
  ec_l64_kernel<<<dim3(NE/64), dim3(256), 0, stream>>>(hB, affB, c1_w3, c1_b3, hA, psum, psq);
  stats_reduce_kernel<<<dim3(1), dim3(256), 0, stream>>>(psum, psq, NE/64, 64, 1.0/NE, c1_g3, c1_be3, affC);
  // 5. max over k -> x1
  ec1_reduce_kernel<<<dim3(NPT*64/256), dim3(256), 0, stream>>>(hA, affC, x1);
  // 6. knn on features
  knn2_kernel<<<dim3(NB*16), dim3(256), 0, stream>>>(x1, idx2);
  // 7. EdgeConv2 (fused k-max/min)
  ec2_kernel<<<dim3(NPT/8), dim3(256), 0, stream>>>(x1, idx2, c2_w1, c2_b1, x2max, x2min, psum, psq);
  stats_reduce_kernel<<<dim3(1), dim3(256), 0, stream>>>(psum, psq, NPT/8, 128, 1.0/NE, c2_g1, c2_be1, aff2);
  ec2_fin_kernel<<<dim3(NPT*128/256), dim3(256), 0, stream>>>(x2max, x2min, aff2, x2);
  // 8. Lin1 fused (no materialization of [32768,1024])
  lin1_kernel<<<dim3(NPT/64), dim3(256), 0, stream>>>(x1, x2, l1_w, l1_b, psum, psq, pmax, pmin);
  lin1_fin_kernel<<<dim3(4), dim3(256), 0, stream>>>(psum, psq, pmax, pmin, l1_g, l1_be, y);
  // 9. head
  head1_kernel<<<dim3(64), dim3(256), 0, stream>>>(y, m1_w, m1_b, h5);
  bn_rows_kernel<<<dim3(2), dim3(256), 0, stream>>>(h5, 512, NB, m1_g, m1_be, affM1);
  head2_kernel<<<dim3(32), dim3(256), 0, stream>>>(h5, affM1, m2_w, m2_b, h6);
  bn_rows_kernel<<<dim3(1), dim3(256), 0, stream>>>(h6, 256, NB, m2_g, m2_be, affM2);
  head3_kernel<<<dim3(1), dim3(64), 0, stream>>>(h6, affM2, m3_w, m3_b, (float*)d_out);
}

// Round 2
// 1575.998 us; speedup vs baseline: 2.9527x; 2.9527x over previous
//
#include <hip/hip_runtime.h>

// DGCNN forward: knn(3d) -> EdgeConv(6->64->64->64,BN) -> knn(64d) ->
// EdgeConv(128->128,BN) -> Lin(192->1024)+BN+maxpool -> head MLP -> [32,2]
// All BN stats are global (training mode) => per-layer kernels with
// deterministic double-precision two-stage reductions; BN folded into
// per-channel affine applied on load by the consumer kernel.
// R2: stats reductions parallelized (block-per-channel) — the single-block
// serial loops were 4.3ms of the 4.65ms total (latency-bound, occ 0.02%).

#define NB 32
#define NP 1024
#define NPT 32768       // NB*NP
#define KNN 5
#define NE 163840       // NPT*KNN

#define FINF 3.402823466e+38f

__device__ __forceinline__ bool lex_less(float da, int ja, float db, int jb) {
  return (da < db) || (da == db && ja < jb);
}

__device__ __forceinline__ float f4c(const float4& v, int q) {
  return q == 0 ? v.x : (q == 1 ? v.y : (q == 2 ? v.z : v.w));
}

// ---------------------------------------------------------------- knn (3-d)
__global__ __launch_bounds__(256) void knn1_kernel(const float* __restrict__ pos,
                                                   int* __restrict__ knn_idx) {
  __shared__ float xs[NP * 3];
  __shared__ float sq[NP];
  const int b = blockIdx.x >> 2;
  const int qtr = blockIdx.x & 3;
  const int t = threadIdx.x;
  for (int i = t; i < NP * 3; i += 256) xs[i] = pos[(size_t)b * NP * 3 + i];
  __syncthreads();
  for (int i = t; i < NP; i += 256) {
    float x0 = xs[i*3+0], x1 = xs[i*3+1], x2 = xs[i*3+2];
    sq[i] = __fadd_rn(__fadd_rn(__fmul_rn(x0,x0), __fmul_rn(x1,x1)), __fmul_rn(x2,x2));
  }
  __syncthreads();
  const int i = qtr * 256 + t;
  const float xi0 = xs[i*3+0], xi1 = xs[i*3+1], xi2 = xs[i*3+2];
  const float sqi = sq[i];
  float d0=FINF,d1=FINF,d2=FINF,d3=FINF,d4=FINF;
  int j0=0x7fffffff,j1=0x7fffffff,j2=0x7fffffff,j3=0x7fffffff,j4=0x7fffffff;
  for (int j = 0; j < NP; ++j) {
    float y0 = xs[j*3+0], y1 = xs[j*3+1], y2 = xs[j*3+2];
    float dot = __fadd_rn(__fadd_rn(__fmul_rn(xi0,y0), __fmul_rn(xi1,y1)), __fmul_rn(xi2,y2));
    float dd = __fsub_rn(__fadd_rn(sqi, sq[j]), __fmul_rn(2.0f, dot));
    if (lex_less(dd, j, d4, j4)) {
      bool L0 = lex_less(dd,j,d0,j0), L1 = lex_less(dd,j,d1,j1),
           L2 = lex_less(dd,j,d2,j2), L3 = lex_less(dd,j,d3,j3);
      d4 = L3 ? d3 : dd;              j4 = L3 ? j3 : j;
      d3 = L3 ? (L2 ? d2 : dd) : d3;  j3 = L3 ? (L2 ? j2 : j) : j3;
      d2 = L2 ? (L1 ? d1 : dd) : d2;  j2 = L2 ? (L1 ? j1 : j) : j2;
      d1 = L1 ? (L0 ? d0 : dd) : d1;  j1 = L1 ? (L0 ? j0 : j) : j1;
      d0 = L0 ? dd : d0;              j0 = L0 ? j : j0;
    }
  }
  const size_t row = (size_t)b * NP + i;
  knn_idx[row*KNN+0] = b*NP + j0;
  knn_idx[row*KNN+1] = b*NP + j1;
  knn_idx[row*KNN+2] = b*NP + j2;
  knn_idx[row*KNN+3] = b*NP + j3;
  knn_idx[row*KNN+4] = b*NP + j4;
}

// ------------------------------------------- EdgeConv1 layer1 (6 -> 64) + stats
__global__ __launch_bounds__(256) void ec1_l1_kernel(const float* __restrict__ pos,
    const int* __restrict__ knn_idx, const float* __restrict__ W,
    const float* __restrict__ bias, float* __restrict__ hout,
    double* __restrict__ psum, double* __restrict__ psq) {
  __shared__ float ef[64][6];
  __shared__ float Wl[6][64];
  __shared__ float bl[64];
  __shared__ double red[256];
  const int blk = blockIdx.x, t = threadIdx.x;
  const int ebase = blk * 64;
  if (t < 64) {
    int e = ebase + t;
    int ip = e / KNN;
    int jp = knn_idx[e];
    float a0 = pos[(size_t)ip*3+0], a1 = pos[(size_t)ip*3+1], a2 = pos[(size_t)ip*3+2];
    float c0 = pos[(size_t)jp*3+0], c1 = pos[(size_t)jp*3+1], c2 = pos[(size_t)jp*3+2];
    ef[t][0] = a0; ef[t][1] = a1; ef[t][2] = a2;
    ef[t][3] = c0 - a0; ef[t][4] = c1 - a1; ef[t][5] = c2 - a2;
    bl[t] = bias[t];
  }
  for (int idx = t; idx < 6*64; idx += 256) Wl[idx>>6][idx&63] = W[idx];
  __syncthreads();
  const int c = t & 63, rs = t >> 6;
  double s = 0.0, ss = 0.0;
  for (int r = rs; r < 64; r += 4) {
    float acc = bl[c];
    #pragma unroll
    for (int q = 0; q < 6; ++q) acc = fmaf(ef[r][q], Wl[q][c], acc);
    acc = fmaxf(acc, 0.0f);
    hout[(size_t)(ebase + r)*64 + c] = acc;
    s += acc; ss += (double)acc * (double)acc;
  }
  red[t] = s; __syncthreads();
  if (t < 64) psum[(size_t)blk*64 + t] = red[t] + red[t+64] + red[t+128] + red[t+192];
  __syncthreads();
  red[t] = ss; __syncthreads();
  if (t < 64) psq[(size_t)blk*64 + t] = red[t] + red[t+64] + red[t+128] + red[t+192];
}

// ------------------- BN stats -> per-channel affine (block per channel, R2)
__global__ __launch_bounds__(256) void stats_reduce_kernel(const double* __restrict__ psum,
    const double* __restrict__ psq, int nblk, int C, double invN,
    const float* __restrict__ g, const float* __restrict__ be,
    float2* __restrict__ aff) {
  __shared__ double rs[256];
  __shared__ double rq[256];
  const int c = blockIdx.x;          // grid = C
  const int t = threadIdx.x;
  double s = 0.0, ss = 0.0;
  for (int i = t; i < nblk; i += 256) {
    s  += psum[(size_t)i*C + c];
    ss += psq [(size_t)i*C + c];
  }
  rs[t] = s; rq[t] = ss; __syncthreads();
  for (int off = 128; off > 0; off >>= 1) {
    if (t < off) { rs[t] += rs[t+off]; rq[t] += rq[t+off]; }
    __syncthreads();
  }
  if (t == 0) {
    double mean = rs[0] * invN;
    double var = rq[0] * invN - mean*mean;
    var = var < 0.0 ? 0.0 : var;
    double inv = 1.0 / sqrt(var + 1e-5);
    float a = (float)((double)g[c] * inv);
    float off2 = (float)((double)be[c] - (double)g[c] * mean * inv);
    aff[c] = make_float2(a, off2);
  }
}

// -------------------------------- EdgeConv1 layers 2/3 (64 -> 64) + stats
__global__ __launch_bounds__(256) void ec_l64_kernel(const float* __restrict__ hin,
    const float2* __restrict__ affprev, const float* __restrict__ W,
    const float* __restrict__ bias, float* __restrict__ hout,
    double* __restrict__ psum, double* __restrict__ psq) {
  __shared__ float ein[64][68];
  __shared__ float Wl[64][64];
  __shared__ float2 affl[64];
  __shared__ float bl[64];
  __shared__ double redS[16][64];
  __shared__ double redQ[16][64];
  const int blk = blockIdx.x, t = threadIdx.x;
  const size_t ebase = (size_t)blk * 64;
  if (t < 64) { affl[t] = affprev[t]; bl[t] = bias[t]; }
  __syncthreads();
  for (int idx = t; idx < 64*64; idx += 256) {
    int r = idx >> 6, c = idx & 63;
    float2 ac = affl[c];
    ein[r][c] = fmaf(hin[ebase*64 + idx], ac.x, ac.y);
    Wl[r][c] = W[idx];
  }
  __syncthreads();
  const int c4 = t & 15, rs = t >> 4;
  const int cbase = c4 * 4;
  const int rbase = rs * 4;
  float acc[4][4];
  #pragma unroll
  for (int ii = 0; ii < 4; ++ii) {
    #pragma unroll
    for (int jj = 0; jj < 4; ++jj) acc[ii][jj] = bl[cbase + jj];
  }
  for (int cin = 0; cin < 64; cin += 4) {
    float4 fi[4];
    #pragma unroll
    for (int ii = 0; ii < 4; ++ii) fi[ii] = *(const float4*)&ein[rbase+ii][cin];
    #pragma unroll
    for (int q = 0; q < 4; ++q) {
      float4 wv = *(const float4*)&Wl[cin+q][cbase];
      #pragma unroll
      for (int ii = 0; ii < 4; ++ii) {
        float f = f4c(fi[ii], q);
        acc[ii][0] = fmaf(f, wv.x, acc[ii][0]);
        acc[ii][1] = fmaf(f, wv.y, acc[ii][1]);
        acc[ii][2] = fmaf(f, wv.z, acc[ii][2]);
        acc[ii][3] = fmaf(f, wv.w, acc[ii][3]);
      }
    }
  }
  double s[4] = {0,0,0,0}, ss[4] = {0,0,0,0};
  #pragma unroll
  for (int ii = 0; ii < 4; ++ii) {
    float4 h;
    h.x = fmaxf(acc[ii][0], 0.f); h.y = fmaxf(acc[ii][1], 0.f);
    h.z = fmaxf(acc[ii][2], 0.f); h.w = fmaxf(acc[ii][3], 0.f);
    *(float4*)&hout[(ebase + rbase + ii)*64 + cbase] = h;
    s[0]+=h.x; s[1]+=h.y; s[2]+=h.z; s[3]+=h.w;
    ss[0]+=(double)h.x*h.x; ss[1]+=(double)h.y*h.y;
    ss[2]+=(double)h.z*h.z; ss[3]+=(double)h.w*h.w;
  }
  #pragma unroll
  for (int jj = 0; jj < 4; ++jj) { redS[rs][cbase+jj] = s[jj]; redQ[rs][cbase+jj] = ss[jj]; }
  __syncthreads();
  if (t < 64) {
    double a = 0, bq = 0;
    #pragma unroll
    for (int r = 0; r < 16; ++r) { a += redS[r][t]; bq += redQ[r][t]; }
    psum[(size_t)blk*64 + t] = a;
    psq[(size_t)blk*64 + t] = bq;
  }
}

// ------------------------------------ max over k with BN affine (monotone)
__global__ void ec1_reduce_kernel(const float* __restrict__ h3,
    const float2* __restrict__ aff, float* __restrict__ x1) {
  int idx = blockIdx.x * 256 + threadIdx.x;
  if (idx >= NPT * 64) return;
  int p = idx >> 6, c = idx & 63;
  float mx = -FINF, mn = FINF;
  #pragma unroll
  for (int kk = 0; kk < KNN; ++kk) {
    float v = h3[((size_t)p*KNN + kk)*64 + c];
    mx = fmaxf(mx, v); mn = fminf(mn, v);
  }
  float2 ac = aff[c];
  x1[idx] = (ac.x >= 0.f) ? fmaf(ac.x, mx, ac.y) : fmaf(ac.x, mn, ac.y);
}

// ---------------------------------------------------------------- knn (64-d)
__global__ __launch_bounds__(256) void knn2_kernel(const float* __restrict__ x1,
                                                   int* __restrict__ knn_idx) {
  __shared__ float xi[64][68];
  __shared__ float xj[64][68];
  __shared__ float sqi[64];
  __shared__ float sqj[64];
  const int b = blockIdx.x >> 4;
  const int it = blockIdx.x & 15;
  const int t = threadIdx.x;
  const int ibase = it * 64;  // within batch
  for (int idx = t; idx < 64*64; idx += 256) {
    int r = idx >> 6, c = idx & 63;
    xi[r][c] = x1[((size_t)b*NP + ibase + r)*64 + c];
  }
  __syncthreads();
  if (t < 64) {
    float s = 0.f;
    #pragma unroll
    for (int c = 0; c < 64; ++c) s = fmaf(xi[t][c], xi[t][c], s);
    sqi[t] = s;
  }
  __syncthreads();
  const int il = t >> 4, jl = t & 15;
  float bd[4][5];
  int bj[4][5];
  #pragma unroll
  for (int ii = 0; ii < 4; ++ii) {
    #pragma unroll
    for (int s = 0; s < 5; ++s) { bd[ii][s] = FINF; bj[ii][s] = 0x7fffffff; }
  }
  float si[4];
  #pragma unroll
  for (int ii = 0; ii < 4; ++ii) si[ii] = sqi[il*4 + ii];

  for (int jt = 0; jt < 16; ++jt) {
    __syncthreads();
    for (int idx = t; idx < 64*64; idx += 256) {
      int r = idx >> 6, c = idx & 63;
      xj[r][c] = x1[((size_t)b*NP + jt*64 + r)*64 + c];
    }
    __syncthreads();
    if (t < 64) {
      float s = 0.f;
      #pragma unroll
      for (int c = 0; c < 64; ++c) s = fmaf(xj[t][c], xj[t][c], s);
      sqj[t] = s;
    }
    __syncthreads();
    float acc[4][4];
    #pragma unroll
    for (int ii = 0; ii < 4; ++ii) {
      #pragma unroll
      for (int jj = 0; jj < 4; ++jj) acc[ii][jj] = 0.f;
    }
    for (int cin = 0; cin < 64; cin += 4) {
      float4 fi[4], fj[4];
      #pragma unroll
      for (int ii = 0; ii < 4; ++ii) fi[ii] = *(const float4*)&xi[il*4+ii][cin];
      #pragma unroll
      for (int jj = 0; jj < 4; ++jj) fj[jj] = *(const float4*)&xj[jl + 16*jj][cin];
      #pragma unroll
      for (int q = 0; q < 4; ++q) {
        #pragma unroll
        for (int ii = 0; ii < 4; ++ii) {
          float f = f4c(fi[ii], q);
          acc[ii][0] = fmaf(f, f4c(fj[0],q), acc[ii][0]);
          acc[ii][1] = fmaf(f, f4c(fj[1],q), acc[ii][1]);
          acc[ii][2] = fmaf(f, f4c(fj[2],q), acc[ii][2]);
          acc[ii][3] = fmaf(f, f4c(fj[3],q), acc[ii][3]);
        }
      }
    }
    #pragma unroll
    for (int jj = 0; jj < 4; ++jj) {
      int jloc = jl + 16*jj;
      int jg = jt*64 + jloc;
      float sj = sqj[jloc];
      #pragma unroll
      for (int ii = 0; ii < 4; ++ii) {
        float dd = fmaf(-2.f, acc[ii][jj], si[ii] + sj);
        if (lex_less(dd, jg, bd[ii][4], bj[ii][4])) {
          bool L0 = lex_less(dd,jg,bd[ii][0],bj[ii][0]);
          bool L1 = lex_less(dd,jg,bd[ii][1],bj[ii][1]);
          bool L2 = lex_less(dd,jg,bd[ii][2],bj[ii][2]);
          bool L3 = lex_less(dd,jg,bd[ii][3],bj[ii][3]);
          bd[ii][4] = L3 ? bd[ii][3] : dd;  bj[ii][4] = L3 ? bj[ii][3] : jg;
          bd[ii][3] = L3 ? (L2 ? bd[ii][2] : dd) : bd[ii][3];
          bj[ii][3] = L3 ? (L2 ? bj[ii][2] : jg) : bj[ii][3];
          bd[ii][2] = L2 ? (L1 ? bd[ii][1] : dd) : bd[ii][2];
          bj[ii][2] = L2 ? (L1 ? bj[ii][1] : jg) : bj[ii][2];
          bd[ii][1] = L1 ? (L0 ? bd[ii][0] : dd) : bd[ii][1];
          bj[ii][1] = L1 ? (L0 ? bj[ii][0] : jg) : bj[ii][1];
          bd[ii][0] = L0 ? dd : bd[ii][0];  bj[ii][0] = L0 ? jg : bj[ii][0];
        }
      }
    }
  }
  // merge sorted top-5 lists across the 16 j-lanes
  #pragma unroll
  for (int ii = 0; ii < 4; ++ii) {
    #pragma unroll
    for (int s = 0; s < 5; ++s) {
      float md = bd[ii][0]; int mj = bj[ii][0];
      #pragma unroll
      for (int off = 1; off <= 8; off <<= 1) {
        float od = __shfl_xor(md, off, 16);
        int oj = __shfl_xor(mj, off, 16);
        if (lex_less(od, oj, md, mj)) { md = od; mj = oj; }
      }
      if (md == bd[ii][0] && mj == bj[ii][0]) {
        bd[ii][0]=bd[ii][1]; bj[ii][0]=bj[ii][1];
        bd[ii][1]=bd[ii][2]; bj[ii][1]=bj[ii][2];
        bd[ii][2]=bd[ii][3]; bj[ii][2]=bj[ii][3];
        bd[ii][3]=bd[ii][4]; bj[ii][3]=bj[ii][4];
        bd[ii][4]=FINF; bj[ii][4]=0x7fffffff;
      }
      if (jl == 0) knn_idx[((size_t)b*NP + ibase + il*4 + ii)*KNN + s] = b*NP + mj;
    }
  }
}

// --------------------- EdgeConv2 (128 -> 128) fused with k-max/min + stats
__global__ __launch_bounds__(256) void ec2_kernel(const float* __restrict__ x1,
    const int* __restrict__ knn_idx, const float* __restrict__ W,
    const float* __restrict__ bias, float* __restrict__ x2max,
    float* __restrict__ x2min, double* __restrict__ psum, double* __restrict__ psq) {
  __shared__ float e2[40][128];
  __shared__ double redS[8][128];
  __shared__ double redQ[8][128];
  const int blk = blockIdx.x, t = threadIdx.x;
  const int pbase = blk * 8;
  for (int idx = t; idx < 40*128; idx += 256) {
    int r = idx >> 7, c = idx & 127;
    int p = pbase + r / KNN;
    int kk = r % KNN;
    int j = knn_idx[(size_t)p*KNN + kk];
    float v;
    if (c < 64) v = x1[(size_t)p*64 + c];
    else {
      int cc = c - 64;
      v = x1[(size_t)j*64 + cc] - x1[(size_t)p*64 + cc];
    }
    e2[r][c] = v;
  }
  __syncthreads();
  const int c4 = t & 31, rs = t >> 5;
  const int cbase = c4 * 4;
  float4 bv = *(const float4*)&bias[cbase];
  float acc[5][4];
  #pragma unroll
  for (int kk = 0; kk < 5; ++kk) {
    acc[kk][0]=bv.x; acc[kk][1]=bv.y; acc[kk][2]=bv.z; acc[kk][3]=bv.w;
  }
  for (int cin = 0; cin < 128; cin += 4) {
    float4 fi[5];
    #pragma unroll
    for (int kk = 0; kk < 5; ++kk) fi[kk] = *(const float4*)&e2[rs*5+kk][cin];
    #pragma unroll
    for (int q = 0; q < 4; ++q) {
      float4 wv = *(const float4*)&W[(size_t)(cin+q)*128 + cbase];
      #pragma unroll
      for (int kk = 0; kk < 5; ++kk) {
        float f = f4c(fi[kk], q);
        acc[kk][0] = fmaf(f, wv.x, acc[kk][0]);
        acc[kk][1] = fmaf(f, wv.y, acc[kk][1]);
        acc[kk][2] = fmaf(f, wv.z, acc[kk][2]);
        acc[kk][3] = fmaf(f, wv.w, acc[kk][3]);
      }
    }
  }
  float mx[4] = {-FINF,-FINF,-FINF,-FINF}, mn[4] = {FINF,FINF,FINF,FINF};
  double s[4] = {0,0,0,0}, ss[4] = {0,0,0,0};
  #pragma unroll
  for (int kk = 0; kk < 5; ++kk) {
    #pragma unroll
    for (int jj = 0; jj < 4; ++jj) {
      float h = fmaxf(acc[kk][jj], 0.f);
      mx[jj] = fmaxf(mx[jj], h); mn[jj] = fminf(mn[jj], h);
      s[jj] += h; ss[jj] += (double)h * h;
    }
  }
  *(float4*)&x2max[((size_t)pbase + rs)*128 + cbase] = make_float4(mx[0],mx[1],mx[2],mx[3]);
  *(float4*)&x2min[((size_t)pbase + rs)*128 + cbase] = make_float4(mn[0],mn[1],mn[2],mn[3]);
  #pragma unroll
  for (int jj = 0; jj < 4; ++jj) { redS[rs][cbase+jj] = s[jj]; redQ[rs][cbase+jj] = ss[jj]; }
  __syncthreads();
  if (t < 128) {
    double a = 0, q2 = 0;
    #pragma unroll
    for (int r = 0; r < 8; ++r) { a += redS[r][t]; q2 += redQ[r][t]; }
    psum[(size_t)blk*128 + t] = a;
    psq[(size_t)blk*128 + t] = q2;
  }
}

__global__ void ec2_fin_kernel(const float* __restrict__ x2max,
    const float* __restrict__ x2min, const float2* __restrict__ aff,
    float* __restrict__ x2) {
  int idx = blockIdx.x*256 + threadIdx.x;
  if (idx >= NPT*128) return;
  int c = idx & 127;
  float2 ac = aff[c];
  x2[idx] = (ac.x >= 0.f) ? fmaf(ac.x, x2max[idx], ac.y) : fmaf(ac.x, x2min[idx], ac.y);
}

// ------------- Lin1 (192 -> 1024) fused with ReLU + stats + per-batch max/min
__global__ __launch_bounds__(256) void lin1_kernel(const float* __restrict__ x1,
    const float* __restrict__ x2, const float* __restrict__ W,
    const float* __restrict__ bias, double* __restrict__ psum,
    double* __restrict__ psq, float* __restrict__ pmax, float* __restrict__ pmin) {
  __shared__ float fin[64][192];
  const int blk = blockIdx.x, t = threadIdx.x;
  const int pbase = blk * 64;
  for (int idx = t; idx < 64*192; idx += 256) {
    int r = idx / 192, c = idx % 192;
    int p = pbase + r;
    fin[r][c] = (c < 64) ? x1[(size_t)p*64 + c] : x2[(size_t)p*128 + (c - 64)];
  }
  __syncthreads();
  const int c0 = t * 4;
  float4 bv = *(const float4*)&bias[c0];
  double s[4] = {0,0,0,0}, ss[4] = {0,0,0,0};
  float mx[4] = {-FINF,-FINF,-FINF,-FINF}, mn[4] = {FINF,FINF,FINF,FINF};
  for (int pass = 0; pass < 4; ++pass) {
    const int rbase = pass * 16;
    float4 acc[16];
    #pragma unroll
    for (int rr = 0; rr < 16; ++rr) acc[rr] = bv;
    for (int cin = 0; cin < 192; cin += 4) {
      float4 wv0 = *(const float4*)&W[(size_t)(cin+0)*1024 + c0];
      float4 wv1 = *(const float4*)&W[(size_t)(cin+1)*1024 + c0];
      float4 wv2 = *(const float4*)&W[(size_t)(cin+2)*1024 + c0];
      float4 wv3 = *(const float4*)&W[(size_t)(cin+3)*1024 + c0];
      #pragma unroll
      for (int rr = 0; rr < 16; ++rr) {
        float4 f = *(const float4*)&fin[rbase+rr][cin];
        acc[rr].x = fmaf(f.x, wv0.x, acc[rr].x);
        acc[rr].y = fmaf(f.x, wv0.y, acc[rr].y);
        acc[rr].z = fmaf(f.x, wv0.z, acc[rr].z);
        acc[rr].w = fmaf(f.x, wv0.w, acc[rr].w);
        acc[rr].x = fmaf(f.y, wv1.x, acc[rr].x);
        acc[rr].y = fmaf(f.y, wv1.y, acc[rr].y);
        acc[rr].z = fmaf(f.y, wv1.z, acc[rr].z);
        acc[rr].w = fmaf(f.y, wv1.w, acc[rr].w);
        acc[rr].x = fmaf(f.z, wv2.x, acc[rr].x);
        acc[rr].y = fmaf(f.z, wv2.y, acc[rr].y);
        acc[rr].z = fmaf(f.z, wv2.z, acc[rr].z);
        acc[rr].w = fmaf(f.z, wv2.w, acc[rr].w);
        acc[rr].x = fmaf(f.w, wv3.x, acc[rr].x);
        acc[rr].y = fmaf(f.w, wv3.y, acc[rr].y);
        acc[rr].z = fmaf(f.w, wv3.z, acc[rr].z);
        acc[rr].w = fmaf(f.w, wv3.w, acc[rr].w);
      }
    }
    #pragma unroll
    for (int rr = 0; rr < 16; ++rr) {
      float h0 = fmaxf(acc[rr].x, 0.f), h1 = fmaxf(acc[rr].y, 0.f);
      float h2 = fmaxf(acc[rr].z, 0.f), h3 = fmaxf(acc[rr].w, 0.f);
      s[0]+=h0; ss[0]+=(double)h0*h0; mx[0]=fmaxf(mx[0],h0); mn[0]=fminf(mn[0],h0);
      s[1]+=h1; ss[1]+=(double)h1*h1; mx[1]=fmaxf(mx[1],h1); mn[1]=fminf(mn[1],h1);
      s[2]+=h2; ss[2]+=(double)h2*h2; mx[2]=fmaxf(mx[2],h2); mn[2]=fminf(mn[2],h2);
      s[3]+=h3; ss[3]+=(double)h3*h3; mx[3]=fmaxf(mx[3],h3); mn[3]=fminf(mn[3],h3);
    }
  }
  #pragma unroll
  for (int jj = 0; jj < 4; ++jj) {
    psum[(size_t)blk*1024 + c0 + jj] = s[jj];
    psq[(size_t)blk*1024 + c0 + jj] = ss[jj];
    pmax[(size_t)blk*1024 + c0 + jj] = mx[jj];
    pmin[(size_t)blk*1024 + c0 + jj] = mn[jj];
  }
}

// ----------------- lin1 BN+maxpool finalize (block per channel, R2)
__global__ __launch_bounds__(256) void lin1_fin_kernel(const double* __restrict__ psum,
    const double* __restrict__ psq, const float* __restrict__ pmax,
    const float* __restrict__ pmin, const float* __restrict__ g,
    const float* __restrict__ be, float* __restrict__ y) {
  __shared__ double rs[256];
  __shared__ double rq[256];
  __shared__ float smx[32][8];
  __shared__ float smn[32][8];
  __shared__ float sa[2];
  const int c = blockIdx.x;          // grid = 1024
  const int t = threadIdx.x;
  double s = 0.0, ss = 0.0;
  for (int i = t; i < 512; i += 256) {
    s  += psum[(size_t)i*1024 + c];
    ss += psq [(size_t)i*1024 + c];
  }
  rs[t] = s; rq[t] = ss; __syncthreads();
  for (int off = 128; off > 0; off >>= 1) {
    if (t < off) { rs[t] += rs[t+off]; rq[t] += rq[t+off]; }
    __syncthreads();
  }
  if (t == 0) {
    double mean = rs[0] / 32768.0;
    double var = rq[0] / 32768.0 - mean*mean;
    var = var < 0.0 ? 0.0 : var;
    double inv = 1.0 / sqrt(var + 1e-5);
    sa[0] = (float)((double)g[c] * inv);
    sa[1] = (float)((double)be[c] - (double)g[c]*mean*inv);
  }
  // per-batch max/min over 16 partials: t = b*8 + q, q handles i=2q,2q+1
  {
    int b = t >> 3, q = t & 7;
    float m0 = pmax[(size_t)(b*16 + 2*q    )*1024 + c];
    float m1 = pmax[(size_t)(b*16 + 2*q + 1)*1024 + c];
    float n0 = pmin[(size_t)(b*16 + 2*q    )*1024 + c];
    float n1 = pmin[(size_t)(b*16 + 2*q + 1)*1024 + c];
    smx[b][q] = fmaxf(m0, m1);
    smn[b][q] = fminf(n0, n1);
  }
  __syncthreads();
  if (t < 32) {
    float mxv = -FINF, mnv = FINF;
    #pragma unroll
    for (int q = 0; q < 8; ++q) { mxv = fmaxf(mxv, smx[t][q]); mnv = fminf(mnv, smn[t][q]); }
    float a = sa[0], off2 = sa[1];
    y[(size_t)t*1024 + c] = (a >= 0.f) ? fmaf(a, mxv, off2) : fmaf(a, mnv, off2);
  }
}

// ---------------------------------------------------------------- head MLP
__global__ void head1_kernel(const float* __restrict__ y, const float* __restrict__ W,
    const float* __restrict__ bias, float* __restrict__ h5) {
  int idx = blockIdx.x*256 + threadIdx.x;   // 32*512
  int r = idx >> 9, c = idx & 511;
  float acc = bias[c];
  for (int cin = 0; cin < 1024; ++cin)
    acc = fmaf(y[(size_t)r*1024 + cin], W[(size_t)cin*512 + c], acc);
  h5[idx] = fmaxf(acc, 0.f);
}

__global__ void bn_rows_kernel(const float* __restrict__ h, int C, int R,
    const float* __restrict__ g, const float* __restrict__ be, float2* __restrict__ aff) {
  int c = blockIdx.x*256 + threadIdx.x;
  if (c >= C) return;
  double s = 0, ss = 0;
  for (int r = 0; r < R; ++r) {
    double v = (double)h[(size_t)r*C + c];
    s += v; ss += v*v;
  }
  double mean = s / (double)R;
  double var = ss / (double)R - mean*mean;
  var = var < 0.0 ? 0.0 : var;
  double inv = 1.0 / sqrt(var + 1e-5);
  float a = (float)((double)g[c] * inv);
  float off = (float)((double)be[c] - (double)g[c]*mean*inv);
  aff[c] = make_float2(a, off);
}

__global__ void head2_kernel(const float* __restrict__ h5, const float2* __restrict__ aff,
    const float* __restrict__ W, const float* __restrict__ bias, float* __restrict__ h6) {
  int idx = blockIdx.x*256 + threadIdx.x;   // 32*256
  int r = idx >> 8, c = idx & 255;
  float acc = bias[c];
  for (int cin = 0; cin < 512; ++cin) {
    float2 a = aff[cin];
    acc = fmaf(fmaf(a.x, h5[(size_t)r*512 + cin], a.y), W[(size_t)cin*256 + c], acc);
  }
  h6[idx] = fmaxf(acc, 0.f);
}

__global__ void head3_kernel(const float* __restrict__ h6, const float2* __restrict__ aff,
    const float* __restrict__ W, const float* __restrict__ bias, float* __restrict__ out) {
  int t = threadIdx.x;
  if (t >= 64) return;
  int r = t >> 1, c = t & 1;
  float acc = bias[c];
  for (int cin = 0; cin < 256; ++cin) {
    float2 a = aff[cin];
    acc = fmaf(fmaf(a.x, h6[(size_t)r*256 + cin], a.y), W[(size_t)cin*2 + c], acc);
  }
  out[(size_t)r*2 + c] = acc;
}

// ------------------------------------------------------------------ launcher
extern "C" void kernel_launch(void* const* d_in, const int* in_sizes, int n_in,
                              void* d_out, int out_size, void* d_ws, size_t ws_size,
                              hipStream_t stream) {
  (void)in_sizes; (void)n_in; (void)out_size; (void)ws_size;
  const float* pos    = (const float*)d_in[0];
  const float* c1_w1  = (const float*)d_in[2];
  const float* c1_b1  = (const float*)d_in[3];
  const float* c1_g1  = (const float*)d_in[4];
  const float* c1_be1 = (const float*)d_in[5];
  const float* c1_w2  = (const float*)d_in[6];
  const float* c1_b2  = (const float*)d_in[7];
  const float* c1_g2  = (const float*)d_in[8];
  const float* c1_be2 = (const float*)d_in[9];
  const float* c1_w3  = (const float*)d_in[10];
  const float* c1_b3  = (const float*)d_in[11];
  const float* c1_g3  = (const float*)d_in[12];
  const float* c1_be3 = (const float*)d_in[13];
  const float* c2_w1  = (const float*)d_in[14];
  const float* c2_b1  = (const float*)d_in[15];
  const float* c2_g1  = (const float*)d_in[16];
  const float* c2_be1 = (const float*)d_in[17];
  const float* l1_w   = (const float*)d_in[18];
  const float* l1_b   = (const float*)d_in[19];
  const float* l1_g   = (const float*)d_in[20];
  const float* l1_be  = (const float*)d_in[21];
  const float* m1_w   = (const float*)d_in[22];
  const float* m1_b   = (const float*)d_in[23];
  const float* m1_g   = (const float*)d_in[24];
  const float* m1_be  = (const float*)d_in[25];
  const float* m2_w   = (const float*)d_in[26];
  const float* m2_b   = (const float*)d_in[27];
  const float* m2_g   = (const float*)d_in[28];
  const float* m2_be  = (const float*)d_in[29];
  const float* m3_w   = (const float*)d_in[30];
  const float* m3_b   = (const float*)d_in[31];

  char* ws = (char*)d_ws;
  size_t off = 0;
  auto alloc = [&](size_t bytes) -> void* {
    void* p = ws + off;
    off += (bytes + 255) & ~(size_t)255;
    return p;
  };
  int*    idx1 = (int*)alloc((size_t)NE * 4);
  int*    idx2 = (int*)alloc((size_t)NE * 4);
  float*  x1   = (float*)alloc((size_t)NPT * 64 * 4);
  float*  x2   = (float*)alloc((size_t)NPT * 128 * 4);
  float*  hA   = (float*)alloc((size_t)NE * 64 * 4);
  float*  hB   = (float*)alloc((size_t)NE * 64 * 4);
  double* psum = (double*)alloc((size_t)524288 * 8);
  double* psq  = (double*)alloc((size_t)524288 * 8);
  float*  pmax = (float*)alloc((size_t)524288 * 4);
  float*  pmin = (float*)alloc((size_t)524288 * 4);
  float2* affA = (float2*)alloc(64 * 8);
  float2* affB = (float2*)alloc(64 * 8);
  float2* affC = (float2*)alloc(64 * 8);
  float2* aff2 = (float2*)alloc(128 * 8);
  float2* affM1 = (float2*)alloc(512 * 8);
  float2* affM2 = (float2*)alloc(256 * 8);
  float*  y    = (float*)alloc((size_t)NB * 1024 * 4);
  float*  h5   = (float*)alloc((size_t)NB * 512 * 4);
  float*  h6   = (float*)alloc((size_t)NB * 256 * 4);
  // x2max/x2min reuse hA (h3 dead by then): 2 * 16.78MB <= 41.9MB
  float* x2max = hA;
  float* x2min = hA + (size_t)NPT * 128;

  // 1. knn on positions
  knn1_kernel<<<dim3(NB*4), dim3(256), 0, stream>>>(pos, idx1);
  // 2. EdgeConv1 layer1
  ec1_l1_kernel<<<dim3(NE/64), dim3(256), 0, stream>>>(pos, idx1, c1_w1, c1_b1, hA, psum, psq);
  stats_reduce_kernel<<<dim3(64), dim3(256), 0, stream>>>(psum, psq, NE/64, 64, 1.0/NE, c1_g1, c1_be1, affA);
  // 3. layer2
  ec_l64_kernel<<<dim3(NE/64), dim3(256), 0, stream>>>(hA, affA, c1_w2, c1_b2, hB, psum, psq);
  stats_reduce_kernel<<<dim3(64), dim3(256), 0, stream>>>(psum, psq, NE/64, 64, 1.0/NE, c1_g2, c1_be2, affB);
  // 4. layer3
  ec_l64_kernel<<<dim3(NE/64), dim3(256), 0, stream>>>(hB, affB, c1_w3, c1_b3, hA, psum, psq);
  stats_reduce_kernel<<<dim3(64), dim3(256), 0, stream>>>(psum, psq, NE/64, 64, 1.0/NE, c1_g3, c1_be3, affC);
  // 5. max over k -> x1
  ec1_reduce_kernel<<<dim3(NPT*64/256), dim3(256), 0, stream>>>(hA, affC, x1);
  // 6. knn on features
  knn2_kernel<<<dim3(NB*16), dim3(256), 0, stream>>>(x1, idx2);
  // 7. EdgeConv2 (fused k-max/min)
  ec2_kernel<<<dim3(NPT/8), dim3(256), 0, stream>>>(x1, idx2, c2_w1, c2_b1, x2max, x2min, psum, psq);
  stats_reduce_kernel<<<dim3(128), dim3(256), 0, stream>>>(psum, psq, NPT/8, 128, 1.0/NE, c2_g1, c2_be1, aff2);
  ec2_fin_kernel<<<dim3(NPT*128/256), dim3(256), 0, stream>>>(x2max, x2min, aff2, x2);
  // 8. Lin1 fused (no materialization of [32768,1024])
  lin1_kernel<<<dim3(NPT/64), dim3(256), 0, stream>>>(x1, x2, l1_w, l1_b, psum, psq, pmax, pmin);
  lin1_fin_kernel<<<dim3(1024), dim3(256), 0, stream>>>(psum, psq, pmax, pmin, l1_g, l1_be, y);
  // 9. head
  head1_kernel<<<dim3(64), dim3(256), 0, stream>>>(y, m1_w, m1_b, h5);
  bn_rows_kernel<<<dim3(2), dim3(256), 0, stream>>>(h5, 512, NB, m1_g, m1_be, affM1);
  head2_kernel<<<dim3(32), dim3(256), 0, stream>>>(h5, affM1, m2_w, m2_b, h6);
  bn_rows_kernel<<<dim3(1), dim3(256), 0, stream>>>(h6, 256, NB, m2_g, m2_be, affM2);
  head3_kernel<<<dim3(1), dim3(64), 0, stream>>>(h6, affM2, m3_w, m3_b, (float*)d_out);
}

// Round 3
// 854.251 us; speedup vs baseline: 5.4474x; 1.8449x over previous
//
#include <hip/hip_runtime.h>

// DGCNN forward: knn(3d) -> EdgeConv(6->64->64->64,BN) -> knn(64d) ->
// EdgeConv(128->128,BN) -> Lin(192->1024)+BN+maxpool -> head MLP -> [32,2]
// R2: stats reductions parallelized (block-per-channel).
// R3: knn2 restructured — old version spilled ~490MB/dispatch to scratch
// (VGPR=256 cap, WRITE_SIZE 478MB, HBM-bound at 586GB/s). New version:
// GEMM tile -> LDS distance tile -> per-ROW selection (10 persistent
// scalars/thread, no indexed arrays) + width-4 shuffle merge.

#define NB 32
#define NP 1024
#define NPT 32768       // NB*NP
#define KNN 5
#define NE 163840       // NPT*KNN

#define FINF 3.402823466e+38f

__device__ __forceinline__ bool lex_less(float da, int ja, float db, int jb) {
  return (da < db) || (da == db && ja < jb);
}

__device__ __forceinline__ float f4c(const float4& v, int q) {
  return q == 0 ? v.x : (q == 1 ? v.y : (q == 2 ? v.z : v.w));
}

// insert (dd,jj) into sorted-ascending 5-list held as named scalars
__device__ __forceinline__ void insert5(float& d0, float& d1, float& d2, float& d3, float& d4,
                                        int& j0, int& j1, int& j2, int& j3, int& j4,
                                        float dd, int jj) {
  if (lex_less(dd, jj, d4, j4)) {
    bool L0 = lex_less(dd,jj,d0,j0), L1 = lex_less(dd,jj,d1,j1),
         L2 = lex_less(dd,jj,d2,j2), L3 = lex_less(dd,jj,d3,j3);
    d4 = L3 ? d3 : dd;              j4 = L3 ? j3 : jj;
    d3 = L3 ? (L2 ? d2 : dd) : d3;  j3 = L3 ? (L2 ? j2 : jj) : j3;
    d2 = L2 ? (L1 ? d1 : dd) : d2;  j2 = L2 ? (L1 ? j1 : jj) : j2;
    d1 = L1 ? (L0 ? d0 : dd) : d1;  j1 = L1 ? (L0 ? j0 : jj) : j1;
    d0 = L0 ? dd : d0;              j0 = L0 ? jj : j0;
  }
}

// ---------------------------------------------------------------- knn (3-d)
__global__ __launch_bounds__(256) void knn1_kernel(const float* __restrict__ pos,
                                                   int* __restrict__ knn_idx) {
  __shared__ float xs[NP * 3];
  __shared__ float sq[NP];
  const int b = blockIdx.x >> 2;
  const int qtr = blockIdx.x & 3;
  const int t = threadIdx.x;
  for (int i = t; i < NP * 3; i += 256) xs[i] = pos[(size_t)b * NP * 3 + i];
  __syncthreads();
  for (int i = t; i < NP; i += 256) {
    float x0 = xs[i*3+0], x1 = xs[i*3+1], x2 = xs[i*3+2];
    sq[i] = __fadd_rn(__fadd_rn(__fmul_rn(x0,x0), __fmul_rn(x1,x1)), __fmul_rn(x2,x2));
  }
  __syncthreads();
  const int i = qtr * 256 + t;
  const float xi0 = xs[i*3+0], xi1 = xs[i*3+1], xi2 = xs[i*3+2];
  const float sqi = sq[i];
  float d0=FINF,d1=FINF,d2=FINF,d3=FINF,d4=FINF;
  int j0=0x7fffffff,j1=0x7fffffff,j2=0x7fffffff,j3=0x7fffffff,j4=0x7fffffff;
  for (int j = 0; j < NP; ++j) {
    float y0 = xs[j*3+0], y1 = xs[j*3+1], y2 = xs[j*3+2];
    float dot = __fadd_rn(__fadd_rn(__fmul_rn(xi0,y0), __fmul_rn(xi1,y1)), __fmul_rn(xi2,y2));
    float dd = __fsub_rn(__fadd_rn(sqi, sq[j]), __fmul_rn(2.0f, dot));
    insert5(d0,d1,d2,d3,d4, j0,j1,j2,j3,j4, dd, j);
  }
  const size_t row = (size_t)b * NP + i;
  knn_idx[row*KNN+0] = b*NP + j0;
  knn_idx[row*KNN+1] = b*NP + j1;
  knn_idx[row*KNN+2] = b*NP + j2;
  knn_idx[row*KNN+3] = b*NP + j3;
  knn_idx[row*KNN+4] = b*NP + j4;
}

// ------------------------------------------- EdgeConv1 layer1 (6 -> 64) + stats
__global__ __launch_bounds__(256) void ec1_l1_kernel(const float* __restrict__ pos,
    const int* __restrict__ knn_idx, const float* __restrict__ W,
    const float* __restrict__ bias, float* __restrict__ hout,
    double* __restrict__ psum, double* __restrict__ psq) {
  __shared__ float ef[64][6];
  __shared__ float Wl[6][64];
  __shared__ float bl[64];
  __shared__ double red[256];
  const int blk = blockIdx.x, t = threadIdx.x;
  const int ebase = blk * 64;
  if (t < 64) {
    int e = ebase + t;
    int ip = e / KNN;
    int jp = knn_idx[e];
    float a0 = pos[(size_t)ip*3+0], a1 = pos[(size_t)ip*3+1], a2 = pos[(size_t)ip*3+2];
    float c0 = pos[(size_t)jp*3+0], c1 = pos[(size_t)jp*3+1], c2 = pos[(size_t)jp*3+2];
    ef[t][0] = a0; ef[t][1] = a1; ef[t][2] = a2;
    ef[t][3] = c0 - a0; ef[t][4] = c1 - a1; ef[t][5] = c2 - a2;
    bl[t] = bias[t];
  }
  for (int idx = t; idx < 6*64; idx += 256) Wl[idx>>6][idx&63] = W[idx];
  __syncthreads();
  const int c = t & 63, rs = t >> 6;
  double s = 0.0, ss = 0.0;
  for (int r = rs; r < 64; r += 4) {
    float acc = bl[c];
    #pragma unroll
    for (int q = 0; q < 6; ++q) acc = fmaf(ef[r][q], Wl[q][c], acc);
    acc = fmaxf(acc, 0.0f);
    hout[(size_t)(ebase + r)*64 + c] = acc;
    s += acc; ss += (double)acc * (double)acc;
  }
  red[t] = s; __syncthreads();
  if (t < 64) psum[(size_t)blk*64 + t] = red[t] + red[t+64] + red[t+128] + red[t+192];
  __syncthreads();
  red[t] = ss; __syncthreads();
  if (t < 64) psq[(size_t)blk*64 + t] = red[t] + red[t+64] + red[t+128] + red[t+192];
}

// ------------------- BN stats -> per-channel affine (block per channel)
__global__ __launch_bounds__(256) void stats_reduce_kernel(const double* __restrict__ psum,
    const double* __restrict__ psq, int nblk, int C, double invN,
    const float* __restrict__ g, const float* __restrict__ be,
    float2* __restrict__ aff) {
  __shared__ double rs[256];
  __shared__ double rq[256];
  const int c = blockIdx.x;          // grid = C
  const int t = threadIdx.x;
  double s = 0.0, ss = 0.0;
  for (int i = t; i < nblk; i += 256) {
    s  += psum[(size_t)i*C + c];
    ss += psq [(size_t)i*C + c];
  }
  rs[t] = s; rq[t] = ss; __syncthreads();
  for (int off = 128; off > 0; off >>= 1) {
    if (t < off) { rs[t] += rs[t+off]; rq[t] += rq[t+off]; }
    __syncthreads();
  }
  if (t == 0) {
    double mean = rs[0] * invN;
    double var = rq[0] * invN - mean*mean;
    var = var < 0.0 ? 0.0 : var;
    double inv = 1.0 / sqrt(var + 1e-5);
    float a = (float)((double)g[c] * inv);
    float off2 = (float)((double)be[c] - (double)g[c] * mean * inv);
    aff[c] = make_float2(a, off2);
  }
}

// -------------------------------- EdgeConv1 layers 2/3 (64 -> 64) + stats
__global__ __launch_bounds__(256) void ec_l64_kernel(const float* __restrict__ hin,
    const float2* __restrict__ affprev, const float* __restrict__ W,
    const float* __restrict__ bias, float* __restrict__ hout,
    double* __restrict__ psum, double* __restrict__ psq) {
  __shared__ float ein[64][68];
  __shared__ float Wl[64][64];
  __shared__ float2 affl[64];
  __shared__ float bl[64];
  __shared__ double redS[16][64];
  __shared__ double redQ[16][64];
  const int blk = blockIdx.x, t = threadIdx.x;
  const size_t ebase = (size_t)blk * 64;
  if (t < 64) { affl[t] = affprev[t]; bl[t] = bias[t]; }
  __syncthreads();
  for (int idx = t; idx < 64*64; idx += 256) {
    int r = idx >> 6, c = idx & 63;
    float2 ac = affl[c];
    ein[r][c] = fmaf(hin[ebase*64 + idx], ac.x, ac.y);
    Wl[r][c] = W[idx];
  }
  __syncthreads();
  const int c4 = t & 15, rs = t >> 4;
  const int cbase = c4 * 4;
  const int rbase = rs * 4;
  float acc[4][4];
  #pragma unroll
  for (int ii = 0; ii < 4; ++ii) {
    #pragma unroll
    for (int jj = 0; jj < 4; ++jj) acc[ii][jj] = bl[cbase + jj];
  }
  for (int cin = 0; cin < 64; cin += 4) {
    float4 fi[4];
    #pragma unroll
    for (int ii = 0; ii < 4; ++ii) fi[ii] = *(const float4*)&ein[rbase+ii][cin];
    #pragma unroll
    for (int q = 0; q < 4; ++q) {
      float4 wv = *(const float4*)&Wl[cin+q][cbase];
      #pragma unroll
      for (int ii = 0; ii < 4; ++ii) {
        float f = f4c(fi[ii], q);
        acc[ii][0] = fmaf(f, wv.x, acc[ii][0]);
        acc[ii][1] = fmaf(f, wv.y, acc[ii][1]);
        acc[ii][2] = fmaf(f, wv.z, acc[ii][2]);
        acc[ii][3] = fmaf(f, wv.w, acc[ii][3]);
      }
    }
  }
  double s[4] = {0,0,0,0}, ss[4] = {0,0,0,0};
  #pragma unroll
  for (int ii = 0; ii < 4; ++ii) {
    float4 h;
    h.x = fmaxf(acc[ii][0], 0.f); h.y = fmaxf(acc[ii][1], 0.f);
    h.z = fmaxf(acc[ii][2], 0.f); h.w = fmaxf(acc[ii][3], 0.f);
    *(float4*)&hout[(ebase + rbase + ii)*64 + cbase] = h;
    s[0]+=h.x; s[1]+=h.y; s[2]+=h.z; s[3]+=h.w;
    ss[0]+=(double)h.x*h.x; ss[1]+=(double)h.y*h.y;
    ss[2]+=(double)h.z*h.z; ss[3]+=(double)h.w*h.w;
  }
  #pragma unroll
  for (int jj = 0; jj < 4; ++jj) { redS[rs][cbase+jj] = s[jj]; redQ[rs][cbase+jj] = ss[jj]; }
  __syncthreads();
  if (t < 64) {
    double a = 0, bq = 0;
    #pragma unroll
    for (int r = 0; r < 16; ++r) { a += redS[r][t]; bq += redQ[r][t]; }
    psum[(size_t)blk*64 + t] = a;
    psq[(size_t)blk*64 + t] = bq;
  }
}

// ------------------------------------ max over k with BN affine (monotone)
__global__ void ec1_reduce_kernel(const float* __restrict__ h3,
    const float2* __restrict__ aff, float* __restrict__ x1) {
  int idx = blockIdx.x * 256 + threadIdx.x;
  if (idx >= NPT * 64) return;
  int p = idx >> 6, c = idx & 63;
  float mx = -FINF, mn = FINF;
  #pragma unroll
  for (int kk = 0; kk < KNN; ++kk) {
    float v = h3[((size_t)p*KNN + kk)*64 + c];
    mx = fmaxf(mx, v); mn = fminf(mn, v);
  }
  float2 ac = aff[c];
  x1[idx] = (ac.x >= 0.f) ? fmaf(ac.x, mx, ac.y) : fmaf(ac.x, mn, ac.y);
}

// ---------------------------------------------------------------- knn (64-d)
// R3 structure: per 64-row i-tile, loop 16 j-tiles:
//   GEMM 4x4/thread -> dd into LDS d2t (aliases xj) -> per-ROW top-5
//   (one row per thread, 10 named scalars) -> width-4 shuffle merge.
__global__ __launch_bounds__(256) void knn2_kernel(const float* __restrict__ x1,
                                                   int* __restrict__ knn_idx) {
  __shared__ float xi[64][68];
  __shared__ float xjd[64][68];   // xj tile, then reused as distance tile
  __shared__ float sqi[64];
  __shared__ float sqj[64];
  const int b = blockIdx.x >> 4;
  const int it = blockIdx.x & 15;
  const int t = threadIdx.x;
  const int ibase = it * 64;  // within batch

  // stage xi tile (float4)
  {
    int r = t >> 4, c4 = (t & 15) * 4;
    #pragma unroll
    for (int rr = 0; rr < 4; ++rr) {
      float4 v = *(const float4*)&x1[((size_t)b*NP + ibase + r + 16*rr)*64 + c4];
      *(float4*)&xi[r + 16*rr][c4] = v;
    }
  }
  __syncthreads();
  if (t < 64) {
    float s = 0.f;
    #pragma unroll
    for (int c = 0; c < 64; ++c) s = fmaf(xi[t][c], xi[t][c], s);
    sqi[t] = s;
  }
  __syncthreads();

  const int il = t >> 4, jl = t & 15;      // GEMM mapping: rows il*4.., cols jl+16*jj
  const int row = t >> 2, ql = t & 3;      // selection mapping: 1 row, 16 j's per lane
  float si[4];
  #pragma unroll
  for (int ii = 0; ii < 4; ++ii) si[ii] = sqi[il*4 + ii];

  // persistent top-5 for THIS thread's row (named scalars -> registers)
  float d0=FINF,d1=FINF,d2=FINF,d3=FINF,d4=FINF;
  int j0=0x7fffffff,j1=0x7fffffff,j2=0x7fffffff,j3=0x7fffffff,j4=0x7fffffff;

  for (int jt = 0; jt < 16; ++jt) {
    __syncthreads();   // previous selection reads done before overwriting xjd
    {
      int r = t >> 4, c4 = (t & 15) * 4;
      #pragma unroll
      for (int rr = 0; rr < 4; ++rr) {
        float4 v = *(const float4*)&x1[((size_t)b*NP + jt*64 + r + 16*rr)*64 + c4];
        *(float4*)&xjd[r + 16*rr][c4] = v;
      }
    }
    __syncthreads();
    if (t < 64) {
      float s = 0.f;
      #pragma unroll
      for (int c = 0; c < 64; ++c) s = fmaf(xjd[t][c], xjd[t][c], s);
      sqj[t] = s;
    }
    __syncthreads();
    float acc[4][4];
    #pragma unroll
    for (int ii = 0; ii < 4; ++ii) {
      #pragma unroll
      for (int jj = 0; jj < 4; ++jj) acc[ii][jj] = 0.f;
    }
    for (int cin = 0; cin < 64; cin += 4) {
      float4 fi[4], fj[4];
      #pragma unroll
      for (int ii = 0; ii < 4; ++ii) fi[ii] = *(const float4*)&xi[il*4+ii][cin];
      #pragma unroll
      for (int jj = 0; jj < 4; ++jj) fj[jj] = *(const float4*)&xjd[jl + 16*jj][cin];
      #pragma unroll
      for (int q = 0; q < 4; ++q) {
        #pragma unroll
        for (int ii = 0; ii < 4; ++ii) {
          float f = f4c(fi[ii], q);
          acc[ii][0] = fmaf(f, f4c(fj[0],q), acc[ii][0]);
          acc[ii][1] = fmaf(f, f4c(fj[1],q), acc[ii][1]);
          acc[ii][2] = fmaf(f, f4c(fj[2],q), acc[ii][2]);
          acc[ii][3] = fmaf(f, f4c(fj[3],q), acc[ii][3]);
        }
      }
    }
    // stash sqj values needed before xjd is overwritten with distances
    float sjv[4];
    #pragma unroll
    for (int jj = 0; jj < 4; ++jj) sjv[jj] = sqj[jl + 16*jj];
    __syncthreads();   // everyone done reading xjd as features
    #pragma unroll
    for (int ii = 0; ii < 4; ++ii) {
      #pragma unroll
      for (int jj = 0; jj < 4; ++jj) {
        xjd[il*4+ii][jl + 16*jj] = fmaf(-2.f, acc[ii][jj], si[ii] + sjv[jj]);
      }
    }
    __syncthreads();
    // selection: this thread's row, columns ql*16 .. ql*16+15 (ascending j)
    const int jgbase = jt*64 + ql*16;
    #pragma unroll
    for (int kk = 0; kk < 4; ++kk) {
      float4 v = *(const float4*)&xjd[row][ql*16 + 4*kk];
      insert5(d0,d1,d2,d3,d4, j0,j1,j2,j3,j4, v.x, jgbase + 4*kk + 0);
      insert5(d0,d1,d2,d3,d4, j0,j1,j2,j3,j4, v.y, jgbase + 4*kk + 1);
      insert5(d0,d1,d2,d3,d4, j0,j1,j2,j3,j4, v.z, jgbase + 4*kk + 2);
      insert5(d0,d1,d2,d3,d4, j0,j1,j2,j3,j4, v.w, jgbase + 4*kk + 3);
    }
  }

  // merge sorted-5 lists across the 4 lanes of each row (width-4 butterfly)
  #pragma unroll
  for (int m = 1; m <= 2; m <<= 1) {
    float e0 = __shfl_xor(d0, m, 4), e1 = __shfl_xor(d1, m, 4),
          e2 = __shfl_xor(d2, m, 4), e3 = __shfl_xor(d3, m, 4),
          e4 = __shfl_xor(d4, m, 4);
    int   k0 = __shfl_xor(j0, m, 4), k1 = __shfl_xor(j1, m, 4),
          k2 = __shfl_xor(j2, m, 4), k3 = __shfl_xor(j3, m, 4),
          k4 = __shfl_xor(j4, m, 4);
    insert5(d0,d1,d2,d3,d4, j0,j1,j2,j3,j4, e0, k0);
    insert5(d0,d1,d2,d3,d4, j0,j1,j2,j3,j4, e1, k1);
    insert5(d0,d1,d2,d3,d4, j0,j1,j2,j3,j4, e2, k2);
    insert5(d0,d1,d2,d3,d4, j0,j1,j2,j3,j4, e3, k3);
    insert5(d0,d1,d2,d3,d4, j0,j1,j2,j3,j4, e4, k4);
  }
  if (ql == 0) {
    const size_t orow = ((size_t)b*NP + ibase + row) * KNN;
    knn_idx[orow+0] = b*NP + j0;
    knn_idx[orow+1] = b*NP + j1;
    knn_idx[orow+2] = b*NP + j2;
    knn_idx[orow+3] = b*NP + j3;
    knn_idx[orow+4] = b*NP + j4;
  }
}

// --------------------- EdgeConv2 (128 -> 128) fused with k-max/min + stats
__global__ __launch_bounds__(256) void ec2_kernel(const float* __restrict__ x1,
    const int* __restrict__ knn_idx, const float* __restrict__ W,
    const float* __restrict__ bias, float* __restrict__ x2max,
    float* __restrict__ x2min, double* __restrict__ psum, double* __restrict__ psq) {
  __shared__ float e2[40][128];
  __shared__ double redS[8][128];
  __shared__ double redQ[8][128];
  const int blk = blockIdx.x, t = threadIdx.x;
  const int pbase = blk * 8;
  for (int idx = t; idx < 40*128; idx += 256) {
    int r = idx >> 7, c = idx & 127;
    int p = pbase + r / KNN;
    int kk = r % KNN;
    int j = knn_idx[(size_t)p*KNN + kk];
    float v;
    if (c < 64) v = x1[(size_t)p*64 + c];
    else {
      int cc = c - 64;
      v = x1[(size_t)j*64 + cc] - x1[(size_t)p*64 + cc];
    }
    e2[r][c] = v;
  }
  __syncthreads();
  const int c4 = t & 31, rs = t >> 5;
  const int cbase = c4 * 4;
  float4 bv = *(const float4*)&bias[cbase];
  float acc[5][4];
  #pragma unroll
  for (int kk = 0; kk < 5; ++kk) {
    acc[kk][0]=bv.x; acc[kk][1]=bv.y; acc[kk][2]=bv.z; acc[kk][3]=bv.w;
  }
  for (int cin = 0; cin < 128; cin += 4) {
    float4 fi[5];
    #pragma unroll
    for (int kk = 0; kk < 5; ++kk) fi[kk] = *(const float4*)&e2[rs*5+kk][cin];
    #pragma unroll
    for (int q = 0; q < 4; ++q) {
      float4 wv = *(const float4*)&W[(size_t)(cin+q)*128 + cbase];
      #pragma unroll
      for (int kk = 0; kk < 5; ++kk) {
        float f = f4c(fi[kk], q);
        acc[kk][0] = fmaf(f, wv.x, acc[kk][0]);
        acc[kk][1] = fmaf(f, wv.y, acc[kk][1]);
        acc[kk][2] = fmaf(f, wv.z, acc[kk][2]);
        acc[kk][3] = fmaf(f, wv.w, acc[kk][3]);
      }
    }
  }
  float mx[4] = {-FINF,-FINF,-FINF,-FINF}, mn[4] = {FINF,FINF,FINF,FINF};
  double s[4] = {0,0,0,0}, ss[4] = {0,0,0,0};
  #pragma unroll
  for (int kk = 0; kk < 5; ++kk) {
    #pragma unroll
    for (int jj = 0; jj < 4; ++jj) {
      float h = fmaxf(acc[kk][jj], 0.f);
      mx[jj] = fmaxf(mx[jj], h); mn[jj] = fminf(mn[jj], h);
      s[jj] += h; ss[jj] += (double)h * h;
    }
  }
  *(float4*)&x2max[((size_t)pbase + rs)*128 + cbase] = make_float4(mx[0],mx[1],mx[2],mx[3]);
  *(float4*)&x2min[((size_t)pbase + rs)*128 + cbase] = make_float4(mn[0],mn[1],mn[2],mn[3]);
  #pragma unroll
  for (int jj = 0; jj < 4; ++jj) { redS[rs][cbase+jj] = s[jj]; redQ[rs][cbase+jj] = ss[jj]; }
  __syncthreads();
  if (t < 128) {
    double a = 0, q2 = 0;
    #pragma unroll
    for (int r = 0; r < 8; ++r) { a += redS[r][t]; q2 += redQ[r][t]; }
    psum[(size_t)blk*128 + t] = a;
    psq[(size_t)blk*128 + t] = q2;
  }
}

__global__ void ec2_fin_kernel(const float* __restrict__ x2max,
    const float* __restrict__ x2min, const float2* __restrict__ aff,
    float* __restrict__ x2) {
  int idx = blockIdx.x*256 + threadIdx.x;
  if (idx >= NPT*128) return;
  int c = idx & 127;
  float2 ac = aff[c];
  x2[idx] = (ac.x >= 0.f) ? fmaf(ac.x, x2max[idx], ac.y) : fmaf(ac.x, x2min[idx], ac.y);
}

// ------------- Lin1 (192 -> 1024) fused with ReLU + stats + per-batch max/min
__global__ __launch_bounds__(256) void lin1_kernel(const float* __restrict__ x1,
    const float* __restrict__ x2, const float* __restrict__ W,
    const float* __restrict__ bias, double* __restrict__ psum,
    double* __restrict__ psq, float* __restrict__ pmax, float* __restrict__ pmin) {
  __shared__ float fin[64][192];
  const int blk = blockIdx.x, t = threadIdx.x;
  const int pbase = blk * 64;
  for (int idx = t; idx < 64*192; idx += 256) {
    int r = idx / 192, c = idx % 192;
    int p = pbase + r;
    fin[r][c] = (c < 64) ? x1[(size_t)p*64 + c] : x2[(size_t)p*128 + (c - 64)];
  }
  __syncthreads();
  const int c0 = t * 4;
  float4 bv = *(const float4*)&bias[c0];
  double s[4] = {0,0,0,0}, ss[4] = {0,0,0,0};
  float mx[4] = {-FINF,-FINF,-FINF,-FINF}, mn[4] = {FINF,FINF,FINF,FINF};
  for (int pass = 0; pass < 4; ++pass) {
    const int rbase = pass * 16;
    float4 acc[16];
    #pragma unroll
    for (int rr = 0; rr < 16; ++rr) acc[rr] = bv;
    for (int cin = 0; cin < 192; cin += 4) {
      float4 wv0 = *(const float4*)&W[(size_t)(cin+0)*1024 + c0];
      float4 wv1 = *(const float4*)&W[(size_t)(cin+1)*1024 + c0];
      float4 wv2 = *(const float4*)&W[(size_t)(cin+2)*1024 + c0];
      float4 wv3 = *(const float4*)&W[(size_t)(cin+3)*1024 + c0];
      #pragma unroll
      for (int rr = 0; rr < 16; ++rr) {
        float4 f = *(const float4*)&fin[rbase+rr][cin];
        acc[rr].x = fmaf(f.x, wv0.x, acc[rr].x);
        acc[rr].y = fmaf(f.x, wv0.y, acc[rr].y);
        acc[rr].z = fmaf(f.x, wv0.z, acc[rr].z);
        acc[rr].w = fmaf(f.x, wv0.w, acc[rr].w);
        acc[rr].x = fmaf(f.y, wv1.x, acc[rr].x);
        acc[rr].y = fmaf(f.y, wv1.y, acc[rr].y);
        acc[rr].z = fmaf(f.y, wv1.z, acc[rr].z);
        acc[rr].w = fmaf(f.y, wv1.w, acc[rr].w);
        acc[rr].x = fmaf(f.z, wv2.x, acc[rr].x);
        acc[rr].y = fmaf(f.z, wv2.y, acc[rr].y);
        acc[rr].z = fmaf(f.z, wv2.z, acc[rr].z);
        acc[rr].w = fmaf(f.z, wv2.w, acc[rr].w);
        acc[rr].x = fmaf(f.w, wv3.x, acc[rr].x);
        acc[rr].y = fmaf(f.w, wv3.y, acc[rr].y);
        acc[rr].z = fmaf(f.w, wv3.z, acc[rr].z);
        acc[rr].w = fmaf(f.w, wv3.w, acc[rr].w);
      }
    }
    #pragma unroll
    for (int rr = 0; rr < 16; ++rr) {
      float h0 = fmaxf(acc[rr].x, 0.f), h1 = fmaxf(acc[rr].y, 0.f);
      float h2 = fmaxf(acc[rr].z, 0.f), h3 = fmaxf(acc[rr].w, 0.f);
      s[0]+=h0; ss[0]+=(double)h0*h0; mx[0]=fmaxf(mx[0],h0); mn[0]=fminf(mn[0],h0);
      s[1]+=h1; ss[1]+=(double)h1*h1; mx[1]=fmaxf(mx[1],h1); mn[1]=fminf(mn[1],h1);
      s[2]+=h2; ss[2]+=(double)h2*h2; mx[2]=fmaxf(mx[2],h2); mn[2]=fminf(mn[2],h2);
      s[3]+=h3; ss[3]+=(double)h3*h3; mx[3]=fmaxf(mx[3],h3); mn[3]=fminf(mn[3],h3);
    }
  }
  #pragma unroll
  for (int jj = 0; jj < 4; ++jj) {
    psum[(size_t)blk*1024 + c0 + jj] = s[jj];
    psq[(size_t)blk*1024 + c0 + jj] = ss[jj];
    pmax[(size_t)blk*1024 + c0 + jj] = mx[jj];
    pmin[(size_t)blk*1024 + c0 + jj] = mn[jj];
  }
}

// ----------------- lin1 BN+maxpool finalize (block per channel)
__global__ __launch_bounds__(256) void lin1_fin_kernel(const double* __restrict__ psum,
    const double* __restrict__ psq, const float* __restrict__ pmax,
    const float* __restrict__ pmin, const float* __restrict__ g,
    const float* __restrict__ be, float* __restrict__ y) {
  __shared__ double rs[256];
  __shared__ double rq[256];
  __shared__ float smx[32][8];
  __shared__ float smn[32][8];
  __shared__ float sa[2];
  const int c = blockIdx.x;          // grid = 1024
  const int t = threadIdx.x;
  double s = 0.0, ss = 0.0;
  for (int i = t; i < 512; i += 256) {
    s  += psum[(size_t)i*1024 + c];
    ss += psq [(size_t)i*1024 + c];
  }
  rs[t] = s; rq[t] = ss; __syncthreads();
  for (int off = 128; off > 0; off >>= 1) {
    if (t < off) { rs[t] += rs[t+off]; rq[t] += rq[t+off]; }
    __syncthreads();
  }
  if (t == 0) {
    double mean = rs[0] / 32768.0;
    double var = rq[0] / 32768.0 - mean*mean;
    var = var < 0.0 ? 0.0 : var;
    double inv = 1.0 / sqrt(var + 1e-5);
    sa[0] = (float)((double)g[c] * inv);
    sa[1] = (float)((double)be[c] - (double)g[c]*mean*inv);
  }
  {
    int b = t >> 3, q = t & 7;
    float m0 = pmax[(size_t)(b*16 + 2*q    )*1024 + c];
    float m1 = pmax[(size_t)(b*16 + 2*q + 1)*1024 + c];
    float n0 = pmin[(size_t)(b*16 + 2*q    )*1024 + c];
    float n1 = pmin[(size_t)(b*16 + 2*q + 1)*1024 + c];
    smx[b][q] = fmaxf(m0, m1);
    smn[b][q] = fminf(n0, n1);
  }
  __syncthreads();
  if (t < 32) {
    float mxv = -FINF, mnv = FINF;
    #pragma unroll
    for (int q = 0; q < 8; ++q) { mxv = fmaxf(mxv, smx[t][q]); mnv = fminf(mnv, smn[t][q]); }
    float a = sa[0], off2 = sa[1];
    y[(size_t)t*1024 + c] = (a >= 0.f) ? fmaf(a, mxv, off2) : fmaf(a, mnv, off2);
  }
}

// ---------------------------------------------------------------- head MLP
__global__ void head1_kernel(const float* __restrict__ y, const float* __restrict__ W,
    const float* __restrict__ bias, float* __restrict__ h5) {
  int idx = blockIdx.x*256 + threadIdx.x;   // 32*512
  int r = idx >> 9, c = idx & 511;
  float acc = bias[c];
  for (int cin = 0; cin < 1024; ++cin)
    acc = fmaf(y[(size_t)r*1024 + cin], W[(size_t)cin*512 + c], acc);
  h5[idx] = fmaxf(acc, 0.f);
}

__global__ void bn_rows_kernel(const float* __restrict__ h, int C, int R,
    const float* __restrict__ g, const float* __restrict__ be, float2* __restrict__ aff) {
  int c = blockIdx.x*256 + threadIdx.x;
  if (c >= C) return;
  double s = 0, ss = 0;
  for (int r = 0; r < R; ++r) {
    double v = (double)h[(size_t)r*C + c];
    s += v; ss += v*v;
  }
  double mean = s / (double)R;
  double var = ss / (double)R - mean*mean;
  var = var < 0.0 ? 0.0 : var;
  double inv = 1.0 / sqrt(var + 1e-5);
  float a = (float)((double)g[c] * inv);
  float off = (float)((double)be[c] - (double)g[c]*mean*inv);
  aff[c] = make_float2(a, off);
}

__global__ void head2_kernel(const float* __restrict__ h5, const float2* __restrict__ aff,
    const float* __restrict__ W, const float* __restrict__ bias, float* __restrict__ h6) {
  int idx = blockIdx.x*256 + threadIdx.x;   // 32*256
  int r = idx >> 8, c = idx & 255;
  float acc = bias[c];
  for (int cin = 0; cin < 512; ++cin) {
    float2 a = aff[cin];
    acc = fmaf(fmaf(a.x, h5[(size_t)r*512 + cin], a.y), W[(size_t)cin*256 + c], acc);
  }
  h6[idx] = fmaxf(acc, 0.f);
}

__global__ void head3_kernel(const float* __restrict__ h6, const float2* __restrict__ aff,
    const float* __restrict__ W, const float* __restrict__ bias, float* __restrict__ out) {
  int t = threadIdx.x;
  if (t >= 64) return;
  int r = t >> 1, c = t & 1;
  float acc = bias[c];
  for (int cin = 0; cin < 256; ++cin) {
    float2 a = aff[cin];
    acc = fmaf(fmaf(a.x, h6[(size_t)r*256 + cin], a.y), W[(size_t)cin*2 + c], acc);
  }
  out[(size_t)r*2 + c] = acc;
}

// ------------------------------------------------------------------ launcher
extern "C" void kernel_launch(void* const* d_in, const int* in_sizes, int n_in,
                              void* d_out, int out_size, void* d_ws, size_t ws_size,
                              hipStream_t stream) {
  (void)in_sizes; (void)n_in; (void)out_size; (void)ws_size;
  const float* pos    = (const float*)d_in[0];
  const float* c1_w1  = (const float*)d_in[2];
  const float* c1_b1  = (const float*)d_in[3];
  const float* c1_g1  = (const float*)d_in[4];
  const float* c1_be1 = (const float*)d_in[5];
  const float* c1_w2  = (const float*)d_in[6];
  const float* c1_b2  = (const float*)d_in[7];
  const float* c1_g2  = (const float*)d_in[8];
  const float* c1_be2 = (const float*)d_in[9];
  const float* c1_w3  = (const float*)d_in[10];
  const float* c1_b3  = (const float*)d_in[11];
  const float* c1_g3  = (const float*)d_in[12];
  const float* c1_be3 = (const float*)d_in[13];
  const float* c2_w1  = (const float*)d_in[14];
  const float* c2_b1  = (const float*)d_in[15];
  const float* c2_g1  = (const float*)d_in[16];
  const float* c2_be1 = (const float*)d_in[17];
  const float* l1_w   = (const float*)d_in[18];
  const float* l1_b   = (const float*)d_in[19];
  const float* l1_g   = (const float*)d_in[20];
  const float* l1_be  = (const float*)d_in[21];
  const float* m1_w   = (const float*)d_in[22];
  const float* m1_b   = (const float*)d_in[23];
  const float* m1_g   = (const float*)d_in[24];
  const float* m1_be  = (const float*)d_in[25];
  const float* m2_w   = (const float*)d_in[26];
  const float* m2_b   = (const float*)d_in[27];
  const float* m2_g   = (const float*)d_in[28];
  const float* m2_be  = (const float*)d_in[29];
  const float* m3_w   = (const float*)d_in[30];
  const float* m3_b   = (const float*)d_in[31];

  char* ws = (char*)d_ws;
  size_t off = 0;
  auto alloc = [&](size_t bytes) -> void* {
    void* p = ws + off;
    off += (bytes + 255) & ~(size_t)255;
    return p;
  };
  int*    idx1 = (int*)alloc((size_t)NE * 4);
  int*    idx2 = (int*)alloc((size_t)NE * 4);
  float*  x1   = (float*)alloc((size_t)NPT * 64 * 4);
  float*  x2   = (float*)alloc((size_t)NPT * 128 * 4);
  float*  hA   = (float*)alloc((size_t)NE * 64 * 4);
  float*  hB   = (float*)alloc((size_t)NE * 64 * 4);
  double* psum = (double*)alloc((size_t)524288 * 8);
  double* psq  = (double*)alloc((size_t)524288 * 8);
  float*  pmax = (float*)alloc((size_t)524288 * 4);
  float*  pmin = (float*)alloc((size_t)524288 * 4);
  float2* affA = (float2*)alloc(64 * 8);
  float2* affB = (float2*)alloc(64 * 8);
  float2* affC = (float2*)alloc(64 * 8);
  float2* aff2 = (float2*)alloc(128 * 8);
  float2* affM1 = (float2*)alloc(512 * 8);
  float2* affM2 = (float2*)alloc(256 * 8);
  float*  y    = (float*)alloc((size_t)NB * 1024 * 4);
  float*  h5   = (float*)alloc((size_t)NB * 512 * 4);
  float*  h6   = (float*)alloc((size_t)NB * 256 * 4);
  // x2max/x2min reuse hA (h3 dead by then)
  float* x2max = hA;
  float* x2min = hA + (size_t)NPT * 128;

  // 1. knn on positions
  knn1_kernel<<<dim3(NB*4), dim3(256), 0, stream>>>(pos, idx1);
  // 2. EdgeConv1 layer1
  ec1_l1_kernel<<<dim3(NE/64), dim3(256), 0, stream>>>(pos, idx1, c1_w1, c1_b1, hA, psum, psq);
  stats_reduce_kernel<<<dim3(64), dim3(256), 0, stream>>>(psum, psq, NE/64, 64, 1.0/NE, c1_g1, c1_be1, affA);
  // 3. layer2
  ec_l64_kernel<<<dim3(NE/64), dim3(256), 0, stream>>>(hA, affA, c1_w2, c1_b2, hB, psum, psq);
  stats_reduce_kernel<<<dim3(64), dim3(256), 0, stream>>>(psum, psq, NE/64, 64, 1.0/NE, c1_g2, c1_be2, affB);
  // 4. layer3
  ec_l64_kernel<<<dim3(NE/64), dim3(256), 0, stream>>>(hB, affB, c1_w3, c1_b3, hA, psum, psq);
  stats_reduce_kernel<<<dim3(64), dim3(256), 0, stream>>>(psum, psq, NE/64, 64, 1.0/NE, c1_g3, c1_be3, affC);
  // 5. max over k -> x1
  ec1_reduce_kernel<<<dim3(NPT*64/256), dim3(256), 0, stream>>>(hA, affC, x1);
  // 6. knn on features
  knn2_kernel<<<dim3(NB*16), dim3(256), 0, stream>>>(x1, idx2);
  // 7. EdgeConv2 (fused k-max/min)
  ec2_kernel<<<dim3(NPT/8), dim3(256), 0, stream>>>(x1, idx2, c2_w1, c2_b1, x2max, x2min, psum, psq);
  stats_reduce_kernel<<<dim3(128), dim3(256), 0, stream>>>(psum, psq, NPT/8, 128, 1.0/NE, c2_g1, c2_be1, aff2);
  ec2_fin_kernel<<<dim3(NPT*128/256), dim3(256), 0, stream>>>(x2max, x2min, aff2, x2);
  // 8. Lin1 fused (no materialization of [32768,1024])
  lin1_kernel<<<dim3(NPT/64), dim3(256), 0, stream>>>(x1, x2, l1_w, l1_b, psum, psq, pmax, pmin);
  lin1_fin_kernel<<<dim3(1024), dim3(256), 0, stream>>>(psum, psq, pmax, pmin, l1_g, l1_be, y);
  // 9. head
  head1_kernel<<<dim3(64), dim3(256), 0, stream>>>(y, m1_w, m1_b, h5);
  bn_rows_kernel<<<dim3(2), dim3(256), 0, stream>>>(h5, 512, NB, m1_g, m1_be, affM1);
  head2_kernel<<<dim3(32), dim3(256), 0, stream>>>(h5, affM1, m2_w, m2_b, h6);
  bn_rows_kernel<<<dim3(1), dim3(256), 0, stream>>>(h6, 256, NB, m2_g, m2_be, affM2);
  head3_kernel<<<dim3(1), dim3(64), 0, stream>>>(h6, affM2, m3_w, m3_b, (float*)d_out);
}

// Round 4
// 706.291 us; speedup vs baseline: 6.5885x; 1.2095x over previous
//
#include <hip/hip_runtime.h>

// DGCNN forward: knn(3d) -> EdgeConv(6->64->64->64,BN) -> knn(64d) ->
// EdgeConv(128->128,BN) -> Lin(192->1024)+BN+maxpool -> head MLP -> [32,2]
// R2: stats reductions parallelized (block-per-channel).
// R3: knn2 restructured (spill-free selection; was 490MB scratch traffic).
// R4: knn1 parallelized 8 lanes/query (was 0.5 wave/SIMD latency-bound,
// VALUBusy 12%, occ 5.5%); (x,y,z,sq) packed in one LDS float4 ->
// one ds_read_b128/neighbor, interleaved j-scan for bank spread.

#define NB 32
#define NP 1024
#define NPT 32768       // NB*NP
#define KNN 5
#define NE 163840       // NPT*KNN

#define FINF 3.402823466e+38f

__device__ __forceinline__ bool lex_less(float da, int ja, float db, int jb) {
  return (da < db) || (da == db && ja < jb);
}

__device__ __forceinline__ float f4c(const float4& v, int q) {
  return q == 0 ? v.x : (q == 1 ? v.y : (q == 2 ? v.z : v.w));
}

// insert (dd,jj) into sorted-ascending 5-list held as named scalars
__device__ __forceinline__ void insert5(float& d0, float& d1, float& d2, float& d3, float& d4,
                                        int& j0, int& j1, int& j2, int& j3, int& j4,
                                        float dd, int jj) {
  if (lex_less(dd, jj, d4, j4)) {
    bool L0 = lex_less(dd,jj,d0,j0), L1 = lex_less(dd,jj,d1,j1),
         L2 = lex_less(dd,jj,d2,j2), L3 = lex_less(dd,jj,d3,j3);
    d4 = L3 ? d3 : dd;              j4 = L3 ? j3 : jj;
    d3 = L3 ? (L2 ? d2 : dd) : d3;  j3 = L3 ? (L2 ? j2 : jj) : j3;
    d2 = L2 ? (L1 ? d1 : dd) : d2;  j2 = L2 ? (L1 ? j1 : jj) : j2;
    d1 = L1 ? (L0 ? d0 : dd) : d1;  j1 = L1 ? (L0 ? j0 : jj) : j1;
    d0 = L0 ? dd : d0;              j0 = L0 ? jj : j0;
  }
}

// ---------------------------------------------------------------- knn (3-d)
// R4: 32 blocks/batch, 32 queries/block, 8 lanes/query; lane ql scans
// j = 8*jj + ql (ascending within lane => lex merge exact).
__global__ __launch_bounds__(256) void knn1_kernel(const float* __restrict__ pos,
                                                   int* __restrict__ knn_idx) {
  __shared__ float4 xs4[NP];    // (x, y, z, |x|^2)
  const int b = blockIdx.x >> 5;
  const int seg = blockIdx.x & 31;
  const int t = threadIdx.x;
  for (int i = t; i < NP; i += 256) {
    float x0 = pos[(size_t)b*NP*3 + i*3 + 0];
    float x1 = pos[(size_t)b*NP*3 + i*3 + 1];
    float x2 = pos[(size_t)b*NP*3 + i*3 + 2];
    float sq = __fadd_rn(__fadd_rn(__fmul_rn(x0,x0), __fmul_rn(x1,x1)), __fmul_rn(x2,x2));
    xs4[i] = make_float4(x0, x1, x2, sq);
  }
  __syncthreads();
  const int q = t >> 3;            // 32 queries per block
  const int ql = t & 7;            // 8 lanes per query
  const int i = seg * 32 + q;
  const float4 xi = xs4[i];
  const float sqi = xi.w;
  float d0=FINF,d1=FINF,d2=FINF,d3=FINF,d4=FINF;
  int j0=0x7fffffff,j1=0x7fffffff,j2=0x7fffffff,j3=0x7fffffff,j4=0x7fffffff;
  for (int jj = 0; jj < NP/8; ++jj) {
    const int j = jj*8 + ql;
    float4 v = xs4[j];
    float dot = __fadd_rn(__fadd_rn(__fmul_rn(xi.x,v.x), __fmul_rn(xi.y,v.y)), __fmul_rn(xi.z,v.z));
    float dd = __fsub_rn(__fadd_rn(sqi, v.w), __fmul_rn(2.0f, dot));
    insert5(d0,d1,d2,d3,d4, j0,j1,j2,j3,j4, dd, j);
  }
  // merge sorted-5 lists across the 8 lanes of each query
  #pragma unroll
  for (int m = 1; m <= 4; m <<= 1) {
    float e0 = __shfl_xor(d0, m, 8), e1 = __shfl_xor(d1, m, 8),
          e2 = __shfl_xor(d2, m, 8), e3 = __shfl_xor(d3, m, 8),
          e4 = __shfl_xor(d4, m, 8);
    int   k0 = __shfl_xor(j0, m, 8), k1 = __shfl_xor(j1, m, 8),
          k2 = __shfl_xor(j2, m, 8), k3 = __shfl_xor(j3, m, 8),
          k4 = __shfl_xor(j4, m, 8);
    insert5(d0,d1,d2,d3,d4, j0,j1,j2,j3,j4, e0, k0);
    insert5(d0,d1,d2,d3,d4, j0,j1,j2,j3,j4, e1, k1);
    insert5(d0,d1,d2,d3,d4, j0,j1,j2,j3,j4, e2, k2);
    insert5(d0,d1,d2,d3,d4, j0,j1,j2,j3,j4, e3, k3);
    insert5(d0,d1,d2,d3,d4, j0,j1,j2,j3,j4, e4, k4);
  }
  if (ql == 0) {
    const size_t row = (size_t)b * NP + i;
    knn_idx[row*KNN+0] = b*NP + j0;
    knn_idx[row*KNN+1] = b*NP + j1;
    knn_idx[row*KNN+2] = b*NP + j2;
    knn_idx[row*KNN+3] = b*NP + j3;
    knn_idx[row*KNN+4] = b*NP + j4;
  }
}

// ------------------------------------------- EdgeConv1 layer1 (6 -> 64) + stats
__global__ __launch_bounds__(256) void ec1_l1_kernel(const float* __restrict__ pos,
    const int* __restrict__ knn_idx, const float* __restrict__ W,
    const float* __restrict__ bias, float* __restrict__ hout,
    double* __restrict__ psum, double* __restrict__ psq) {
  __shared__ float ef[64][6];
  __shared__ float Wl[6][64];
  __shared__ float bl[64];
  __shared__ double red[256];
  const int blk = blockIdx.x, t = threadIdx.x;
  const int ebase = blk * 64;
  if (t < 64) {
    int e = ebase + t;
    int ip = e / KNN;
    int jp = knn_idx[e];
    float a0 = pos[(size_t)ip*3+0], a1 = pos[(size_t)ip*3+1], a2 = pos[(size_t)ip*3+2];
    float c0 = pos[(size_t)jp*3+0], c1 = pos[(size_t)jp*3+1], c2 = pos[(size_t)jp*3+2];
    ef[t][0] = a0; ef[t][1] = a1; ef[t][2] = a2;
    ef[t][3] = c0 - a0; ef[t][4] = c1 - a1; ef[t][5] = c2 - a2;
    bl[t] = bias[t];
  }
  for (int idx = t; idx < 6*64; idx += 256) Wl[idx>>6][idx&63] = W[idx];
  __syncthreads();
  const int c = t & 63, rs = t >> 6;
  double s = 0.0, ss = 0.0;
  for (int r = rs; r < 64; r += 4) {
    float acc = bl[c];
    #pragma unroll
    for (int q = 0; q < 6; ++q) acc = fmaf(ef[r][q], Wl[q][c], acc);
    acc = fmaxf(acc, 0.0f);
    hout[(size_t)(ebase + r)*64 + c] = acc;
    s += acc; ss += (double)acc * (double)acc;
  }
  red[t] = s; __syncthreads();
  if (t < 64) psum[(size_t)blk*64 + t] = red[t] + red[t+64] + red[t+128] + red[t+192];
  __syncthreads();
  red[t] = ss; __syncthreads();
  if (t < 64) psq[(size_t)blk*64 + t] = red[t] + red[t+64] + red[t+128] + red[t+192];
}

// ------------------- BN stats -> per-channel affine (block per channel)
__global__ __launch_bounds__(256) void stats_reduce_kernel(const double* __restrict__ psum,
    const double* __restrict__ psq, int nblk, int C, double invN,
    const float* __restrict__ g, const float* __restrict__ be,
    float2* __restrict__ aff) {
  __shared__ double rs[256];
  __shared__ double rq[256];
  const int c = blockIdx.x;          // grid = C
  const int t = threadIdx.x;
  double s = 0.0, ss = 0.0;
  for (int i = t; i < nblk; i += 256) {
    s  += psum[(size_t)i*C + c];
    ss += psq [(size_t)i*C + c];
  }
  rs[t] = s; rq[t] = ss; __syncthreads();
  for (int off = 128; off > 0; off >>= 1) {
    if (t < off) { rs[t] += rs[t+off]; rq[t] += rq[t+off]; }
    __syncthreads();
  }
  if (t == 0) {
    double mean = rs[0] * invN;
    double var = rq[0] * invN - mean*mean;
    var = var < 0.0 ? 0.0 : var;
    double inv = 1.0 / sqrt(var + 1e-5);
    float a = (float)((double)g[c] * inv);
    float off2 = (float)((double)be[c] - (double)g[c] * mean * inv);
    aff[c] = make_float2(a, off2);
  }
}

// -------------------------------- EdgeConv1 layers 2/3 (64 -> 64) + stats
__global__ __launch_bounds__(256) void ec_l64_kernel(const float* __restrict__ hin,
    const float2* __restrict__ affprev, const float* __restrict__ W,
    const float* __restrict__ bias, float* __restrict__ hout,
    double* __restrict__ psum, double* __restrict__ psq) {
  __shared__ float ein[64][68];
  __shared__ float Wl[64][64];
  __shared__ float2 affl[64];
  __shared__ float bl[64];
  __shared__ double redS[16][64];
  __shared__ double redQ[16][64];
  const int blk = blockIdx.x, t = threadIdx.x;
  const size_t ebase = (size_t)blk * 64;
  if (t < 64) { affl[t] = affprev[t]; bl[t] = bias[t]; }
  __syncthreads();
  for (int idx = t; idx < 64*64; idx += 256) {
    int r = idx >> 6, c = idx & 63;
    float2 ac = affl[c];
    ein[r][c] = fmaf(hin[ebase*64 + idx], ac.x, ac.y);
    Wl[r][c] = W[idx];
  }
  __syncthreads();
  const int c4 = t & 15, rs = t >> 4;
  const int cbase = c4 * 4;
  const int rbase = rs * 4;
  float acc[4][4];
  #pragma unroll
  for (int ii = 0; ii < 4; ++ii) {
    #pragma unroll
    for (int jj = 0; jj < 4; ++jj) acc[ii][jj] = bl[cbase + jj];
  }
  for (int cin = 0; cin < 64; cin += 4) {
    float4 fi[4];
    #pragma unroll
    for (int ii = 0; ii < 4; ++ii) fi[ii] = *(const float4*)&ein[rbase+ii][cin];
    #pragma unroll
    for (int q = 0; q < 4; ++q) {
      float4 wv = *(const float4*)&Wl[cin+q][cbase];
      #pragma unroll
      for (int ii = 0; ii < 4; ++ii) {
        float f = f4c(fi[ii], q);
        acc[ii][0] = fmaf(f, wv.x, acc[ii][0]);
        acc[ii][1] = fmaf(f, wv.y, acc[ii][1]);
        acc[ii][2] = fmaf(f, wv.z, acc[ii][2]);
        acc[ii][3] = fmaf(f, wv.w, acc[ii][3]);
      }
    }
  }
  double s[4] = {0,0,0,0}, ss[4] = {0,0,0,0};
  #pragma unroll
  for (int ii = 0; ii < 4; ++ii) {
    float4 h;
    h.x = fmaxf(acc[ii][0], 0.f); h.y = fmaxf(acc[ii][1], 0.f);
    h.z = fmaxf(acc[ii][2], 0.f); h.w = fmaxf(acc[ii][3], 0.f);
    *(float4*)&hout[(ebase + rbase + ii)*64 + cbase] = h;
    s[0]+=h.x; s[1]+=h.y; s[2]+=h.z; s[3]+=h.w;
    ss[0]+=(double)h.x*h.x; ss[1]+=(double)h.y*h.y;
    ss[2]+=(double)h.z*h.z; ss[3]+=(double)h.w*h.w;
  }
  #pragma unroll
  for (int jj = 0; jj < 4; ++jj) { redS[rs][cbase+jj] = s[jj]; redQ[rs][cbase+jj] = ss[jj]; }
  __syncthreads();
  if (t < 64) {
    double a = 0, bq = 0;
    #pragma unroll
    for (int r = 0; r < 16; ++r) { a += redS[r][t]; bq += redQ[r][t]; }
    psum[(size_t)blk*64 + t] = a;
    psq[(size_t)blk*64 + t] = bq;
  }
}

// ------------------------------------ max over k with BN affine (monotone)
__global__ void ec1_reduce_kernel(const float* __restrict__ h3,
    const float2* __restrict__ aff, float* __restrict__ x1) {
  int idx = blockIdx.x * 256 + threadIdx.x;
  if (idx >= NPT * 64) return;
  int p = idx >> 6, c = idx & 63;
  float mx = -FINF, mn = FINF;
  #pragma unroll
  for (int kk = 0; kk < KNN; ++kk) {
    float v = h3[((size_t)p*KNN + kk)*64 + c];
    mx = fmaxf(mx, v); mn = fminf(mn, v);
  }
  float2 ac = aff[c];
  x1[idx] = (ac.x >= 0.f) ? fmaf(ac.x, mx, ac.y) : fmaf(ac.x, mn, ac.y);
}

// ---------------------------------------------------------------- knn (64-d)
__global__ __launch_bounds__(256) void knn2_kernel(const float* __restrict__ x1,
                                                   int* __restrict__ knn_idx) {
  __shared__ float xi[64][68];
  __shared__ float xjd[64][68];   // xj tile, then reused as distance tile
  __shared__ float sqi[64];
  __shared__ float sqj[64];
  const int b = blockIdx.x >> 4;
  const int it = blockIdx.x & 15;
  const int t = threadIdx.x;
  const int ibase = it * 64;  // within batch

  {
    int r = t >> 4, c4 = (t & 15) * 4;
    #pragma unroll
    for (int rr = 0; rr < 4; ++rr) {
      float4 v = *(const float4*)&x1[((size_t)b*NP + ibase + r + 16*rr)*64 + c4];
      *(float4*)&xi[r + 16*rr][c4] = v;
    }
  }
  __syncthreads();
  if (t < 64) {
    float s = 0.f;
    #pragma unroll
    for (int c = 0; c < 64; ++c) s = fmaf(xi[t][c], xi[t][c], s);
    sqi[t] = s;
  }
  __syncthreads();

  const int il = t >> 4, jl = t & 15;      // GEMM mapping
  const int row = t >> 2, ql = t & 3;      // selection mapping
  float si[4];
  #pragma unroll
  for (int ii = 0; ii < 4; ++ii) si[ii] = sqi[il*4 + ii];

  float d0=FINF,d1=FINF,d2=FINF,d3=FINF,d4=FINF;
  int j0=0x7fffffff,j1=0x7fffffff,j2=0x7fffffff,j3=0x7fffffff,j4=0x7fffffff;

  for (int jt = 0; jt < 16; ++jt) {
    __syncthreads();
    {
      int r = t >> 4, c4 = (t & 15) * 4;
      #pragma unroll
      for (int rr = 0; rr < 4; ++rr) {
        float4 v = *(const float4*)&x1[((size_t)b*NP + jt*64 + r + 16*rr)*64 + c4];
        *(float4*)&xjd[r + 16*rr][c4] = v;
      }
    }
    __syncthreads();
    if (t < 64) {
      float s = 0.f;
      #pragma unroll
      for (int c = 0; c < 64; ++c) s = fmaf(xjd[t][c], xjd[t][c], s);
      sqj[t] = s;
    }
    __syncthreads();
    float acc[4][4];
    #pragma unroll
    for (int ii = 0; ii < 4; ++ii) {
      #pragma unroll
      for (int jj = 0; jj < 4; ++jj) acc[ii][jj] = 0.f;
    }
    for (int cin = 0; cin < 64; cin += 4) {
      float4 fi[4], fj[4];
      #pragma unroll
      for (int ii = 0; ii < 4; ++ii) fi[ii] = *(const float4*)&xi[il*4+ii][cin];
      #pragma unroll
      for (int jj = 0; jj < 4; ++jj) fj[jj] = *(const float4*)&xjd[jl + 16*jj][cin];
      #pragma unroll
      for (int q = 0; q < 4; ++q) {
        #pragma unroll
        for (int ii = 0; ii < 4; ++ii) {
          float f = f4c(fi[ii], q);
          acc[ii][0] = fmaf(f, f4c(fj[0],q), acc[ii][0]);
          acc[ii][1] = fmaf(f, f4c(fj[1],q), acc[ii][1]);
          acc[ii][2] = fmaf(f, f4c(fj[2],q), acc[ii][2]);
          acc[ii][3] = fmaf(f, f4c(fj[3],q), acc[ii][3]);
        }
      }
    }
    float sjv[4];
    #pragma unroll
    for (int jj = 0; jj < 4; ++jj) sjv[jj] = sqj[jl + 16*jj];
    __syncthreads();
    #pragma unroll
    for (int ii = 0; ii < 4; ++ii) {
      #pragma unroll
      for (int jj = 0; jj < 4; ++jj) {
        xjd[il*4+ii][jl + 16*jj] = fmaf(-2.f, acc[ii][jj], si[ii] + sjv[jj]);
      }
    }
    __syncthreads();
    const int jgbase = jt*64 + ql*16;
    #pragma unroll
    for (int kk = 0; kk < 4; ++kk) {
      float4 v = *(const float4*)&xjd[row][ql*16 + 4*kk];
      insert5(d0,d1,d2,d3,d4, j0,j1,j2,j3,j4, v.x, jgbase + 4*kk + 0);
      insert5(d0,d1,d2,d3,d4, j0,j1,j2,j3,j4, v.y, jgbase + 4*kk + 1);
      insert5(d0,d1,d2,d3,d4, j0,j1,j2,j3,j4, v.z, jgbase + 4*kk + 2);
      insert5(d0,d1,d2,d3,d4, j0,j1,j2,j3,j4, v.w, jgbase + 4*kk + 3);
    }
  }

  #pragma unroll
  for (int m = 1; m <= 2; m <<= 1) {
    float e0 = __shfl_xor(d0, m, 4), e1 = __shfl_xor(d1, m, 4),
          e2 = __shfl_xor(d2, m, 4), e3 = __shfl_xor(d3, m, 4),
          e4 = __shfl_xor(d4, m, 4);
    int   k0 = __shfl_xor(j0, m, 4), k1 = __shfl_xor(j1, m, 4),
          k2 = __shfl_xor(j2, m, 4), k3 = __shfl_xor(j3, m, 4),
          k4 = __shfl_xor(j4, m, 4);
    insert5(d0,d1,d2,d3,d4, j0,j1,j2,j3,j4, e0, k0);
    insert5(d0,d1,d2,d3,d4, j0,j1,j2,j3,j4, e1, k1);
    insert5(d0,d1,d2,d3,d4, j0,j1,j2,j3,j4, e2, k2);
    insert5(d0,d1,d2,d3,d4, j0,j1,j2,j3,j4, e3, k3);
    insert5(d0,d1,d2,d3,d4, j0,j1,j2,j3,j4, e4, k4);
  }
  if (ql == 0) {
    const size_t orow = ((size_t)b*NP + ibase + row) * KNN;
    knn_idx[orow+0] = b*NP + j0;
    knn_idx[orow+1] = b*NP + j1;
    knn_idx[orow+2] = b*NP + j2;
    knn_idx[orow+3] = b*NP + j3;
    knn_idx[orow+4] = b*NP + j4;
  }
}

// --------------------- EdgeConv2 (128 -> 128) fused with k-max/min + stats
__global__ __launch_bounds__(256) void ec2_kernel(const float* __restrict__ x1,
    const int* __restrict__ knn_idx, const float* __restrict__ W,
    const float* __restrict__ bias, float* __restrict__ x2max,
    float* __restrict__ x2min, double* __restrict__ psum, double* __restrict__ psq) {
  __shared__ float e2[40][128];
  __shared__ double redS[8][128];
  __shared__ double redQ[8][128];
  const int blk = blockIdx.x, t = threadIdx.x;
  const int pbase = blk * 8;
  for (int idx = t; idx < 40*128; idx += 256) {
    int r = idx >> 7, c = idx & 127;
    int p = pbase + r / KNN;
    int kk = r % KNN;
    int j = knn_idx[(size_t)p*KNN + kk];
    float v;
    if (c < 64) v = x1[(size_t)p*64 + c];
    else {
      int cc = c - 64;
      v = x1[(size_t)j*64 + cc] - x1[(size_t)p*64 + cc];
    }
    e2[r][c] = v;
  }
  __syncthreads();
  const int c4 = t & 31, rs = t >> 5;
  const int cbase = c4 * 4;
  float4 bv = *(const float4*)&bias[cbase];
  float acc[5][4];
  #pragma unroll
  for (int kk = 0; kk < 5; ++kk) {
    acc[kk][0]=bv.x; acc[kk][1]=bv.y; acc[kk][2]=bv.z; acc[kk][3]=bv.w;
  }
  for (int cin = 0; cin < 128; cin += 4) {
    float4 fi[5];
    #pragma unroll
    for (int kk = 0; kk < 5; ++kk) fi[kk] = *(const float4*)&e2[rs*5+kk][cin];
    #pragma unroll
    for (int q = 0; q < 4; ++q) {
      float4 wv = *(const float4*)&W[(size_t)(cin+q)*128 + cbase];
      #pragma unroll
      for (int kk = 0; kk < 5; ++kk) {
        float f = f4c(fi[kk], q);
        acc[kk][0] = fmaf(f, wv.x, acc[kk][0]);
        acc[kk][1] = fmaf(f, wv.y, acc[kk][1]);
        acc[kk][2] = fmaf(f, wv.z, acc[kk][2]);
        acc[kk][3] = fmaf(f, wv.w, acc[kk][3]);
      }
    }
  }
  float mx[4] = {-FINF,-FINF,-FINF,-FINF}, mn[4] = {FINF,FINF,FINF,FINF};
  double s[4] = {0,0,0,0}, ss[4] = {0,0,0,0};
  #pragma unroll
  for (int kk = 0; kk < 5; ++kk) {
    #pragma unroll
    for (int jj = 0; jj < 4; ++jj) {
      float h = fmaxf(acc[kk][jj], 0.f);
      mx[jj] = fmaxf(mx[jj], h); mn[jj] = fminf(mn[jj], h);
      s[jj] += h; ss[jj] += (double)h * h;
    }
  }
  *(float4*)&x2max[((size_t)pbase + rs)*128 + cbase] = make_float4(mx[0],mx[1],mx[2],mx[3]);
  *(float4*)&x2min[((size_t)pbase + rs)*128 + cbase] = make_float4(mn[0],mn[1],mn[2],mn[3]);
  #pragma unroll
  for (int jj = 0; jj < 4; ++jj) { redS[rs][cbase+jj] = s[jj]; redQ[rs][cbase+jj] = ss[jj]; }
  __syncthreads();
  if (t < 128) {
    double a = 0, q2 = 0;
    #pragma unroll
    for (int r = 0; r < 8; ++r) { a += redS[r][t]; q2 += redQ[r][t]; }
    psum[(size_t)blk*128 + t] = a;
    psq[(size_t)blk*128 + t] = q2;
  }
}

__global__ void ec2_fin_kernel(const float* __restrict__ x2max,
    const float* __restrict__ x2min, const float2* __restrict__ aff,
    float* __restrict__ x2) {
  int idx = blockIdx.x*256 + threadIdx.x;
  if (idx >= NPT*128) return;
  int c = idx & 127;
  float2 ac = aff[c];
  x2[idx] = (ac.x >= 0.f) ? fmaf(ac.x, x2max[idx], ac.y) : fmaf(ac.x, x2min[idx], ac.y);
}

// ------------- Lin1 (192 -> 1024) fused with ReLU + stats + per-batch max/min
__global__ __launch_bounds__(256) void lin1_kernel(const float* __restrict__ x1,
    const float* __restrict__ x2, const float* __restrict__ W,
    const float* __restrict__ bias, double* __restrict__ psum,
    double* __restrict__ psq, float* __restrict__ pmax, float* __restrict__ pmin) {
  __shared__ float fin[64][192];
  const int blk = blockIdx.x, t = threadIdx.x;
  const int pbase = blk * 64;
  for (int idx = t; idx < 64*192; idx += 256) {
    int r = idx / 192, c = idx % 192;
    int p = pbase + r;
    fin[r][c] = (c < 64) ? x1[(size_t)p*64 + c] : x2[(size_t)p*128 + (c - 64)];
  }
  __syncthreads();
  const int c0 = t * 4;
  float4 bv = *(const float4*)&bias[c0];
  double s[4] = {0,0,0,0}, ss[4] = {0,0,0,0};
  float mx[4] = {-FINF,-FINF,-FINF,-FINF}, mn[4] = {FINF,FINF,FINF,FINF};
  for (int pass = 0; pass < 4; ++pass) {
    const int rbase = pass * 16;
    float4 acc[16];
    #pragma unroll
    for (int rr = 0; rr < 16; ++rr) acc[rr] = bv;
    for (int cin = 0; cin < 192; cin += 4) {
      float4 wv0 = *(const float4*)&W[(size_t)(cin+0)*1024 + c0];
      float4 wv1 = *(const float4*)&W[(size_t)(cin+1)*1024 + c0];
      float4 wv2 = *(const float4*)&W[(size_t)(cin+2)*1024 + c0];
      float4 wv3 = *(const float4*)&W[(size_t)(cin+3)*1024 + c0];
      #pragma unroll
      for (int rr = 0; rr < 16; ++rr) {
        float4 f = *(const float4*)&fin[rbase+rr][cin];
        acc[rr].x = fmaf(f.x, wv0.x, acc[rr].x);
        acc[rr].y = fmaf(f.x, wv0.y, acc[rr].y);
        acc[rr].z = fmaf(f.x, wv0.z, acc[rr].z);
        acc[rr].w = fmaf(f.x, wv0.w, acc[rr].w);
        acc[rr].x = fmaf(f.y, wv1.x, acc[rr].x);
        acc[rr].y = fmaf(f.y, wv1.y, acc[rr].y);
        acc[rr].z = fmaf(f.y, wv1.z, acc[rr].z);
        acc[rr].w = fmaf(f.y, wv1.w, acc[rr].w);
        acc[rr].x = fmaf(f.z, wv2.x, acc[rr].x);
        acc[rr].y = fmaf(f.z, wv2.y, acc[rr].y);
        acc[rr].z = fmaf(f.z, wv2.z, acc[rr].z);
        acc[rr].w = fmaf(f.z, wv2.w, acc[rr].w);
        acc[rr].x = fmaf(f.w, wv3.x, acc[rr].x);
        acc[rr].y = fmaf(f.w, wv3.y, acc[rr].y);
        acc[rr].z = fmaf(f.w, wv3.z, acc[rr].z);
        acc[rr].w = fmaf(f.w, wv3.w, acc[rr].w);
      }
    }
    #pragma unroll
    for (int rr = 0; rr < 16; ++rr) {
      float h0 = fmaxf(acc[rr].x, 0.f), h1 = fmaxf(acc[rr].y, 0.f);
      float h2 = fmaxf(acc[rr].z, 0.f), h3 = fmaxf(acc[rr].w, 0.f);
      s[0]+=h0; ss[0]+=(double)h0*h0; mx[0]=fmaxf(mx[0],h0); mn[0]=fminf(mn[0],h0);
      s[1]+=h1; ss[1]+=(double)h1*h1; mx[1]=fmaxf(mx[1],h1); mn[1]=fminf(mn[1],h1);
      s[2]+=h2; ss[2]+=(double)h2*h2; mx[2]=fmaxf(mx[2],h2); mn[2]=fminf(mn[2],h2);
      s[3]+=h3; ss[3]+=(double)h3*h3; mx[3]=fmaxf(mx[3],h3); mn[3]=fminf(mn[3],h3);
    }
  }
  #pragma unroll
  for (int jj = 0; jj < 4; ++jj) {
    psum[(size_t)blk*1024 + c0 + jj] = s[jj];
    psq[(size_t)blk*1024 + c0 + jj] = ss[jj];
    pmax[(size_t)blk*1024 + c0 + jj] = mx[jj];
    pmin[(size_t)blk*1024 + c0 + jj] = mn[jj];
  }
}

// ----------------- lin1 BN+maxpool finalize (block per channel)
__global__ __launch_bounds__(256) void lin1_fin_kernel(const double* __restrict__ psum,
    const double* __restrict__ psq, const float* __restrict__ pmax,
    const float* __restrict__ pmin, const float* __restrict__ g,
    const float* __restrict__ be, float* __restrict__ y) {
  __shared__ double rs[256];
  __shared__ double rq[256];
  __shared__ float smx[32][8];
  __shared__ float smn[32][8];
  __shared__ float sa[2];
  const int c = blockIdx.x;          // grid = 1024
  const int t = threadIdx.x;
  double s = 0.0, ss = 0.0;
  for (int i = t; i < 512; i += 256) {
    s  += psum[(size_t)i*1024 + c];
    ss += psq [(size_t)i*1024 + c];
  }
  rs[t] = s; rq[t] = ss; __syncthreads();
  for (int off = 128; off > 0; off >>= 1) {
    if (t < off) { rs[t] += rs[t+off]; rq[t] += rq[t+off]; }
    __syncthreads();
  }
  if (t == 0) {
    double mean = rs[0] / 32768.0;
    double var = rq[0] / 32768.0 - mean*mean;
    var = var < 0.0 ? 0.0 : var;
    double inv = 1.0 / sqrt(var + 1e-5);
    sa[0] = (float)((double)g[c] * inv);
    sa[1] = (float)((double)be[c] - (double)g[c]*mean*inv);
  }
  {
    int b = t >> 3, q = t & 7;
    float m0 = pmax[(size_t)(b*16 + 2*q    )*1024 + c];
    float m1 = pmax[(size_t)(b*16 + 2*q + 1)*1024 + c];
    float n0 = pmin[(size_t)(b*16 + 2*q    )*1024 + c];
    float n1 = pmin[(size_t)(b*16 + 2*q + 1)*1024 + c];
    smx[b][q] = fmaxf(m0, m1);
    smn[b][q] = fminf(n0, n1);
  }
  __syncthreads();
  if (t < 32) {
    float mxv = -FINF, mnv = FINF;
    #pragma unroll
    for (int q = 0; q < 8; ++q) { mxv = fmaxf(mxv, smx[t][q]); mnv = fminf(mnv, smn[t][q]); }
    float a = sa[0], off2 = sa[1];
    y[(size_t)t*1024 + c] = (a >= 0.f) ? fmaf(a, mxv, off2) : fmaf(a, mnv, off2);
  }
}

// ---------------------------------------------------------------- head MLP
__global__ void head1_kernel(const float* __restrict__ y, const float* __restrict__ W,
    const float* __restrict__ bias, float* __restrict__ h5) {
  int idx = blockIdx.x*256 + threadIdx.x;   // 32*512
  int r = idx >> 9, c = idx & 511;
  float acc = bias[c];
  for (int cin = 0; cin < 1024; ++cin)
    acc = fmaf(y[(size_t)r*1024 + cin], W[(size_t)cin*512 + c], acc);
  h5[idx] = fmaxf(acc, 0.f);
}

__global__ void bn_rows_kernel(const float* __restrict__ h, int C, int R,
    const float* __restrict__ g, const float* __restrict__ be, float2* __restrict__ aff) {
  int c = blockIdx.x*256 + threadIdx.x;
  if (c >= C) return;
  double s = 0, ss = 0;
  for (int r = 0; r < R; ++r) {
    double v = (double)h[(size_t)r*C + c];
    s += v; ss += v*v;
  }
  double mean = s / (double)R;
  double var = ss / (double)R - mean*mean;
  var = var < 0.0 ? 0.0 : var;
  double inv = 1.0 / sqrt(var + 1e-5);
  float a = (float)((double)g[c] * inv);
  float off = (float)((double)be[c] - (double)g[c]*mean*inv);
  aff[c] = make_float2(a, off);
}

__global__ void head2_kernel(const float* __restrict__ h5, const float2* __restrict__ aff,
    const float* __restrict__ W, const float* __restrict__ bias, float* __restrict__ h6) {
  int idx = blockIdx.x*256 + threadIdx.x;   // 32*256
  int r = idx >> 8, c = idx & 255;
  float acc = bias[c];
  for (int cin = 0; cin < 512; ++cin) {
    float2 a = aff[cin];
    acc = fmaf(fmaf(a.x, h5[(size_t)r*512 + cin], a.y), W[(size_t)cin*256 + c], acc);
  }
  h6[idx] = fmaxf(acc, 0.f);
}

__global__ void head3_kernel(const float* __restrict__ h6, const float2* __restrict__ aff,
    const float* __restrict__ W, const float* __restrict__ bias, float* __restrict__ out) {
  int t = threadIdx.x;
  if (t >= 64) return;
  int r = t >> 1, c = t & 1;
  float acc = bias[c];
  for (int cin = 0; cin < 256; ++cin) {
    float2 a = aff[cin];
    acc = fmaf(fmaf(a.x, h6[(size_t)r*256 + cin], a.y), W[(size_t)cin*2 + c], acc);
  }
  out[(size_t)r*2 + c] = acc;
}

// ------------------------------------------------------------------ launcher
extern "C" void kernel_launch(void* const* d_in, const int* in_sizes, int n_in,
                              void* d_out, int out_size, void* d_ws, size_t ws_size,
                              hipStream_t stream) {
  (void)in_sizes; (void)n_in; (void)out_size; (void)ws_size;
  const float* pos    = (const float*)d_in[0];
  const float* c1_w1  = (const float*)d_in[2];
  const float* c1_b1  = (const float*)d_in[3];
  const float* c1_g1  = (const float*)d_in[4];
  const float* c1_be1 = (const float*)d_in[5];
  const float* c1_w2  = (const float*)d_in[6];
  const float* c1_b2  = (const float*)d_in[7];
  const float* c1_g2  = (const float*)d_in[8];
  const float* c1_be2 = (const float*)d_in[9];
  const float* c1_w3  = (const float*)d_in[10];
  const float* c1_b3  = (const float*)d_in[11];
  const float* c1_g3  = (const float*)d_in[12];
  const float* c1_be3 = (const float*)d_in[13];
  const float* c2_w1  = (const float*)d_in[14];
  const float* c2_b1  = (const float*)d_in[15];
  const float* c2_g1  = (const float*)d_in[16];
  const float* c2_be1 = (const float*)d_in[17];
  const float* l1_w   = (const float*)d_in[18];
  const float* l1_b   = (const float*)d_in[19];
  const float* l1_g   = (const float*)d_in[20];
  const float* l1_be  = (const float*)d_in[21];
  const float* m1_w   = (const float*)d_in[22];
  const float* m1_b   = (const float*)d_in[23];
  const float* m1_g   = (const float*)d_in[24];
  const float* m1_be  = (const float*)d_in[25];
  const float* m2_w   = (const float*)d_in[26];
  const float* m2_b   = (const float*)d_in[27];
  const float* m2_g   = (const float*)d_in[28];
  const float* m2_be  = (const float*)d_in[29];
  const float* m3_w   = (const float*)d_in[30];
  const float* m3_b   = (const float*)d_in[31];

  char* ws = (char*)d_ws;
  size_t off = 0;
  auto alloc = [&](size_t bytes) -> void* {
    void* p = ws + off;
    off += (bytes + 255) & ~(size_t)255;
    return p;
  };
  int*    idx1 = (int*)alloc((size_t)NE * 4);
  int*    idx2 = (int*)alloc((size_t)NE * 4);
  float*  x1   = (float*)alloc((size_t)NPT * 64 * 4);
  float*  x2   = (float*)alloc((size_t)NPT * 128 * 4);
  float*  hA   = (float*)alloc((size_t)NE * 64 * 4);
  float*  hB   = (float*)alloc((size_t)NE * 64 * 4);
  double* psum = (double*)alloc((size_t)524288 * 8);
  double* psq  = (double*)alloc((size_t)524288 * 8);
  float*  pmax = (float*)alloc((size_t)524288 * 4);
  float*  pmin = (float*)alloc((size_t)524288 * 4);
  float2* affA = (float2*)alloc(64 * 8);
  float2* affB = (float2*)alloc(64 * 8);
  float2* affC = (float2*)alloc(64 * 8);
  float2* aff2 = (float2*)alloc(128 * 8);
  float2* affM1 = (float2*)alloc(512 * 8);
  float2* affM2 = (float2*)alloc(256 * 8);
  float*  y    = (float*)alloc((size_t)NB * 1024 * 4);
  float*  h5   = (float*)alloc((size_t)NB * 512 * 4);
  float*  h6   = (float*)alloc((size_t)NB * 256 * 4);
  float* x2max = hA;
  float* x2min = hA + (size_t)NPT * 128;

  // 1. knn on positions (R4: 8 lanes/query)
  knn1_kernel<<<dim3(NB*32), dim3(256), 0, stream>>>(pos, idx1);
  // 2. EdgeConv1 layer1
  ec1_l1_kernel<<<dim3(NE/64), dim3(256), 0, stream>>>(pos, idx1, c1_w1, c1_b1, hA, psum, psq);
  stats_reduce_kernel<<<dim3(64), dim3(256), 0, stream>>>(psum, psq, NE/64, 64, 1.0/NE, c1_g1, c1_be1, affA);
  // 3. layer2
  ec_l64_kernel<<<dim3(NE/64), dim3(256), 0, stream>>>(hA, affA, c1_w2, c1_b2, hB, psum, psq);
  stats_reduce_kernel<<<dim3(64), dim3(256), 0, stream>>>(psum, psq, NE/64, 64, 1.0/NE, c1_g2, c1_be2, affB);
  // 4. layer3
  ec_l64_kernel<<<dim3(NE/64), dim3(256), 0, stream>>>(hB, affB, c1_w3, c1_b3, hA, psum, psq);
  stats_reduce_kernel<<<dim3(64), dim3(256), 0, stream>>>(psum, psq, NE/64, 64, 1.0/NE, c1_g3, c1_be3, affC);
  // 5. max over k -> x1
  ec1_reduce_kernel<<<dim3(NPT*64/256), dim3(256), 0, stream>>>(hA, affC, x1);
  // 6. knn on features
  knn2_kernel<<<dim3(NB*16), dim3(256), 0, stream>>>(x1, idx2);
  // 7. EdgeConv2 (fused k-max/min)
  ec2_kernel<<<dim3(NPT/8), dim3(256), 0, stream>>>(x1, idx2, c2_w1, c2_b1, x2max, x2min, psum, psq);
  stats_reduce_kernel<<<dim3(128), dim3(256), 0, stream>>>(psum, psq, NPT/8, 128, 1.0/NE, c2_g1, c2_be1, aff2);
  ec2_fin_kernel<<<dim3(NPT*128/256), dim3(256), 0, stream>>>(x2max, x2min, aff2, x2);
  // 8. Lin1 fused
  lin1_kernel<<<dim3(NPT/64), dim3(256), 0, stream>>>(x1, x2, l1_w, l1_b, psum, psq, pmax, pmin);
  lin1_fin_kernel<<<dim3(1024), dim3(256), 0, stream>>>(psum, psq, pmax, pmin, l1_g, l1_be, y);
  // 9. head
  head1_kernel<<<dim3(64), dim3(256), 0, stream>>>(y, m1_w, m1_b, h5);
  bn_rows_kernel<<<dim3(2), dim3(256), 0, stream>>>(h5, 512, NB, m1_g, m1_be, affM1);
  head2_kernel<<<dim3(32), dim3(256), 0, stream>>>(h5, affM1, m2_w, m2_b, h6);
  bn_rows_kernel<<<dim3(1), dim3(256), 0, stream>>>(h6, 256, NB, m2_g, m2_be, affM2);
  head3_kernel<<<dim3(1), dim3(64), 0, stream>>>(h6, affM2, m3_w, m3_b, (float*)d_out);
}

// Round 5
// 689.527 us; speedup vs baseline: 6.7487x; 1.0243x over previous
//
#include <hip/hip_runtime.h>

// DGCNN forward: knn(3d) -> EdgeConv(6->64->64->64,BN) -> knn(64d) ->
// EdgeConv(128->128,BN) -> Lin(192->1024)+BN+maxpool -> head MLP -> [32,2]
// R2: stats reductions parallelized (block-per-channel).
// R3: knn2 restructured (spill-free selection; was 490MB scratch traffic).
// R4: knn1 parallelized 8 lanes/query.
// R5: lin1 32-rows/block (1024 blocks; was 512 blocks = 2/CU, occ 18%,
// L2-latency starved at 48% of fp32 peak); head1/head2 re-parallelized
// (LDS-staged row + coalesced W + K-split).

#define NB 32
#define NP 1024
#define NPT 32768       // NB*NP
#define KNN 5
#define NE 163840       // NPT*KNN

#define FINF 3.402823466e+38f

__device__ __forceinline__ bool lex_less(float da, int ja, float db, int jb) {
  return (da < db) || (da == db && ja < jb);
}

__device__ __forceinline__ float f4c(const float4& v, int q) {
  return q == 0 ? v.x : (q == 1 ? v.y : (q == 2 ? v.z : v.w));
}

// insert (dd,jj) into sorted-ascending 5-list held as named scalars
__device__ __forceinline__ void insert5(float& d0, float& d1, float& d2, float& d3, float& d4,
                                        int& j0, int& j1, int& j2, int& j3, int& j4,
                                        float dd, int jj) {
  if (lex_less(dd, jj, d4, j4)) {
    bool L0 = lex_less(dd,jj,d0,j0), L1 = lex_less(dd,jj,d1,j1),
         L2 = lex_less(dd,jj,d2,j2), L3 = lex_less(dd,jj,d3,j3);
    d4 = L3 ? d3 : dd;              j4 = L3 ? j3 : jj;
    d3 = L3 ? (L2 ? d2 : dd) : d3;  j3 = L3 ? (L2 ? j2 : jj) : j3;
    d2 = L2 ? (L1 ? d1 : dd) : d2;  j2 = L2 ? (L1 ? j1 : jj) : j2;
    d1 = L1 ? (L0 ? d0 : dd) : d1;  j1 = L1 ? (L0 ? j0 : jj) : j1;
    d0 = L0 ? dd : d0;              j0 = L0 ? jj : j0;
  }
}

// ---------------------------------------------------------------- knn (3-d)
__global__ __launch_bounds__(256) void knn1_kernel(const float* __restrict__ pos,
                                                   int* __restrict__ knn_idx) {
  __shared__ float4 xs4[NP];    // (x, y, z, |x|^2)
  const int b = blockIdx.x >> 5;
  const int seg = blockIdx.x & 31;
  const int t = threadIdx.x;
  for (int i = t; i < NP; i += 256) {
    float x0 = pos[(size_t)b*NP*3 + i*3 + 0];
    float x1 = pos[(size_t)b*NP*3 + i*3 + 1];
    float x2 = pos[(size_t)b*NP*3 + i*3 + 2];
    float sq = __fadd_rn(__fadd_rn(__fmul_rn(x0,x0), __fmul_rn(x1,x1)), __fmul_rn(x2,x2));
    xs4[i] = make_float4(x0, x1, x2, sq);
  }
  __syncthreads();
  const int q = t >> 3;            // 32 queries per block
  const int ql = t & 7;            // 8 lanes per query
  const int i = seg * 32 + q;
  const float4 xi = xs4[i];
  const float sqi = xi.w;
  float d0=FINF,d1=FINF,d2=FINF,d3=FINF,d4=FINF;
  int j0=0x7fffffff,j1=0x7fffffff,j2=0x7fffffff,j3=0x7fffffff,j4=0x7fffffff;
  for (int jj = 0; jj < NP/8; ++jj) {
    const int j = jj*8 + ql;
    float4 v = xs4[j];
    float dot = __fadd_rn(__fadd_rn(__fmul_rn(xi.x,v.x), __fmul_rn(xi.y,v.y)), __fmul_rn(xi.z,v.z));
    float dd = __fsub_rn(__fadd_rn(sqi, v.w), __fmul_rn(2.0f, dot));
    insert5(d0,d1,d2,d3,d4, j0,j1,j2,j3,j4, dd, j);
  }
  #pragma unroll
  for (int m = 1; m <= 4; m <<= 1) {
    float e0 = __shfl_xor(d0, m, 8), e1 = __shfl_xor(d1, m, 8),
          e2 = __shfl_xor(d2, m, 8), e3 = __shfl_xor(d3, m, 8),
          e4 = __shfl_xor(d4, m, 8);
    int   k0 = __shfl_xor(j0, m, 8), k1 = __shfl_xor(j1, m, 8),
          k2 = __shfl_xor(j2, m, 8), k3 = __shfl_xor(j3, m, 8),
          k4 = __shfl_xor(j4, m, 8);
    insert5(d0,d1,d2,d3,d4, j0,j1,j2,j3,j4, e0, k0);
    insert5(d0,d1,d2,d3,d4, j0,j1,j2,j3,j4, e1, k1);
    insert5(d0,d1,d2,d3,d4, j0,j1,j2,j3,j4, e2, k2);
    insert5(d0,d1,d2,d3,d4, j0,j1,j2,j3,j4, e3, k3);
    insert5(d0,d1,d2,d3,d4, j0,j1,j2,j3,j4, e4, k4);
  }
  if (ql == 0) {
    const size_t row = (size_t)b * NP + i;
    knn_idx[row*KNN+0] = b*NP + j0;
    knn_idx[row*KNN+1] = b*NP + j1;
    knn_idx[row*KNN+2] = b*NP + j2;
    knn_idx[row*KNN+3] = b*NP + j3;
    knn_idx[row*KNN+4] = b*NP + j4;
  }
}

// ------------------------------------------- EdgeConv1 layer1 (6 -> 64) + stats
__global__ __launch_bounds__(256) void ec1_l1_kernel(const float* __restrict__ pos,
    const int* __restrict__ knn_idx, const float* __restrict__ W,
    const float* __restrict__ bias, float* __restrict__ hout,
    double* __restrict__ psum, double* __restrict__ psq) {
  __shared__ float ef[64][6];
  __shared__ float Wl[6][64];
  __shared__ float bl[64];
  __shared__ double red[256];
  const int blk = blockIdx.x, t = threadIdx.x;
  const int ebase = blk * 64;
  if (t < 64) {
    int e = ebase + t;
    int ip = e / KNN;
    int jp = knn_idx[e];
    float a0 = pos[(size_t)ip*3+0], a1 = pos[(size_t)ip*3+1], a2 = pos[(size_t)ip*3+2];
    float c0 = pos[(size_t)jp*3+0], c1 = pos[(size_t)jp*3+1], c2 = pos[(size_t)jp*3+2];
    ef[t][0] = a0; ef[t][1] = a1; ef[t][2] = a2;
    ef[t][3] = c0 - a0; ef[t][4] = c1 - a1; ef[t][5] = c2 - a2;
    bl[t] = bias[t];
  }
  for (int idx = t; idx < 6*64; idx += 256) Wl[idx>>6][idx&63] = W[idx];
  __syncthreads();
  const int c = t & 63, rs = t >> 6;
  double s = 0.0, ss = 0.0;
  for (int r = rs; r < 64; r += 4) {
    float acc = bl[c];
    #pragma unroll
    for (int q = 0; q < 6; ++q) acc = fmaf(ef[r][q], Wl[q][c], acc);
    acc = fmaxf(acc, 0.0f);
    hout[(size_t)(ebase + r)*64 + c] = acc;
    s += acc; ss += (double)acc * (double)acc;
  }
  red[t] = s; __syncthreads();
  if (t < 64) psum[(size_t)blk*64 + t] = red[t] + red[t+64] + red[t+128] + red[t+192];
  __syncthreads();
  red[t] = ss; __syncthreads();
  if (t < 64) psq[(size_t)blk*64 + t] = red[t] + red[t+64] + red[t+128] + red[t+192];
}

// ------------------- BN stats -> per-channel affine (block per channel)
__global__ __launch_bounds__(256) void stats_reduce_kernel(const double* __restrict__ psum,
    const double* __restrict__ psq, int nblk, int C, double invN,
    const float* __restrict__ g, const float* __restrict__ be,
    float2* __restrict__ aff) {
  __shared__ double rs[256];
  __shared__ double rq[256];
  const int c = blockIdx.x;          // grid = C
  const int t = threadIdx.x;
  double s = 0.0, ss = 0.0;
  for (int i = t; i < nblk; i += 256) {
    s  += psum[(size_t)i*C + c];
    ss += psq [(size_t)i*C + c];
  }
  rs[t] = s; rq[t] = ss; __syncthreads();
  for (int off = 128; off > 0; off >>= 1) {
    if (t < off) { rs[t] += rs[t+off]; rq[t] += rq[t+off]; }
    __syncthreads();
  }
  if (t == 0) {
    double mean = rs[0] * invN;
    double var = rq[0] * invN - mean*mean;
    var = var < 0.0 ? 0.0 : var;
    double inv = 1.0 / sqrt(var + 1e-5);
    float a = (float)((double)g[c] * inv);
    float off2 = (float)((double)be[c] - (double)g[c] * mean * inv);
    aff[c] = make_float2(a, off2);
  }
}

// -------------------------------- EdgeConv1 layers 2/3 (64 -> 64) + stats
__global__ __launch_bounds__(256) void ec_l64_kernel(const float* __restrict__ hin,
    const float2* __restrict__ affprev, const float* __restrict__ W,
    const float* __restrict__ bias, float* __restrict__ hout,
    double* __restrict__ psum, double* __restrict__ psq) {
  __shared__ float ein[64][68];
  __shared__ float Wl[64][64];
  __shared__ float2 affl[64];
  __shared__ float bl[64];
  __shared__ double redS[16][64];
  __shared__ double redQ[16][64];
  const int blk = blockIdx.x, t = threadIdx.x;
  const size_t ebase = (size_t)blk * 64;
  if (t < 64) { affl[t] = affprev[t]; bl[t] = bias[t]; }
  __syncthreads();
  for (int idx = t; idx < 64*64; idx += 256) {
    int r = idx >> 6, c = idx & 63;
    float2 ac = affl[c];
    ein[r][c] = fmaf(hin[ebase*64 + idx], ac.x, ac.y);
    Wl[r][c] = W[idx];
  }
  __syncthreads();
  const int c4 = t & 15, rs = t >> 4;
  const int cbase = c4 * 4;
  const int rbase = rs * 4;
  float acc[4][4];
  #pragma unroll
  for (int ii = 0; ii < 4; ++ii) {
    #pragma unroll
    for (int jj = 0; jj < 4; ++jj) acc[ii][jj] = bl[cbase + jj];
  }
  for (int cin = 0; cin < 64; cin += 4) {
    float4 fi[4];
    #pragma unroll
    for (int ii = 0; ii < 4; ++ii) fi[ii] = *(const float4*)&ein[rbase+ii][cin];
    #pragma unroll
    for (int q = 0; q < 4; ++q) {
      float4 wv = *(const float4*)&Wl[cin+q][cbase];
      #pragma unroll
      for (int ii = 0; ii < 4; ++ii) {
        float f = f4c(fi[ii], q);
        acc[ii][0] = fmaf(f, wv.x, acc[ii][0]);
        acc[ii][1] = fmaf(f, wv.y, acc[ii][1]);
        acc[ii][2] = fmaf(f, wv.z, acc[ii][2]);
        acc[ii][3] = fmaf(f, wv.w, acc[ii][3]);
      }
    }
  }
  double s[4] = {0,0,0,0}, ss[4] = {0,0,0,0};
  #pragma unroll
  for (int ii = 0; ii < 4; ++ii) {
    float4 h;
    h.x = fmaxf(acc[ii][0], 0.f); h.y = fmaxf(acc[ii][1], 0.f);
    h.z = fmaxf(acc[ii][2], 0.f); h.w = fmaxf(acc[ii][3], 0.f);
    *(float4*)&hout[(ebase + rbase + ii)*64 + cbase] = h;
    s[0]+=h.x; s[1]+=h.y; s[2]+=h.z; s[3]+=h.w;
    ss[0]+=(double)h.x*h.x; ss[1]+=(double)h.y*h.y;
    ss[2]+=(double)h.z*h.z; ss[3]+=(double)h.w*h.w;
  }
  #pragma unroll
  for (int jj = 0; jj < 4; ++jj) { redS[rs][cbase+jj] = s[jj]; redQ[rs][cbase+jj] = ss[jj]; }
  __syncthreads();
  if (t < 64) {
    double a = 0, bq = 0;
    #pragma unroll
    for (int r = 0; r < 16; ++r) { a += redS[r][t]; bq += redQ[r][t]; }
    psum[(size_t)blk*64 + t] = a;
    psq[(size_t)blk*64 + t] = bq;
  }
}

// ------------------------------------ max over k with BN affine (monotone)
__global__ void ec1_reduce_kernel(const float* __restrict__ h3,
    const float2* __restrict__ aff, float* __restrict__ x1) {
  int idx = blockIdx.x * 256 + threadIdx.x;
  if (idx >= NPT * 64) return;
  int p = idx >> 6, c = idx & 63;
  float mx = -FINF, mn = FINF;
  #pragma unroll
  for (int kk = 0; kk < KNN; ++kk) {
    float v = h3[((size_t)p*KNN + kk)*64 + c];
    mx = fmaxf(mx, v); mn = fminf(mn, v);
  }
  float2 ac = aff[c];
  x1[idx] = (ac.x >= 0.f) ? fmaf(ac.x, mx, ac.y) : fmaf(ac.x, mn, ac.y);
}

// ---------------------------------------------------------------- knn (64-d)
__global__ __launch_bounds__(256) void knn2_kernel(const float* __restrict__ x1,
                                                   int* __restrict__ knn_idx) {
  __shared__ float xi[64][68];
  __shared__ float xjd[64][68];   // xj tile, then reused as distance tile
  __shared__ float sqi[64];
  __shared__ float sqj[64];
  const int b = blockIdx.x >> 4;
  const int it = blockIdx.x & 15;
  const int t = threadIdx.x;
  const int ibase = it * 64;  // within batch

  {
    int r = t >> 4, c4 = (t & 15) * 4;
    #pragma unroll
    for (int rr = 0; rr < 4; ++rr) {
      float4 v = *(const float4*)&x1[((size_t)b*NP + ibase + r + 16*rr)*64 + c4];
      *(float4*)&xi[r + 16*rr][c4] = v;
    }
  }
  __syncthreads();
  if (t < 64) {
    float s = 0.f;
    #pragma unroll
    for (int c = 0; c < 64; ++c) s = fmaf(xi[t][c], xi[t][c], s);
    sqi[t] = s;
  }
  __syncthreads();

  const int il = t >> 4, jl = t & 15;      // GEMM mapping
  const int row = t >> 2, ql = t & 3;      // selection mapping
  float si[4];
  #pragma unroll
  for (int ii = 0; ii < 4; ++ii) si[ii] = sqi[il*4 + ii];

  float d0=FINF,d1=FINF,d2=FINF,d3=FINF,d4=FINF;
  int j0=0x7fffffff,j1=0x7fffffff,j2=0x7fffffff,j3=0x7fffffff,j4=0x7fffffff;

  for (int jt = 0; jt < 16; ++jt) {
    __syncthreads();
    {
      int r = t >> 4, c4 = (t & 15) * 4;
      #pragma unroll
      for (int rr = 0; rr < 4; ++rr) {
        float4 v = *(const float4*)&x1[((size_t)b*NP + jt*64 + r + 16*rr)*64 + c4];
        *(float4*)&xjd[r + 16*rr][c4] = v;
      }
    }
    __syncthreads();
    if (t < 64) {
      float s = 0.f;
      #pragma unroll
      for (int c = 0; c < 64; ++c) s = fmaf(xjd[t][c], xjd[t][c], s);
      sqj[t] = s;
    }
    __syncthreads();
    float acc[4][4];
    #pragma unroll
    for (int ii = 0; ii < 4; ++ii) {
      #pragma unroll
      for (int jj = 0; jj < 4; ++jj) acc[ii][jj] = 0.f;
    }
    for (int cin = 0; cin < 64; cin += 4) {
      float4 fi[4], fj[4];
      #pragma unroll
      for (int ii = 0; ii < 4; ++ii) fi[ii] = *(const float4*)&xi[il*4+ii][cin];
      #pragma unroll
      for (int jj = 0; jj < 4; ++jj) fj[jj] = *(const float4*)&xjd[jl + 16*jj][cin];
      #pragma unroll
      for (int q = 0; q < 4; ++q) {
        #pragma unroll
        for (int ii = 0; ii < 4; ++ii) {
          float f = f4c(fi[ii], q);
          acc[ii][0] = fmaf(f, f4c(fj[0],q), acc[ii][0]);
          acc[ii][1] = fmaf(f, f4c(fj[1],q), acc[ii][1]);
          acc[ii][2] = fmaf(f, f4c(fj[2],q), acc[ii][2]);
          acc[ii][3] = fmaf(f, f4c(fj[3],q), acc[ii][3]);
        }
      }
    }
    float sjv[4];
    #pragma unroll
    for (int jj = 0; jj < 4; ++jj) sjv[jj] = sqj[jl + 16*jj];
    __syncthreads();
    #pragma unroll
    for (int ii = 0; ii < 4; ++ii) {
      #pragma unroll
      for (int jj = 0; jj < 4; ++jj) {
        xjd[il*4+ii][jl + 16*jj] = fmaf(-2.f, acc[ii][jj], si[ii] + sjv[jj]);
      }
    }
    __syncthreads();
    const int jgbase = jt*64 + ql*16;
    #pragma unroll
    for (int kk = 0; kk < 4; ++kk) {
      float4 v = *(const float4*)&xjd[row][ql*16 + 4*kk];
      insert5(d0,d1,d2,d3,d4, j0,j1,j2,j3,j4, v.x, jgbase + 4*kk + 0);
      insert5(d0,d1,d2,d3,d4, j0,j1,j2,j3,j4, v.y, jgbase + 4*kk + 1);
      insert5(d0,d1,d2,d3,d4, j0,j1,j2,j3,j4, v.z, jgbase + 4*kk + 2);
      insert5(d0,d1,d2,d3,d4, j0,j1,j2,j3,j4, v.w, jgbase + 4*kk + 3);
    }
  }

  #pragma unroll
  for (int m = 1; m <= 2; m <<= 1) {
    float e0 = __shfl_xor(d0, m, 4), e1 = __shfl_xor(d1, m, 4),
          e2 = __shfl_xor(d2, m, 4), e3 = __shfl_xor(d3, m, 4),
          e4 = __shfl_xor(d4, m, 4);
    int   k0 = __shfl_xor(j0, m, 4), k1 = __shfl_xor(j1, m, 4),
          k2 = __shfl_xor(j2, m, 4), k3 = __shfl_xor(j3, m, 4),
          k4 = __shfl_xor(j4, m, 4);
    insert5(d0,d1,d2,d3,d4, j0,j1,j2,j3,j4, e0, k0);
    insert5(d0,d1,d2,d3,d4, j0,j1,j2,j3,j4, e1, k1);
    insert5(d0,d1,d2,d3,d4, j0,j1,j2,j3,j4, e2, k2);
    insert5(d0,d1,d2,d3,d4, j0,j1,j2,j3,j4, e3, k3);
    insert5(d0,d1,d2,d3,d4, j0,j1,j2,j3,j4, e4, k4);
  }
  if (ql == 0) {
    const size_t orow = ((size_t)b*NP + ibase + row) * KNN;
    knn_idx[orow+0] = b*NP + j0;
    knn_idx[orow+1] = b*NP + j1;
    knn_idx[orow+2] = b*NP + j2;
    knn_idx[orow+3] = b*NP + j3;
    knn_idx[orow+4] = b*NP + j4;
  }
}

// --------------------- EdgeConv2 (128 -> 128) fused with k-max/min + stats
__global__ __launch_bounds__(256) void ec2_kernel(const float* __restrict__ x1,
    const int* __restrict__ knn_idx, const float* __restrict__ W,
    const float* __restrict__ bias, float* __restrict__ x2max,
    float* __restrict__ x2min, double* __restrict__ psum, double* __restrict__ psq) {
  __shared__ float e2[40][128];
  __shared__ double redS[8][128];
  __shared__ double redQ[8][128];
  const int blk = blockIdx.x, t = threadIdx.x;
  const int pbase = blk * 8;
  for (int idx = t; idx < 40*128; idx += 256) {
    int r = idx >> 7, c = idx & 127;
    int p = pbase + r / KNN;
    int kk = r % KNN;
    int j = knn_idx[(size_t)p*KNN + kk];
    float v;
    if (c < 64) v = x1[(size_t)p*64 + c];
    else {
      int cc = c - 64;
      v = x1[(size_t)j*64 + cc] - x1[(size_t)p*64 + cc];
    }
    e2[r][c] = v;
  }
  __syncthreads();
  const int c4 = t & 31, rs = t >> 5;
  const int cbase = c4 * 4;
  float4 bv = *(const float4*)&bias[cbase];
  float acc[5][4];
  #pragma unroll
  for (int kk = 0; kk < 5; ++kk) {
    acc[kk][0]=bv.x; acc[kk][1]=bv.y; acc[kk][2]=bv.z; acc[kk][3]=bv.w;
  }
  for (int cin = 0; cin < 128; cin += 4) {
    float4 fi[5];
    #pragma unroll
    for (int kk = 0; kk < 5; ++kk) fi[kk] = *(const float4*)&e2[rs*5+kk][cin];
    #pragma unroll
    for (int q = 0; q < 4; ++q) {
      float4 wv = *(const float4*)&W[(size_t)(cin+q)*128 + cbase];
      #pragma unroll
      for (int kk = 0; kk < 5; ++kk) {
        float f = f4c(fi[kk], q);
        acc[kk][0] = fmaf(f, wv.x, acc[kk][0]);
        acc[kk][1] = fmaf(f, wv.y, acc[kk][1]);
        acc[kk][2] = fmaf(f, wv.z, acc[kk][2]);
        acc[kk][3] = fmaf(f, wv.w, acc[kk][3]);
      }
    }
  }
  float mx[4] = {-FINF,-FINF,-FINF,-FINF}, mn[4] = {FINF,FINF,FINF,FINF};
  double s[4] = {0,0,0,0}, ss[4] = {0,0,0,0};
  #pragma unroll
  for (int kk = 0; kk < 5; ++kk) {
    #pragma unroll
    for (int jj = 0; jj < 4; ++jj) {
      float h = fmaxf(acc[kk][jj], 0.f);
      mx[jj] = fmaxf(mx[jj], h); mn[jj] = fminf(mn[jj], h);
      s[jj] += h; ss[jj] += (double)h * h;
    }
  }
  *(float4*)&x2max[((size_t)pbase + rs)*128 + cbase] = make_float4(mx[0],mx[1],mx[2],mx[3]);
  *(float4*)&x2min[((size_t)pbase + rs)*128 + cbase] = make_float4(mn[0],mn[1],mn[2],mn[3]);
  #pragma unroll
  for (int jj = 0; jj < 4; ++jj) { redS[rs][cbase+jj] = s[jj]; redQ[rs][cbase+jj] = ss[jj]; }
  __syncthreads();
  if (t < 128) {
    double a = 0, q2 = 0;
    #pragma unroll
    for (int r = 0; r < 8; ++r) { a += redS[r][t]; q2 += redQ[r][t]; }
    psum[(size_t)blk*128 + t] = a;
    psq[(size_t)blk*128 + t] = q2;
  }
}

__global__ void ec2_fin_kernel(const float* __restrict__ x2max,
    const float* __restrict__ x2min, const float2* __restrict__ aff,
    float* __restrict__ x2) {
  int idx = blockIdx.x*256 + threadIdx.x;
  if (idx >= NPT*128) return;
  int c = idx & 127;
  float2 ac = aff[c];
  x2[idx] = (ac.x >= 0.f) ? fmaf(ac.x, x2max[idx], ac.y) : fmaf(ac.x, x2min[idx], ac.y);
}

// ------------- Lin1 (192 -> 1024) fused with ReLU + stats + per-batch max/min
// R5: 32 rows/block (1024 blocks -> 4 blocks/CU; was 2/CU and L2-latency bound)
__global__ __launch_bounds__(256) void lin1_kernel(const float* __restrict__ x1,
    const float* __restrict__ x2, const float* __restrict__ W,
    const float* __restrict__ bias, double* __restrict__ psum,
    double* __restrict__ psq, float* __restrict__ pmax, float* __restrict__ pmin) {
  __shared__ float fin[32][192];
  const int blk = blockIdx.x, t = threadIdx.x;
  const int pbase = blk * 32;
  for (int idx = t; idx < 32*192; idx += 256) {
    int r = idx / 192, c = idx % 192;
    int p = pbase + r;
    fin[r][c] = (c < 64) ? x1[(size_t)p*64 + c] : x2[(size_t)p*128 + (c - 64)];
  }
  __syncthreads();
  const int c0 = t * 4;
  float4 bv = *(const float4*)&bias[c0];
  double s[4] = {0,0,0,0}, ss[4] = {0,0,0,0};
  float mx[4] = {-FINF,-FINF,-FINF,-FINF}, mn[4] = {FINF,FINF,FINF,FINF};
  for (int pass = 0; pass < 2; ++pass) {
    const int rbase = pass * 16;
    float4 acc[16];
    #pragma unroll
    for (int rr = 0; rr < 16; ++rr) acc[rr] = bv;
    for (int cin = 0; cin < 192; cin += 4) {
      float4 wv0 = *(const float4*)&W[(size_t)(cin+0)*1024 + c0];
      float4 wv1 = *(const float4*)&W[(size_t)(cin+1)*1024 + c0];
      float4 wv2 = *(const float4*)&W[(size_t)(cin+2)*1024 + c0];
      float4 wv3 = *(const float4*)&W[(size_t)(cin+3)*1024 + c0];
      #pragma unroll
      for (int rr = 0; rr < 16; ++rr) {
        float4 f = *(const float4*)&fin[rbase+rr][cin];
        acc[rr].x = fmaf(f.x, wv0.x, acc[rr].x);
        acc[rr].y = fmaf(f.x, wv0.y, acc[rr].y);
        acc[rr].z = fmaf(f.x, wv0.z, acc[rr].z);
        acc[rr].w = fmaf(f.x, wv0.w, acc[rr].w);
        acc[rr].x = fmaf(f.y, wv1.x, acc[rr].x);
        acc[rr].y = fmaf(f.y, wv1.y, acc[rr].y);
        acc[rr].z = fmaf(f.y, wv1.z, acc[rr].z);
        acc[rr].w = fmaf(f.y, wv1.w, acc[rr].w);
        acc[rr].x = fmaf(f.z, wv2.x, acc[rr].x);
        acc[rr].y = fmaf(f.z, wv2.y, acc[rr].y);
        acc[rr].z = fmaf(f.z, wv2.z, acc[rr].z);
        acc[rr].w = fmaf(f.z, wv2.w, acc[rr].w);
        acc[rr].x = fmaf(f.w, wv3.x, acc[rr].x);
        acc[rr].y = fmaf(f.w, wv3.y, acc[rr].y);
        acc[rr].z = fmaf(f.w, wv3.z, acc[rr].z);
        acc[rr].w = fmaf(f.w, wv3.w, acc[rr].w);
      }
    }
    #pragma unroll
    for (int rr = 0; rr < 16; ++rr) {
      float h0 = fmaxf(acc[rr].x, 0.f), h1 = fmaxf(acc[rr].y, 0.f);
      float h2 = fmaxf(acc[rr].z, 0.f), h3 = fmaxf(acc[rr].w, 0.f);
      s[0]+=h0; ss[0]+=(double)h0*h0; mx[0]=fmaxf(mx[0],h0); mn[0]=fminf(mn[0],h0);
      s[1]+=h1; ss[1]+=(double)h1*h1; mx[1]=fmaxf(mx[1],h1); mn[1]=fminf(mn[1],h1);
      s[2]+=h2; ss[2]+=(double)h2*h2; mx[2]=fmaxf(mx[2],h2); mn[2]=fminf(mn[2],h2);
      s[3]+=h3; ss[3]+=(double)h3*h3; mx[3]=fmaxf(mx[3],h3); mn[3]=fminf(mn[3],h3);
    }
  }
  #pragma unroll
  for (int jj = 0; jj < 4; ++jj) {
    psum[(size_t)blk*1024 + c0 + jj] = s[jj];
    psq[(size_t)blk*1024 + c0 + jj] = ss[jj];
    pmax[(size_t)blk*1024 + c0 + jj] = mx[jj];
    pmin[(size_t)blk*1024 + c0 + jj] = mn[jj];
  }
}

// ----------------- lin1 BN+maxpool finalize (block per channel; 1024 partials)
__global__ __launch_bounds__(256) void lin1_fin_kernel(const double* __restrict__ psum,
    const double* __restrict__ psq, const float* __restrict__ pmax,
    const float* __restrict__ pmin, const float* __restrict__ g,
    const float* __restrict__ be, float* __restrict__ y) {
  __shared__ double rs[256];
  __shared__ double rq[256];
  __shared__ float smx[32][8];
  __shared__ float smn[32][8];
  __shared__ float sa[2];
  const int c = blockIdx.x;          // grid = 1024
  const int t = threadIdx.x;
  double s = 0.0, ss = 0.0;
  for (int i = t; i < 1024; i += 256) {
    s  += psum[(size_t)i*1024 + c];
    ss += psq [(size_t)i*1024 + c];
  }
  rs[t] = s; rq[t] = ss; __syncthreads();
  for (int off = 128; off > 0; off >>= 1) {
    if (t < off) { rs[t] += rs[t+off]; rq[t] += rq[t+off]; }
    __syncthreads();
  }
  if (t == 0) {
    double mean = rs[0] / 32768.0;
    double var = rq[0] / 32768.0 - mean*mean;
    var = var < 0.0 ? 0.0 : var;
    double inv = 1.0 / sqrt(var + 1e-5);
    sa[0] = (float)((double)g[c] * inv);
    sa[1] = (float)((double)be[c] - (double)g[c]*mean*inv);
  }
  // per-batch max/min over 32 partials: t = b*8 + q; q handles i = 4q..4q+3
  {
    int b = t >> 3, q = t & 7;
    float mxv = -FINF, mnv = FINF;
    #pragma unroll
    for (int k = 0; k < 4; ++k) {
      int i = b*32 + q*4 + k;
      mxv = fmaxf(mxv, pmax[(size_t)i*1024 + c]);
      mnv = fminf(mnv, pmin[(size_t)i*1024 + c]);
    }
    smx[b][q] = mxv;
    smn[b][q] = mnv;
  }
  __syncthreads();
  if (t < 32) {
    float mxv = -FINF, mnv = FINF;
    #pragma unroll
    for (int q = 0; q < 8; ++q) { mxv = fmaxf(mxv, smx[t][q]); mnv = fminf(mnv, smn[t][q]); }
    float a = sa[0], off2 = sa[1];
    y[(size_t)t*1024 + c] = (a >= 0.f) ? fmaf(a, mxv, off2) : fmaf(a, mnv, off2);
  }
}

// ---------------------------------------------------------------- head MLP
// R5: 128 blocks; block = (row r, 128-col segment); K split in half across
// thread pairs; y row staged in LDS.
__global__ __launch_bounds__(256) void head1_kernel(const float* __restrict__ y,
    const float* __restrict__ W, const float* __restrict__ bias, float* __restrict__ h5) {
  __shared__ float yr[1024];
  __shared__ float part[256];
  const int r = blockIdx.x >> 2;
  const int cseg = (blockIdx.x & 3) * 128;
  const int t = threadIdx.x;
  for (int i = t; i < 1024; i += 256) yr[i] = y[(size_t)r*1024 + i];
  __syncthreads();
  const int c = cseg + (t & 127);
  const int kh = t >> 7;               // 0/1: which K half
  const int kbase = kh * 512;
  float a0 = 0.f, a1 = 0.f, a2 = 0.f, a3 = 0.f;
  for (int cin = 0; cin < 512; cin += 4) {
    a0 = fmaf(yr[kbase+cin+0], W[(size_t)(kbase+cin+0)*512 + c], a0);
    a1 = fmaf(yr[kbase+cin+1], W[(size_t)(kbase+cin+1)*512 + c], a1);
    a2 = fmaf(yr[kbase+cin+2], W[(size_t)(kbase+cin+2)*512 + c], a2);
    a3 = fmaf(yr[kbase+cin+3], W[(size_t)(kbase+cin+3)*512 + c], a3);
  }
  part[t] = ((a0 + a1) + (a2 + a3));
  __syncthreads();
  if (t < 128) {
    float acc = bias[c] + part[t] + part[t + 128];
    h5[(size_t)r*512 + c] = fmaxf(acc, 0.f);
  }
}

__global__ void bn_rows_kernel(const float* __restrict__ h, int C, int R,
    const float* __restrict__ g, const float* __restrict__ be, float2* __restrict__ aff) {
  int c = blockIdx.x*256 + threadIdx.x;
  if (c >= C) return;
  double s = 0, ss = 0;
  for (int r = 0; r < R; ++r) {
    double v = (double)h[(size_t)r*C + c];
    s += v; ss += v*v;
  }
  double mean = s / (double)R;
  double var = ss / (double)R - mean*mean;
  var = var < 0.0 ? 0.0 : var;
  double inv = 1.0 / sqrt(var + 1e-5);
  float a = (float)((double)g[c] * inv);
  float off = (float)((double)be[c] - (double)g[c]*mean*inv);
  aff[c] = make_float2(a, off);
}

// R5: one block per row; affine'd h5 row staged in LDS; coalesced W.
__global__ __launch_bounds__(256) void head2_kernel(const float* __restrict__ h5,
    const float2* __restrict__ aff, const float* __restrict__ W,
    const float* __restrict__ bias, float* __restrict__ h6) {
  __shared__ float hr[512];
  const int r = blockIdx.x;            // grid = 32
  const int t = threadIdx.x;
  for (int i = t; i < 512; i += 256) {
    float2 a = aff[i];
    hr[i] = fmaf(a.x, h5[(size_t)r*512 + i], a.y);
  }
  __syncthreads();
  const int c = t;                     // 256 cols
  float a0 = 0.f, a1 = 0.f, a2 = 0.f, a3 = 0.f;
  for (int cin = 0; cin < 512; cin += 4) {
    a0 = fmaf(hr[cin+0], W[(size_t)(cin+0)*256 + c], a0);
    a1 = fmaf(hr[cin+1], W[(size_t)(cin+1)*256 + c], a1);
    a2 = fmaf(hr[cin+2], W[(size_t)(cin+2)*256 + c], a2);
    a3 = fmaf(hr[cin+3], W[(size_t)(cin+3)*256 + c], a3);
  }
  float acc = bias[c] + ((a0 + a1) + (a2 + a3));
  h6[(size_t)r*256 + c] = fmaxf(acc, 0.f);
}

__global__ void head3_kernel(const float* __restrict__ h6, const float2* __restrict__ aff,
    const float* __restrict__ W, const float* __restrict__ bias, float* __restrict__ out) {
  int t = threadIdx.x;
  if (t >= 64) return;
  int r = t >> 1, c = t & 1;
  float acc = bias[c];
  for (int cin = 0; cin < 256; ++cin) {
    float2 a = aff[cin];
    acc = fmaf(fmaf(a.x, h6[(size_t)r*256 + cin], a.y), W[(size_t)cin*2 + c], acc);
  }
  out[(size_t)r*2 + c] = acc;
}

// ------------------------------------------------------------------ launcher
extern "C" void kernel_launch(void* const* d_in, const int* in_sizes, int n_in,
                              void* d_out, int out_size, void* d_ws, size_t ws_size,
                              hipStream_t stream) {
  (void)in_sizes; (void)n_in; (void)out_size; (void)ws_size;
  const float* pos    = (const float*)d_in[0];
  const float* c1_w1  = (const float*)d_in[2];
  const float* c1_b1  = (const float*)d_in[3];
  const float* c1_g1  = (const float*)d_in[4];
  const float* c1_be1 = (const float*)d_in[5];
  const float* c1_w2  = (const float*)d_in[6];
  const float* c1_b2  = (const float*)d_in[7];
  const float* c1_g2  = (const float*)d_in[8];
  const float* c1_be2 = (const float*)d_in[9];
  const float* c1_w3  = (const float*)d_in[10];
  const float* c1_b3  = (const float*)d_in[11];
  const float* c1_g3  = (const float*)d_in[12];
  const float* c1_be3 = (const float*)d_in[13];
  const float* c2_w1  = (const float*)d_in[14];
  const float* c2_b1  = (const float*)d_in[15];
  const float* c2_g1  = (const float*)d_in[16];
  const float* c2_be1 = (const float*)d_in[17];
  const float* l1_w   = (const float*)d_in[18];
  const float* l1_b   = (const float*)d_in[19];
  const float* l1_g   = (const float*)d_in[20];
  const float* l1_be  = (const float*)d_in[21];
  const float* m1_w   = (const float*)d_in[22];
  const float* m1_b   = (const float*)d_in[23];
  const float* m1_g   = (const float*)d_in[24];
  const float* m1_be  = (const float*)d_in[25];
  const float* m2_w   = (const float*)d_in[26];
  const float* m2_b   = (const float*)d_in[27];
  const float* m2_g   = (const float*)d_in[28];
  const float* m2_be  = (const float*)d_in[29];
  const float* m3_w   = (const float*)d_in[30];
  const float* m3_b   = (const float*)d_in[31];

  char* ws = (char*)d_ws;
  size_t off = 0;
  auto alloc = [&](size_t bytes) -> void* {
    void* p = ws + off;
    off += (bytes + 255) & ~(size_t)255;
    return p;
  };
  int*    idx1 = (int*)alloc((size_t)NE * 4);
  int*    idx2 = (int*)alloc((size_t)NE * 4);
  float*  x1   = (float*)alloc((size_t)NPT * 64 * 4);
  float*  x2   = (float*)alloc((size_t)NPT * 128 * 4);
  float*  hA   = (float*)alloc((size_t)NE * 64 * 4);
  float*  hB   = (float*)alloc((size_t)NE * 64 * 4);
  double* psum = (double*)alloc((size_t)1048576 * 8);
  double* psq  = (double*)alloc((size_t)1048576 * 8);
  float*  pmax = (float*)alloc((size_t)1048576 * 4);
  float*  pmin = (float*)alloc((size_t)1048576 * 4);
  float2* affA = (float2*)alloc(64 * 8);
  float2* affB = (float2*)alloc(64 * 8);
  float2* affC = (float2*)alloc(64 * 8);
  float2* aff2 = (float2*)alloc(128 * 8);
  float2* affM1 = (float2*)alloc(512 * 8);
  float2* affM2 = (float2*)alloc(256 * 8);
  float*  y    = (float*)alloc((size_t)NB * 1024 * 4);
  float*  h5   = (float*)alloc((size_t)NB * 512 * 4);
  float*  h6   = (float*)alloc((size_t)NB * 256 * 4);
  float* x2max = hA;
  float* x2min = hA + (size_t)NPT * 128;

  // 1. knn on positions
  knn1_kernel<<<dim3(NB*32), dim3(256), 0, stream>>>(pos, idx1);
  // 2. EdgeConv1 layer1
  ec1_l1_kernel<<<dim3(NE/64), dim3(256), 0, stream>>>(pos, idx1, c1_w1, c1_b1, hA, psum, psq);
  stats_reduce_kernel<<<dim3(64), dim3(256), 0, stream>>>(psum, psq, NE/64, 64, 1.0/NE, c1_g1, c1_be1, affA);
  // 3. layer2
  ec_l64_kernel<<<dim3(NE/64), dim3(256), 0, stream>>>(hA, affA, c1_w2, c1_b2, hB, psum, psq);
  stats_reduce_kernel<<<dim3(64), dim3(256), 0, stream>>>(psum, psq, NE/64, 64, 1.0/NE, c1_g2, c1_be2, affB);
  // 4. layer3
  ec_l64_kernel<<<dim3(NE/64), dim3(256), 0, stream>>>(hB, affB, c1_w3, c1_b3, hA, psum, psq);
  stats_reduce_kernel<<<dim3(64), dim3(256), 0, stream>>>(psum, psq, NE/64, 64, 1.0/NE, c1_g3, c1_be3, affC);
  // 5. max over k -> x1
  ec1_reduce_kernel<<<dim3(NPT*64/256), dim3(256), 0, stream>>>(hA, affC, x1);
  // 6. knn on features
  knn2_kernel<<<dim3(NB*16), dim3(256), 0, stream>>>(x1, idx2);
  // 7. EdgeConv2 (fused k-max/min)
  ec2_kernel<<<dim3(NPT/8), dim3(256), 0, stream>>>(x1, idx2, c2_w1, c2_b1, x2max, x2min, psum, psq);
  stats_reduce_kernel<<<dim3(128), dim3(256), 0, stream>>>(psum, psq, NPT/8, 128, 1.0/NE, c2_g1, c2_be1, aff2);
  ec2_fin_kernel<<<dim3(NPT*128/256), dim3(256), 0, stream>>>(x2max, x2min, aff2, x2);
  // 8. Lin1 fused (R5: 1024 blocks)
  lin1_kernel<<<dim3(NPT/32), dim3(256), 0, stream>>>(x1, x2, l1_w, l1_b, psum, psq, pmax, pmin);
  lin1_fin_kernel<<<dim3(1024), dim3(256), 0, stream>>>(psum, psq, pmax, pmin, l1_g, l1_be, y);
  // 9. head
  head1_kernel<<<dim3(128), dim3(256), 0, stream>>>(y, m1_w, m1_b, h5);
  bn_rows_kernel<<<dim3(2), dim3(256), 0, stream>>>(h5, 512, NB, m1_g, m1_be, affM1);
  head2_kernel<<<dim3(32), dim3(256), 0, stream>>>(h5, affM1, m2_w, m2_b, h6);
  bn_rows_kernel<<<dim3(1), dim3(256), 0, stream>>>(h6, 256, NB, m2_g, m2_be, affM2);
  head3_kernel<<<dim3(1), dim3(64), 0, stream>>>(h6, affM2, m3_w, m3_b, (float*)d_out);
}

// Round 6
// 607.014 us; speedup vs baseline: 7.6661x; 1.1359x over previous
//
#include <hip/hip_runtime.h>

// DGCNN forward: knn(3d) -> EdgeConv(6->64->64->64,BN) -> knn(64d) ->
// EdgeConv(128->128,BN) -> Lin(192->1024)+BN+maxpool -> head MLP -> [32,2]
// R2: stats reductions parallelized (block-per-channel).
// R3: knn2 restructured (spill-free selection).
// R4: knn1 parallelized 8 lanes/query.
// R5: lin1 fp32 re-tiling — NEUTRAL (71% VALU issue ceiling of the fp32
//     structure, not occupancy). heads re-parallelized.
// R6: lin1 -> bf16 MFMA (16x16x32). knn paths and EdgeConv1 chain stay
//     fp32-bit-exact (neighbor indices must match reference). W pre-
//     converted to Wt[1024][192] bf16 for 16B/lane B-frag loads.

#define NB 32
#define NP 1024
#define NPT 32768       // NB*NP
#define KNN 5
#define NE 163840       // NPT*KNN

#define FINF 3.402823466e+38f

typedef __attribute__((ext_vector_type(8))) short bf16x8;
typedef __attribute__((ext_vector_type(4))) float f32x4;

__device__ __forceinline__ bool lex_less(float da, int ja, float db, int jb) {
  return (da < db) || (da == db && ja < jb);
}

__device__ __forceinline__ float f4c(const float4& v, int q) {
  return q == 0 ? v.x : (q == 1 ? v.y : (q == 2 ? v.z : v.w));
}

// f32 -> bf16 (round-to-nearest-even)
__device__ __forceinline__ ushort f2bf(float f) {
  union { float f; unsigned u; } v; v.f = f;
  unsigned r = (v.u + 0x7FFFu + ((v.u >> 16) & 1u)) >> 16;
  return (ushort)r;
}

// insert (dd,jj) into sorted-ascending 5-list held as named scalars
__device__ __forceinline__ void insert5(float& d0, float& d1, float& d2, float& d3, float& d4,
                                        int& j0, int& j1, int& j2, int& j3, int& j4,
                                        float dd, int jj) {
  if (lex_less(dd, jj, d4, j4)) {
    bool L0 = lex_less(dd,jj,d0,j0), L1 = lex_less(dd,jj,d1,j1),
         L2 = lex_less(dd,jj,d2,j2), L3 = lex_less(dd,jj,d3,j3);
    d4 = L3 ? d3 : dd;              j4 = L3 ? j3 : jj;
    d3 = L3 ? (L2 ? d2 : dd) : d3;  j3 = L3 ? (L2 ? j2 : jj) : j3;
    d2 = L2 ? (L1 ? d1 : dd) : d2;  j2 = L2 ? (L1 ? j1 : jj) : j2;
    d1 = L1 ? (L0 ? d0 : dd) : d1;  j1 = L1 ? (L0 ? j0 : jj) : j1;
    d0 = L0 ? dd : d0;              j0 = L0 ? jj : j0;
  }
}

// ---------------------------------------------------------------- knn (3-d)
__global__ __launch_bounds__(256) void knn1_kernel(const float* __restrict__ pos,
                                                   int* __restrict__ knn_idx) {
  __shared__ float4 xs4[NP];    // (x, y, z, |x|^2)
  const int b = blockIdx.x >> 5;
  const int seg = blockIdx.x & 31;
  const int t = threadIdx.x;
  for (int i = t; i < NP; i += 256) {
    float x0 = pos[(size_t)b*NP*3 + i*3 + 0];
    float x1 = pos[(size_t)b*NP*3 + i*3 + 1];
    float x2 = pos[(size_t)b*NP*3 + i*3 + 2];
    float sq = __fadd_rn(__fadd_rn(__fmul_rn(x0,x0), __fmul_rn(x1,x1)), __fmul_rn(x2,x2));
    xs4[i] = make_float4(x0, x1, x2, sq);
  }
  __syncthreads();
  const int q = t >> 3;
  const int ql = t & 7;
  const int i = seg * 32 + q;
  const float4 xi = xs4[i];
  const float sqi = xi.w;
  float d0=FINF,d1=FINF,d2=FINF,d3=FINF,d4=FINF;
  int j0=0x7fffffff,j1=0x7fffffff,j2=0x7fffffff,j3=0x7fffffff,j4=0x7fffffff;
  for (int jj = 0; jj < NP/8; ++jj) {
    const int j = jj*8 + ql;
    float4 v = xs4[j];
    float dot = __fadd_rn(__fadd_rn(__fmul_rn(xi.x,v.x), __fmul_rn(xi.y,v.y)), __fmul_rn(xi.z,v.z));
    float dd = __fsub_rn(__fadd_rn(sqi, v.w), __fmul_rn(2.0f, dot));
    insert5(d0,d1,d2,d3,d4, j0,j1,j2,j3,j4, dd, j);
  }
  #pragma unroll
  for (int m = 1; m <= 4; m <<= 1) {
    float e0 = __shfl_xor(d0, m, 8), e1 = __shfl_xor(d1, m, 8),
          e2 = __shfl_xor(d2, m, 8), e3 = __shfl_xor(d3, m, 8),
          e4 = __shfl_xor(d4, m, 8);
    int   k0 = __shfl_xor(j0, m, 8), k1 = __shfl_xor(j1, m, 8),
          k2 = __shfl_xor(j2, m, 8), k3 = __shfl_xor(j3, m, 8),
          k4 = __shfl_xor(j4, m, 8);
    insert5(d0,d1,d2,d3,d4, j0,j1,j2,j3,j4, e0, k0);
    insert5(d0,d1,d2,d3,d4, j0,j1,j2,j3,j4, e1, k1);
    insert5(d0,d1,d2,d3,d4, j0,j1,j2,j3,j4, e2, k2);
    insert5(d0,d1,d2,d3,d4, j0,j1,j2,j3,j4, e3, k3);
    insert5(d0,d1,d2,d3,d4, j0,j1,j2,j3,j4, e4, k4);
  }
  if (ql == 0) {
    const size_t row = (size_t)b * NP + i;
    knn_idx[row*KNN+0] = b*NP + j0;
    knn_idx[row*KNN+1] = b*NP + j1;
    knn_idx[row*KNN+2] = b*NP + j2;
    knn_idx[row*KNN+3] = b*NP + j3;
    knn_idx[row*KNN+4] = b*NP + j4;
  }
}

// ------------------------------------------- EdgeConv1 layer1 (6 -> 64) + stats
__global__ __launch_bounds__(256) void ec1_l1_kernel(const float* __restrict__ pos,
    const int* __restrict__ knn_idx, const float* __restrict__ W,
    const float* __restrict__ bias, float* __restrict__ hout,
    double* __restrict__ psum, double* __restrict__ psq) {
  __shared__ float ef[64][6];
  __shared__ float Wl[6][64];
  __shared__ float bl[64];
  __shared__ double red[256];
  const int blk = blockIdx.x, t = threadIdx.x;
  const int ebase = blk * 64;
  if (t < 64) {
    int e = ebase + t;
    int ip = e / KNN;
    int jp = knn_idx[e];
    float a0 = pos[(size_t)ip*3+0], a1 = pos[(size_t)ip*3+1], a2 = pos[(size_t)ip*3+2];
    float c0 = pos[(size_t)jp*3+0], c1 = pos[(size_t)jp*3+1], c2 = pos[(size_t)jp*3+2];
    ef[t][0] = a0; ef[t][1] = a1; ef[t][2] = a2;
    ef[t][3] = c0 - a0; ef[t][4] = c1 - a1; ef[t][5] = c2 - a2;
    bl[t] = bias[t];
  }
  for (int idx = t; idx < 6*64; idx += 256) Wl[idx>>6][idx&63] = W[idx];
  __syncthreads();
  const int c = t & 63, rs = t >> 6;
  double s = 0.0, ss = 0.0;
  for (int r = rs; r < 64; r += 4) {
    float acc = bl[c];
    #pragma unroll
    for (int q = 0; q < 6; ++q) acc = fmaf(ef[r][q], Wl[q][c], acc);
    acc = fmaxf(acc, 0.0f);
    hout[(size_t)(ebase + r)*64 + c] = acc;
    s += acc; ss += (double)acc * (double)acc;
  }
  red[t] = s; __syncthreads();
  if (t < 64) psum[(size_t)blk*64 + t] = red[t] + red[t+64] + red[t+128] + red[t+192];
  __syncthreads();
  red[t] = ss; __syncthreads();
  if (t < 64) psq[(size_t)blk*64 + t] = red[t] + red[t+64] + red[t+128] + red[t+192];
}

// ------------------- BN stats -> per-channel affine (block per channel)
__global__ __launch_bounds__(256) void stats_reduce_kernel(const double* __restrict__ psum,
    const double* __restrict__ psq, int nblk, int C, double invN,
    const float* __restrict__ g, const float* __restrict__ be,
    float2* __restrict__ aff) {
  __shared__ double rs[256];
  __shared__ double rq[256];
  const int c = blockIdx.x;          // grid = C
  const int t = threadIdx.x;
  double s = 0.0, ss = 0.0;
  for (int i = t; i < nblk; i += 256) {
    s  += psum[(size_t)i*C + c];
    ss += psq [(size_t)i*C + c];
  }
  rs[t] = s; rq[t] = ss; __syncthreads();
  for (int off = 128; off > 0; off >>= 1) {
    if (t < off) { rs[t] += rs[t+off]; rq[t] += rq[t+off]; }
    __syncthreads();
  }
  if (t == 0) {
    double mean = rs[0] * invN;
    double var = rq[0] * invN - mean*mean;
    var = var < 0.0 ? 0.0 : var;
    double inv = 1.0 / sqrt(var + 1e-5);
    float a = (float)((double)g[c] * inv);
    float off2 = (float)((double)be[c] - (double)g[c] * mean * inv);
    aff[c] = make_float2(a, off2);
  }
}

// -------------------------------- EdgeConv1 layers 2/3 (64 -> 64) + stats
__global__ __launch_bounds__(256) void ec_l64_kernel(const float* __restrict__ hin,
    const float2* __restrict__ affprev, const float* __restrict__ W,
    const float* __restrict__ bias, float* __restrict__ hout,
    double* __restrict__ psum, double* __restrict__ psq) {
  __shared__ float ein[64][68];
  __shared__ float Wl[64][64];
  __shared__ float2 affl[64];
  __shared__ float bl[64];
  __shared__ double redS[16][64];
  __shared__ double redQ[16][64];
  const int blk = blockIdx.x, t = threadIdx.x;
  const size_t ebase = (size_t)blk * 64;
  if (t < 64) { affl[t] = affprev[t]; bl[t] = bias[t]; }
  __syncthreads();
  for (int idx = t; idx < 64*64; idx += 256) {
    int r = idx >> 6, c = idx & 63;
    float2 ac = affl[c];
    ein[r][c] = fmaf(hin[ebase*64 + idx], ac.x, ac.y);
    Wl[r][c] = W[idx];
  }
  __syncthreads();
  const int c4 = t & 15, rs = t >> 4;
  const int cbase = c4 * 4;
  const int rbase = rs * 4;
  float acc[4][4];
  #pragma unroll
  for (int ii = 0; ii < 4; ++ii) {
    #pragma unroll
    for (int jj = 0; jj < 4; ++jj) acc[ii][jj] = bl[cbase + jj];
  }
  for (int cin = 0; cin < 64; cin += 4) {
    float4 fi[4];
    #pragma unroll
    for (int ii = 0; ii < 4; ++ii) fi[ii] = *(const float4*)&ein[rbase+ii][cin];
    #pragma unroll
    for (int q = 0; q < 4; ++q) {
      float4 wv = *(const float4*)&Wl[cin+q][cbase];
      #pragma unroll
      for (int ii = 0; ii < 4; ++ii) {
        float f = f4c(fi[ii], q);
        acc[ii][0] = fmaf(f, wv.x, acc[ii][0]);
        acc[ii][1] = fmaf(f, wv.y, acc[ii][1]);
        acc[ii][2] = fmaf(f, wv.z, acc[ii][2]);
        acc[ii][3] = fmaf(f, wv.w, acc[ii][3]);
      }
    }
  }
  double s[4] = {0,0,0,0}, ss[4] = {0,0,0,0};
  #pragma unroll
  for (int ii = 0; ii < 4; ++ii) {
    float4 h;
    h.x = fmaxf(acc[ii][0], 0.f); h.y = fmaxf(acc[ii][1], 0.f);
    h.z = fmaxf(acc[ii][2], 0.f); h.w = fmaxf(acc[ii][3], 0.f);
    *(float4*)&hout[(ebase + rbase + ii)*64 + cbase] = h;
    s[0]+=h.x; s[1]+=h.y; s[2]+=h.z; s[3]+=h.w;
    ss[0]+=(double)h.x*h.x; ss[1]+=(double)h.y*h.y;
    ss[2]+=(double)h.z*h.z; ss[3]+=(double)h.w*h.w;
  }
  #pragma unroll
  for (int jj = 0; jj < 4; ++jj) { redS[rs][cbase+jj] = s[jj]; redQ[rs][cbase+jj] = ss[jj]; }
  __syncthreads();
  if (t < 64) {
    double a = 0, bq = 0;
    #pragma unroll
    for (int r = 0; r < 16; ++r) { a += redS[r][t]; bq += redQ[r][t]; }
    psum[(size_t)blk*64 + t] = a;
    psq[(size_t)blk*64 + t] = bq;
  }
}

// ------------------------------------ max over k with BN affine (monotone)
__global__ void ec1_reduce_kernel(const float* __restrict__ h3,
    const float2* __restrict__ aff, float* __restrict__ x1) {
  int idx = blockIdx.x * 256 + threadIdx.x;
  if (idx >= NPT * 64) return;
  int p = idx >> 6, c = idx & 63;
  float mx = -FINF, mn = FINF;
  #pragma unroll
  for (int kk = 0; kk < KNN; ++kk) {
    float v = h3[((size_t)p*KNN + kk)*64 + c];
    mx = fmaxf(mx, v); mn = fminf(mn, v);
  }
  float2 ac = aff[c];
  x1[idx] = (ac.x >= 0.f) ? fmaf(ac.x, mx, ac.y) : fmaf(ac.x, mn, ac.y);
}

// ---------------------------------------------------------------- knn (64-d)
__global__ __launch_bounds__(256) void knn2_kernel(const float* __restrict__ x1,
                                                   int* __restrict__ knn_idx) {
  __shared__ float xi[64][68];
  __shared__ float xjd[64][68];   // xj tile, then reused as distance tile
  __shared__ float sqi[64];
  __shared__ float sqj[64];
  const int b = blockIdx.x >> 4;
  const int it = blockIdx.x & 15;
  const int t = threadIdx.x;
  const int ibase = it * 64;  // within batch

  {
    int r = t >> 4, c4 = (t & 15) * 4;
    #pragma unroll
    for (int rr = 0; rr < 4; ++rr) {
      float4 v = *(const float4*)&x1[((size_t)b*NP + ibase + r + 16*rr)*64 + c4];
      *(float4*)&xi[r + 16*rr][c4] = v;
    }
  }
  __syncthreads();
  if (t < 64) {
    float s = 0.f;
    #pragma unroll
    for (int c = 0; c < 64; ++c) s = fmaf(xi[t][c], xi[t][c], s);
    sqi[t] = s;
  }
  __syncthreads();

  const int il = t >> 4, jl = t & 15;      // GEMM mapping
  const int row = t >> 2, ql = t & 3;      // selection mapping
  float si[4];
  #pragma unroll
  for (int ii = 0; ii < 4; ++ii) si[ii] = sqi[il*4 + ii];

  float d0=FINF,d1=FINF,d2=FINF,d3=FINF,d4=FINF;
  int j0=0x7fffffff,j1=0x7fffffff,j2=0x7fffffff,j3=0x7fffffff,j4=0x7fffffff;

  for (int jt = 0; jt < 16; ++jt) {
    __syncthreads();
    {
      int r = t >> 4, c4 = (t & 15) * 4;
      #pragma unroll
      for (int rr = 0; rr < 4; ++rr) {
        float4 v = *(const float4*)&x1[((size_t)b*NP + jt*64 + r + 16*rr)*64 + c4];
        *(float4*)&xjd[r + 16*rr][c4] = v;
      }
    }
    __syncthreads();
    if (t < 64) {
      float s = 0.f;
      #pragma unroll
      for (int c = 0; c < 64; ++c) s = fmaf(xjd[t][c], xjd[t][c], s);
      sqj[t] = s;
    }
    __syncthreads();
    float acc[4][4];
    #pragma unroll
    for (int ii = 0; ii < 4; ++ii) {
      #pragma unroll
      for (int jj = 0; jj < 4; ++jj) acc[ii][jj] = 0.f;
    }
    for (int cin = 0; cin < 64; cin += 4) {
      float4 fi[4], fj[4];
      #pragma unroll
      for (int ii = 0; ii < 4; ++ii) fi[ii] = *(const float4*)&xi[il*4+ii][cin];
      #pragma unroll
      for (int jj = 0; jj < 4; ++jj) fj[jj] = *(const float4*)&xjd[jl + 16*jj][cin];
      #pragma unroll
      for (int q = 0; q < 4; ++q) {
        #pragma unroll
        for (int ii = 0; ii < 4; ++ii) {
          float f = f4c(fi[ii], q);
          acc[ii][0] = fmaf(f, f4c(fj[0],q), acc[ii][0]);
          acc[ii][1] = fmaf(f, f4c(fj[1],q), acc[ii][1]);
          acc[ii][2] = fmaf(f, f4c(fj[2],q), acc[ii][2]);
          acc[ii][3] = fmaf(f, f4c(fj[3],q), acc[ii][3]);
        }
      }
    }
    float sjv[4];
    #pragma unroll
    for (int jj = 0; jj < 4; ++jj) sjv[jj] = sqj[jl + 16*jj];
    __syncthreads();
    #pragma unroll
    for (int ii = 0; ii < 4; ++ii) {
      #pragma unroll
      for (int jj = 0; jj < 4; ++jj) {
        xjd[il*4+ii][jl + 16*jj] = fmaf(-2.f, acc[ii][jj], si[ii] + sjv[jj]);
      }
    }
    __syncthreads();
    const int jgbase = jt*64 + ql*16;
    #pragma unroll
    for (int kk = 0; kk < 4; ++kk) {
      float4 v = *(const float4*)&xjd[row][ql*16 + 4*kk];
      insert5(d0,d1,d2,d3,d4, j0,j1,j2,j3,j4, v.x, jgbase + 4*kk + 0);
      insert5(d0,d1,d2,d3,d4, j0,j1,j2,j3,j4, v.y, jgbase + 4*kk + 1);
      insert5(d0,d1,d2,d3,d4, j0,j1,j2,j3,j4, v.z, jgbase + 4*kk + 2);
      insert5(d0,d1,d2,d3,d4, j0,j1,j2,j3,j4, v.w, jgbase + 4*kk + 3);
    }
  }

  #pragma unroll
  for (int m = 1; m <= 2; m <<= 1) {
    float e0 = __shfl_xor(d0, m, 4), e1 = __shfl_xor(d1, m, 4),
          e2 = __shfl_xor(d2, m, 4), e3 = __shfl_xor(d3, m, 4),
          e4 = __shfl_xor(d4, m, 4);
    int   k0 = __shfl_xor(j0, m, 4), k1 = __shfl_xor(j1, m, 4),
          k2 = __shfl_xor(j2, m, 4), k3 = __shfl_xor(j3, m, 4),
          k4 = __shfl_xor(j4, m, 4);
    insert5(d0,d1,d2,d3,d4, j0,j1,j2,j3,j4, e0, k0);
    insert5(d0,d1,d2,d3,d4, j0,j1,j2,j3,j4, e1, k1);
    insert5(d0,d1,d2,d3,d4, j0,j1,j2,j3,j4, e2, k2);
    insert5(d0,d1,d2,d3,d4, j0,j1,j2,j3,j4, e3, k3);
    insert5(d0,d1,d2,d3,d4, j0,j1,j2,j3,j4, e4, k4);
  }
  if (ql == 0) {
    const size_t orow = ((size_t)b*NP + ibase + row) * KNN;
    knn_idx[orow+0] = b*NP + j0;
    knn_idx[orow+1] = b*NP + j1;
    knn_idx[orow+2] = b*NP + j2;
    knn_idx[orow+3] = b*NP + j3;
    knn_idx[orow+4] = b*NP + j4;
  }
}

// --------------------- EdgeConv2 (128 -> 128) fused with k-max/min + stats
__global__ __launch_bounds__(256) void ec2_kernel(const float* __restrict__ x1,
    const int* __restrict__ knn_idx, const float* __restrict__ W,
    const float* __restrict__ bias, float* __restrict__ x2max,
    float* __restrict__ x2min, double* __restrict__ psum, double* __restrict__ psq) {
  __shared__ float e2[40][128];
  __shared__ double redS[8][128];
  __shared__ double redQ[8][128];
  const int blk = blockIdx.x, t = threadIdx.x;
  const int pbase = blk * 8;
  for (int idx = t; idx < 40*128; idx += 256) {
    int r = idx >> 7, c = idx & 127;
    int p = pbase + r / KNN;
    int kk = r % KNN;
    int j = knn_idx[(size_t)p*KNN + kk];
    float v;
    if (c < 64) v = x1[(size_t)p*64 + c];
    else {
      int cc = c - 64;
      v = x1[(size_t)j*64 + cc] - x1[(size_t)p*64 + cc];
    }
    e2[r][c] = v;
  }
  __syncthreads();
  const int c4 = t & 31, rs = t >> 5;
  const int cbase = c4 * 4;
  float4 bv = *(const float4*)&bias[cbase];
  float acc[5][4];
  #pragma unroll
  for (int kk = 0; kk < 5; ++kk) {
    acc[kk][0]=bv.x; acc[kk][1]=bv.y; acc[kk][2]=bv.z; acc[kk][3]=bv.w;
  }
  for (int cin = 0; cin < 128; cin += 4) {
    float4 fi[5];
    #pragma unroll
    for (int kk = 0; kk < 5; ++kk) fi[kk] = *(const float4*)&e2[rs*5+kk][cin];
    #pragma unroll
    for (int q = 0; q < 4; ++q) {
      float4 wv = *(const float4*)&W[(size_t)(cin+q)*128 + cbase];
      #pragma unroll
      for (int kk = 0; kk < 5; ++kk) {
        float f = f4c(fi[kk], q);
        acc[kk][0] = fmaf(f, wv.x, acc[kk][0]);
        acc[kk][1] = fmaf(f, wv.y, acc[kk][1]);
        acc[kk][2] = fmaf(f, wv.z, acc[kk][2]);
        acc[kk][3] = fmaf(f, wv.w, acc[kk][3]);
      }
    }
  }
  float mx[4] = {-FINF,-FINF,-FINF,-FINF}, mn[4] = {FINF,FINF,FINF,FINF};
  double s[4] = {0,0,0,0}, ss[4] = {0,0,0,0};
  #pragma unroll
  for (int kk = 0; kk < 5; ++kk) {
    #pragma unroll
    for (int jj = 0; jj < 4; ++jj) {
      float h = fmaxf(acc[kk][jj], 0.f);
      mx[jj] = fmaxf(mx[jj], h); mn[jj] = fminf(mn[jj], h);
      s[jj] += h; ss[jj] += (double)h * h;
    }
  }
  *(float4*)&x2max[((size_t)pbase + rs)*128 + cbase] = make_float4(mx[0],mx[1],mx[2],mx[3]);
  *(float4*)&x2min[((size_t)pbase + rs)*128 + cbase] = make_float4(mn[0],mn[1],mn[2],mn[3]);
  #pragma unroll
  for (int jj = 0; jj < 4; ++jj) { redS[rs][cbase+jj] = s[jj]; redQ[rs][cbase+jj] = ss[jj]; }
  __syncthreads();
  if (t < 128) {
    double a = 0, q2 = 0;
    #pragma unroll
    for (int r = 0; r < 8; ++r) { a += redS[r][t]; q2 += redQ[r][t]; }
    psum[(size_t)blk*128 + t] = a;
    psq[(size_t)blk*128 + t] = q2;
  }
}

__global__ void ec2_fin_kernel(const float* __restrict__ x2max,
    const float* __restrict__ x2min, const float2* __restrict__ aff,
    float* __restrict__ x2) {
  int idx = blockIdx.x*256 + threadIdx.x;
  if (idx >= NPT*128) return;
  int c = idx & 127;
  float2 ac = aff[c];
  x2[idx] = (ac.x >= 0.f) ? fmaf(ac.x, x2max[idx], ac.y) : fmaf(ac.x, x2min[idx], ac.y);
}

// ------------------- W[192][1024] f32 -> Wt[1024][192] bf16 (for MFMA B-frags)
__global__ __launch_bounds__(256) void wt_kernel(const float* __restrict__ W,
                                                 ushort* __restrict__ Wt) {
  __shared__ ushort ls[64][192];
  const int cbase = blockIdx.x * 64;   // grid = 16
  const int t = threadIdx.x;
  for (int idx = t; idx < 192 * 64; idx += 256) {
    int cc = idx & 63, k = idx >> 6;
    ls[cc][k] = f2bf(W[(size_t)k * 1024 + cbase + cc]);
  }
  __syncthreads();
  const int c = t >> 2, part = (t & 3) * 48;
  #pragma unroll
  for (int i = 0; i < 6; ++i) {
    *(bf16x8*)&Wt[(size_t)(cbase + c) * 192 + part + i * 8] =
        *(const bf16x8*)&ls[c][part + i * 8];
  }
}

// ------------- Lin1 (192 -> 1024) bf16 MFMA, fused ReLU + stats + max/min
// R6: block = 32 rows; 4 waves x (2 row-tiles x 16 col-tiles) 16x16x32 MFMA.
__global__ __launch_bounds__(256) void lin1_kernel(const float* __restrict__ x1,
    const float* __restrict__ x2, const ushort* __restrict__ Wt,
    const float* __restrict__ bias, double* __restrict__ psum,
    double* __restrict__ psq, float* __restrict__ pmax, float* __restrict__ pmin) {
  __shared__ ushort As[32 * 208];   // 32 rows x 192 bf16, stride 208 (16B-aligned)
  const int blk = blockIdx.x, t = threadIdx.x;
  const int pbase = blk * 32;
  for (int idx = t; idx < 32 * 192; idx += 256) {
    int r = idx / 192, c = idx - r * 192;
    int p = pbase + r;
    float v = (c < 64) ? x1[(size_t)p * 64 + c] : x2[(size_t)p * 128 + (c - 64)];
    As[r * 208 + c] = f2bf(v);
  }
  __syncthreads();
  const int l = t & 63, w = t >> 6;
  const int lr = l & 15, lg = l >> 4;
  const int cbase = w * 256;
  f32x4 acc0[16], acc1[16];
  #pragma unroll
  for (int ct = 0; ct < 16; ++ct) {
    acc0[ct] = (f32x4){0.f, 0.f, 0.f, 0.f};
    acc1[ct] = (f32x4){0.f, 0.f, 0.f, 0.f};
  }
  #pragma unroll
  for (int ks = 0; ks < 6; ++ks) {
    const int k0 = ks * 32;
    bf16x8 a0 = *(const bf16x8*)&As[lr * 208 + k0 + lg * 8];
    bf16x8 a1 = *(const bf16x8*)&As[(16 + lr) * 208 + k0 + lg * 8];
    #pragma unroll
    for (int ct = 0; ct < 16; ++ct) {
      bf16x8 bv = *(const bf16x8*)&Wt[(size_t)(cbase + ct * 16 + lr) * 192 + k0 + lg * 8];
      acc0[ct] = __builtin_amdgcn_mfma_f32_16x16x32_bf16(a0, bv, acc0[ct], 0, 0, 0);
      acc1[ct] = __builtin_amdgcn_mfma_f32_16x16x32_bf16(a1, bv, acc1[ct], 0, 0, 0);
    }
  }
  // epilogue: bias + relu; per-channel {sum,sumsq} (double) + max/min over 32 rows
  #pragma unroll
  for (int ct = 0; ct < 16; ++ct) {
    const int c = cbase + ct * 16 + lr;
    const float bv = bias[c];
    double s = 0.0, ss = 0.0;
    float mx = -FINF, mn = FINF;
    #pragma unroll
    for (int i = 0; i < 4; ++i) {
      float h0 = fmaxf(acc0[ct][i] + bv, 0.f);
      float h1 = fmaxf(acc1[ct][i] + bv, 0.f);
      s += (double)h0 + (double)h1;
      ss += (double)h0 * h0 + (double)h1 * h1;
      mx = fmaxf(mx, fmaxf(h0, h1));
      mn = fminf(mn, fminf(h0, h1));
    }
    s  += __shfl_xor(s, 16);  ss += __shfl_xor(ss, 16);
    mx = fmaxf(mx, __shfl_xor(mx, 16)); mn = fminf(mn, __shfl_xor(mn, 16));
    s  += __shfl_xor(s, 32);  ss += __shfl_xor(ss, 32);
    mx = fmaxf(mx, __shfl_xor(mx, 32)); mn = fminf(mn, __shfl_xor(mn, 32));
    if (lg == 0) {
      psum[(size_t)blk * 1024 + c] = s;
      psq [(size_t)blk * 1024 + c] = ss;
      pmax[(size_t)blk * 1024 + c] = mx;
      pmin[(size_t)blk * 1024 + c] = mn;
    }
  }
}

// ----------------- lin1 BN+maxpool finalize (block per channel; 1024 partials)
__global__ __launch_bounds__(256) void lin1_fin_kernel(const double* __restrict__ psum,
    const double* __restrict__ psq, const float* __restrict__ pmax,
    const float* __restrict__ pmin, const float* __restrict__ g,
    const float* __restrict__ be, float* __restrict__ y) {
  __shared__ double rs[256];
  __shared__ double rq[256];
  __shared__ float smx[32][8];
  __shared__ float smn[32][8];
  __shared__ float sa[2];
  const int c = blockIdx.x;          // grid = 1024
  const int t = threadIdx.x;
  double s = 0.0, ss = 0.0;
  for (int i = t; i < 1024; i += 256) {
    s  += psum[(size_t)i*1024 + c];
    ss += psq [(size_t)i*1024 + c];
  }
  rs[t] = s; rq[t] = ss; __syncthreads();
  for (int off = 128; off > 0; off >>= 1) {
    if (t < off) { rs[t] += rs[t+off]; rq[t] += rq[t+off]; }
    __syncthreads();
  }
  if (t == 0) {
    double mean = rs[0] / 32768.0;
    double var = rq[0] / 32768.0 - mean*mean;
    var = var < 0.0 ? 0.0 : var;
    double inv = 1.0 / sqrt(var + 1e-5);
    sa[0] = (float)((double)g[c] * inv);
    sa[1] = (float)((double)be[c] - (double)g[c]*mean*inv);
  }
  {
    int b = t >> 3, q = t & 7;
    float mxv = -FINF, mnv = FINF;
    #pragma unroll
    for (int k = 0; k < 4; ++k) {
      int i = b*32 + q*4 + k;
      mxv = fmaxf(mxv, pmax[(size_t)i*1024 + c]);
      mnv = fminf(mnv, pmin[(size_t)i*1024 + c]);
    }
    smx[b][q] = mxv;
    smn[b][q] = mnv;
  }
  __syncthreads();
  if (t < 32) {
    float mxv = -FINF, mnv = FINF;
    #pragma unroll
    for (int q = 0; q < 8; ++q) { mxv = fmaxf(mxv, smx[t][q]); mnv = fminf(mnv, smn[t][q]); }
    float a = sa[0], off2 = sa[1];
    y[(size_t)t*1024 + c] = (a >= 0.f) ? fmaf(a, mxv, off2) : fmaf(a, mnv, off2);
  }
}

// ---------------------------------------------------------------- head MLP
__global__ __launch_bounds__(256) void head1_kernel(const float* __restrict__ y,
    const float* __restrict__ W, const float* __restrict__ bias, float* __restrict__ h5) {
  __shared__ float yr[1024];
  __shared__ float part[256];
  const int r = blockIdx.x >> 2;
  const int cseg = (blockIdx.x & 3) * 128;
  const int t = threadIdx.x;
  for (int i = t; i < 1024; i += 256) yr[i] = y[(size_t)r*1024 + i];
  __syncthreads();
  const int c = cseg + (t & 127);
  const int kh = t >> 7;
  const int kbase = kh * 512;
  float a0 = 0.f, a1 = 0.f, a2 = 0.f, a3 = 0.f;
  for (int cin = 0; cin < 512; cin += 4) {
    a0 = fmaf(yr[kbase+cin+0], W[(size_t)(kbase+cin+0)*512 + c], a0);
    a1 = fmaf(yr[kbase+cin+1], W[(size_t)(kbase+cin+1)*512 + c], a1);
    a2 = fmaf(yr[kbase+cin+2], W[(size_t)(kbase+cin+2)*512 + c], a2);
    a3 = fmaf(yr[kbase+cin+3], W[(size_t)(kbase+cin+3)*512 + c], a3);
  }
  part[t] = ((a0 + a1) + (a2 + a3));
  __syncthreads();
  if (t < 128) {
    float acc = bias[c] + part[t] + part[t + 128];
    h5[(size_t)r*512 + c] = fmaxf(acc, 0.f);
  }
}

__global__ void bn_rows_kernel(const float* __restrict__ h, int C, int R,
    const float* __restrict__ g, const float* __restrict__ be, float2* __restrict__ aff) {
  int c = blockIdx.x*256 + threadIdx.x;
  if (c >= C) return;
  double s = 0, ss = 0;
  for (int r = 0; r < R; ++r) {
    double v = (double)h[(size_t)r*C + c];
    s += v; ss += v*v;
  }
  double mean = s / (double)R;
  double var = ss / (double)R - mean*mean;
  var = var < 0.0 ? 0.0 : var;
  double inv = 1.0 / sqrt(var + 1e-5);
  float a = (float)((double)g[c] * inv);
  float off = (float)((double)be[c] - (double)g[c]*mean*inv);
  aff[c] = make_float2(a, off);
}

__global__ __launch_bounds__(256) void head2_kernel(const float* __restrict__ h5,
    const float2* __restrict__ aff, const float* __restrict__ W,
    const float* __restrict__ bias, float* __restrict__ h6) {
  __shared__ float hr[512];
  const int r = blockIdx.x;            // grid = 32
  const int t = threadIdx.x;
  for (int i = t; i < 512; i += 256) {
    float2 a = aff[i];
    hr[i] = fmaf(a.x, h5[(size_t)r*512 + i], a.y);
  }
  __syncthreads();
  const int c = t;
  float a0 = 0.f, a1 = 0.f, a2 = 0.f, a3 = 0.f;
  for (int cin = 0; cin < 512; cin += 4) {
    a0 = fmaf(hr[cin+0], W[(size_t)(cin+0)*256 + c], a0);
    a1 = fmaf(hr[cin+1], W[(size_t)(cin+1)*256 + c], a1);
    a2 = fmaf(hr[cin+2], W[(size_t)(cin+2)*256 + c], a2);
    a3 = fmaf(hr[cin+3], W[(size_t)(cin+3)*256 + c], a3);
  }
  float acc = bias[c] + ((a0 + a1) + (a2 + a3));
  h6[(size_t)r*256 + c] = fmaxf(acc, 0.f);
}

__global__ void head3_kernel(const float* __restrict__ h6, const float2* __restrict__ aff,
    const float* __restrict__ W, const float* __restrict__ bias, float* __restrict__ out) {
  int t = threadIdx.x;
  if (t >= 64) return;
  int r = t >> 1, c = t & 1;
  float acc = bias[c];
  for (int cin = 0; cin < 256; ++cin) {
    float2 a = aff[cin];
    acc = fmaf(fmaf(a.x, h6[(size_t)r*256 + cin], a.y), W[(size_t)cin*2 + c], acc);
  }
  out[(size_t)r*2 + c] = acc;
}

// ------------------------------------------------------------------ launcher
extern "C" void kernel_launch(void* const* d_in, const int* in_sizes, int n_in,
                              void* d_out, int out_size, void* d_ws, size_t ws_size,
                              hipStream_t stream) {
  (void)in_sizes; (void)n_in; (void)out_size; (void)ws_size;
  const float* pos    = (const float*)d_in[0];
  const float* c1_w1  = (const float*)d_in[2];
  const float* c1_b1  = (const float*)d_in[3];
  const float* c1_g1  = (const float*)d_in[4];
  const float* c1_be1 = (const float*)d_in[5];
  const float* c1_w2  = (const float*)d_in[6];
  const float* c1_b2  = (const float*)d_in[7];
  const float* c1_g2  = (const float*)d_in[8];
  const float* c1_be2 = (const float*)d_in[9];
  const float* c1_w3  = (const float*)d_in[10];
  const float* c1_b3  = (const float*)d_in[11];
  const float* c1_g3  = (const float*)d_in[12];
  const float* c1_be3 = (const float*)d_in[13];
  const float* c2_w1  = (const float*)d_in[14];
  const float* c2_b1  = (const float*)d_in[15];
  const float* c2_g1  = (const float*)d_in[16];
  const float* c2_be1 = (const float*)d_in[17];
  const float* l1_w   = (const float*)d_in[18];
  const float* l1_b   = (const float*)d_in[19];
  const float* l1_g   = (const float*)d_in[20];
  const float* l1_be  = (const float*)d_in[21];
  const float* m1_w   = (const float*)d_in[22];
  const float* m1_b   = (const float*)d_in[23];
  const float* m1_g   = (const float*)d_in[24];
  const float* m1_be  = (const float*)d_in[25];
  const float* m2_w   = (const float*)d_in[26];
  const float* m2_b   = (const float*)d_in[27];
  const float* m2_g   = (const float*)d_in[28];
  const float* m2_be  = (const float*)d_in[29];
  const float* m3_w   = (const float*)d_in[30];
  const float* m3_b   = (const float*)d_in[31];

  char* ws = (char*)d_ws;
  size_t off = 0;
  auto alloc = [&](size_t bytes) -> void* {
    void* p = ws + off;
    off += (bytes + 255) & ~(size_t)255;
    return p;
  };
  int*    idx1 = (int*)alloc((size_t)NE * 4);
  int*    idx2 = (int*)alloc((size_t)NE * 4);
  float*  x1   = (float*)alloc((size_t)NPT * 64 * 4);
  float*  x2   = (float*)alloc((size_t)NPT * 128 * 4);
  float*  hA   = (float*)alloc((size_t)NE * 64 * 4);
  float*  hB   = (float*)alloc((size_t)NE * 64 * 4);
  double* psum = (double*)alloc((size_t)1048576 * 8);
  double* psq  = (double*)alloc((size_t)1048576 * 8);
  float*  pmax = (float*)alloc((size_t)1048576 * 4);
  float*  pmin = (float*)alloc((size_t)1048576 * 4);
  float2* affA = (float2*)alloc(64 * 8);
  float2* affB = (float2*)alloc(64 * 8);
  float2* affC = (float2*)alloc(64 * 8);
  float2* aff2 = (float2*)alloc(128 * 8);
  float2* affM1 = (float2*)alloc(512 * 8);
  float2* affM2 = (float2*)alloc(256 * 8);
  float*  y    = (float*)alloc((size_t)NB * 1024 * 4);
  float*  h5   = (float*)alloc((size_t)NB * 512 * 4);
  float*  h6   = (float*)alloc((size_t)NB * 256 * 4);
  ushort* Wt   = (ushort*)alloc((size_t)1024 * 192 * 2);
  float* x2max = hA;
  float* x2min = hA + (size_t)NPT * 128;

  // 0. W -> bf16 transpose (only needs l1_w)
  wt_kernel<<<dim3(16), dim3(256), 0, stream>>>(l1_w, Wt);
  // 1. knn on positions
  knn1_kernel<<<dim3(NB*32), dim3(256), 0, stream>>>(pos, idx1);
  // 2. EdgeConv1 layer1
  ec1_l1_kernel<<<dim3(NE/64), dim3(256), 0, stream>>>(pos, idx1, c1_w1, c1_b1, hA, psum, psq);
  stats_reduce_kernel<<<dim3(64), dim3(256), 0, stream>>>(psum, psq, NE/64, 64, 1.0/NE, c1_g1, c1_be1, affA);
  // 3. layer2
  ec_l64_kernel<<<dim3(NE/64), dim3(256), 0, stream>>>(hA, affA, c1_w2, c1_b2, hB, psum, psq);
  stats_reduce_kernel<<<dim3(64), dim3(256), 0, stream>>>(psum, psq, NE/64, 64, 1.0/NE, c1_g2, c1_be2, affB);
  // 4. layer3
  ec_l64_kernel<<<dim3(NE/64), dim3(256), 0, stream>>>(hB, affB, c1_w3, c1_b3, hA, psum, psq);
  stats_reduce_kernel<<<dim3(64), dim3(256), 0, stream>>>(psum, psq, NE/64, 64, 1.0/NE, c1_g3, c1_be3, affC);
  // 5. max over k -> x1
  ec1_reduce_kernel<<<dim3(NPT*64/256), dim3(256), 0, stream>>>(hA, affC, x1);
  // 6. knn on features
  knn2_kernel<<<dim3(NB*16), dim3(256), 0, stream>>>(x1, idx2);
  // 7. EdgeConv2 (fused k-max/min)
  ec2_kernel<<<dim3(NPT/8), dim3(256), 0, stream>>>(x1, idx2, c2_w1, c2_b1, x2max, x2min, psum, psq);
  stats_reduce_kernel<<<dim3(128), dim3(256), 0, stream>>>(psum, psq, NPT/8, 128, 1.0/NE, c2_g1, c2_be1, aff2);
  ec2_fin_kernel<<<dim3(NPT*128/256), dim3(256), 0, stream>>>(x2max, x2min, aff2, x2);
  // 8. Lin1 bf16-MFMA fused
  lin1_kernel<<<dim3(NPT/32), dim3(256), 0, stream>>>(x1, x2, Wt, l1_b, psum, psq, pmax, pmin);
  lin1_fin_kernel<<<dim3(1024), dim3(256), 0, stream>>>(psum, psq, pmax, pmin, l1_g, l1_be, y);
  // 9. head
  head1_kernel<<<dim3(128), dim3(256), 0, stream>>>(y, m1_w, m1_b, h5);
  bn_rows_kernel<<<dim3(2), dim3(256), 0, stream>>>(h5, 512, NB, m1_g, m1_be, affM1);
  head2_kernel<<<dim3(32), dim3(256), 0, stream>>>(h5, affM1, m2_w, m2_b, h6);
  bn_rows_kernel<<<dim3(1), dim3(256), 0, stream>>>(h6, 256, NB, m2_g, m2_be, affM2);
  head3_kernel<<<dim3(1), dim3(64), 0, stream>>>(h6, affM2, m3_w, m3_b, (float*)d_out);
}

// Round 8
// 586.159 us; speedup vs baseline: 7.9388x; 1.0356x over previous
//
#include <hip/hip_runtime.h>

// DGCNN forward. R2: parallel stats. R3: spill-free knn2 selection.
// R4: knn1 8 lanes/query. R5: heads re-parallelized. R6: lin1 bf16 MFMA
// (absmax 0.039, passes). R7: ec2 bf16 FAILED (0.156>0.101 — two serial
// bf16 GEMMs compound + discrete k-max flips). R8: ec2 reverted to exact
// fp32; KEEP knn2 j-split 2-way + sq precompute + exact lex merge (all
// fp32-bit-identical to the passing R6 ranking path).

#define NB 32
#define NP 1024
#define NPT 32768       // NB*NP
#define KNN 5
#define NE 163840       // NPT*KNN

#define FINF 3.402823466e+38f

typedef __attribute__((ext_vector_type(8))) short bf16x8;
typedef __attribute__((ext_vector_type(4))) float f32x4;

__device__ __forceinline__ bool lex_less(float da, int ja, float db, int jb) {
  return (da < db) || (da == db && ja < jb);
}

__device__ __forceinline__ float f4c(const float4& v, int q) {
  return q == 0 ? v.x : (q == 1 ? v.y : (q == 2 ? v.z : v.w));
}

// f32 -> bf16 (round-to-nearest-even)
__device__ __forceinline__ ushort f2bf(float f) {
  union { float f; unsigned u; } v; v.f = f;
  unsigned r = (v.u + 0x7FFFu + ((v.u >> 16) & 1u)) >> 16;
  return (ushort)r;
}

// insert (dd,jj) into sorted-ascending 5-list held as named scalars
__device__ __forceinline__ void insert5(float& d0, float& d1, float& d2, float& d3, float& d4,
                                        int& j0, int& j1, int& j2, int& j3, int& j4,
                                        float dd, int jj) {
  if (lex_less(dd, jj, d4, j4)) {
    bool L0 = lex_less(dd,jj,d0,j0), L1 = lex_less(dd,jj,d1,j1),
         L2 = lex_less(dd,jj,d2,j2), L3 = lex_less(dd,jj,d3,j3);
    d4 = L3 ? d3 : dd;              j4 = L3 ? j3 : jj;
    d3 = L3 ? (L2 ? d2 : dd) : d3;  j3 = L3 ? (L2 ? j2 : jj) : j3;
    d2 = L2 ? (L1 ? d1 : dd) : d2;  j2 = L2 ? (L1 ? j1 : jj) : j2;
    d1 = L1 ? (L0 ? d0 : dd) : d1;  j1 = L1 ? (L0 ? j0 : jj) : j1;
    d0 = L0 ? dd : d0;              j0 = L0 ? jj : j0;
  }
}

// ---------------------------------------------------------------- knn (3-d)
__global__ __launch_bounds__(256) void knn1_kernel(const float* __restrict__ pos,
                                                   int* __restrict__ knn_idx) {
  __shared__ float4 xs4[NP];    // (x, y, z, |x|^2)
  const int b = blockIdx.x >> 5;
  const int seg = blockIdx.x & 31;
  const int t = threadIdx.x;
  for (int i = t; i < NP; i += 256) {
    float x0 = pos[(size_t)b*NP*3 + i*3 + 0];
    float x1 = pos[(size_t)b*NP*3 + i*3 + 1];
    float x2 = pos[(size_t)b*NP*3 + i*3 + 2];
    float sq = __fadd_rn(__fadd_rn(__fmul_rn(x0,x0), __fmul_rn(x1,x1)), __fmul_rn(x2,x2));
    xs4[i] = make_float4(x0, x1, x2, sq);
  }
  __syncthreads();
  const int q = t >> 3;
  const int ql = t & 7;
  const int i = seg * 32 + q;
  const float4 xi = xs4[i];
  const float sqi = xi.w;
  float d0=FINF,d1=FINF,d2=FINF,d3=FINF,d4=FINF;
  int j0=0x7fffffff,j1=0x7fffffff,j2=0x7fffffff,j3=0x7fffffff,j4=0x7fffffff;
  for (int jj = 0; jj < NP/8; ++jj) {
    const int j = jj*8 + ql;
    float4 v = xs4[j];
    float dot = __fadd_rn(__fadd_rn(__fmul_rn(xi.x,v.x), __fmul_rn(xi.y,v.y)), __fmul_rn(xi.z,v.z));
    float dd = __fsub_rn(__fadd_rn(sqi, v.w), __fmul_rn(2.0f, dot));
    insert5(d0,d1,d2,d3,d4, j0,j1,j2,j3,j4, dd, j);
  }
  #pragma unroll
  for (int m = 1; m <= 4; m <<= 1) {
    float e0 = __shfl_xor(d0, m, 8), e1 = __shfl_xor(d1, m, 8),
          e2 = __shfl_xor(d2, m, 8), e3 = __shfl_xor(d3, m, 8),
          e4 = __shfl_xor(d4, m, 8);
    int   k0 = __shfl_xor(j0, m, 8), k1 = __shfl_xor(j1, m, 8),
          k2 = __shfl_xor(j2, m, 8), k3 = __shfl_xor(j3, m, 8),
          k4 = __shfl_xor(j4, m, 8);
    insert5(d0,d1,d2,d3,d4, j0,j1,j2,j3,j4, e0, k0);
    insert5(d0,d1,d2,d3,d4, j0,j1,j2,j3,j4, e1, k1);
    insert5(d0,d1,d2,d3,d4, j0,j1,j2,j3,j4, e2, k2);
    insert5(d0,d1,d2,d3,d4, j0,j1,j2,j3,j4, e3, k3);
    insert5(d0,d1,d2,d3,d4, j0,j1,j2,j3,j4, e4, k4);
  }
  if (ql == 0) {
    const size_t row = (size_t)b * NP + i;
    knn_idx[row*KNN+0] = b*NP + j0;
    knn_idx[row*KNN+1] = b*NP + j1;
    knn_idx[row*KNN+2] = b*NP + j2;
    knn_idx[row*KNN+3] = b*NP + j3;
    knn_idx[row*KNN+4] = b*NP + j4;
  }
}

// ------------------------------------------- EdgeConv1 layer1 (6 -> 64) + stats
__global__ __launch_bounds__(256) void ec1_l1_kernel(const float* __restrict__ pos,
    const int* __restrict__ knn_idx, const float* __restrict__ W,
    const float* __restrict__ bias, float* __restrict__ hout,
    double* __restrict__ psum, double* __restrict__ psq) {
  __shared__ float ef[64][6];
  __shared__ float Wl[6][64];
  __shared__ float bl[64];
  __shared__ double red[256];
  const int blk = blockIdx.x, t = threadIdx.x;
  const int ebase = blk * 64;
  if (t < 64) {
    int e = ebase + t;
    int ip = e / KNN;
    int jp = knn_idx[e];
    float a0 = pos[(size_t)ip*3+0], a1 = pos[(size_t)ip*3+1], a2 = pos[(size_t)ip*3+2];
    float c0 = pos[(size_t)jp*3+0], c1 = pos[(size_t)jp*3+1], c2 = pos[(size_t)jp*3+2];
    ef[t][0] = a0; ef[t][1] = a1; ef[t][2] = a2;
    ef[t][3] = c0 - a0; ef[t][4] = c1 - a1; ef[t][5] = c2 - a2;
    bl[t] = bias[t];
  }
  for (int idx = t; idx < 6*64; idx += 256) Wl[idx>>6][idx&63] = W[idx];
  __syncthreads();
  const int c = t & 63, rs = t >> 6;
  double s = 0.0, ss = 0.0;
  for (int r = rs; r < 64; r += 4) {
    float acc = bl[c];
    #pragma unroll
    for (int q = 0; q < 6; ++q) acc = fmaf(ef[r][q], Wl[q][c], acc);
    acc = fmaxf(acc, 0.0f);
    hout[(size_t)(ebase + r)*64 + c] = acc;
    s += acc; ss += (double)acc * (double)acc;
  }
  red[t] = s; __syncthreads();
  if (t < 64) psum[(size_t)blk*64 + t] = red[t] + red[t+64] + red[t+128] + red[t+192];
  __syncthreads();
  red[t] = ss; __syncthreads();
  if (t < 64) psq[(size_t)blk*64 + t] = red[t] + red[t+64] + red[t+128] + red[t+192];
}

// ------------------- BN stats -> per-channel affine (block per channel)
__global__ __launch_bounds__(256) void stats_reduce_kernel(const double* __restrict__ psum,
    const double* __restrict__ psq, int nblk, int C, double invN,
    const float* __restrict__ g, const float* __restrict__ be,
    float2* __restrict__ aff) {
  __shared__ double rs[256];
  __shared__ double rq[256];
  const int c = blockIdx.x;          // grid = C
  const int t = threadIdx.x;
  double s = 0.0, ss = 0.0;
  for (int i = t; i < nblk; i += 256) {
    s  += psum[(size_t)i*C + c];
    ss += psq [(size_t)i*C + c];
  }
  rs[t] = s; rq[t] = ss; __syncthreads();
  for (int off = 128; off > 0; off >>= 1) {
    if (t < off) { rs[t] += rs[t+off]; rq[t] += rq[t+off]; }
    __syncthreads();
  }
  if (t == 0) {
    double mean = rs[0] * invN;
    double var = rq[0] * invN - mean*mean;
    var = var < 0.0 ? 0.0 : var;
    double inv = 1.0 / sqrt(var + 1e-5);
    float a = (float)((double)g[c] * inv);
    float off2 = (float)((double)be[c] - (double)g[c] * mean * inv);
    aff[c] = make_float2(a, off2);
  }
}

// -------------------------------- EdgeConv1 layers 2/3 (64 -> 64) + stats
__global__ __launch_bounds__(256) void ec_l64_kernel(const float* __restrict__ hin,
    const float2* __restrict__ affprev, const float* __restrict__ W,
    const float* __restrict__ bias, float* __restrict__ hout,
    double* __restrict__ psum, double* __restrict__ psq) {
  __shared__ float ein[64][68];
  __shared__ float Wl[64][64];
  __shared__ float2 affl[64];
  __shared__ float bl[64];
  __shared__ double redS[16][64];
  __shared__ double redQ[16][64];
  const int blk = blockIdx.x, t = threadIdx.x;
  const size_t ebase = (size_t)blk * 64;
  if (t < 64) { affl[t] = affprev[t]; bl[t] = bias[t]; }
  __syncthreads();
  for (int idx = t; idx < 64*64; idx += 256) {
    int r = idx >> 6, c = idx & 63;
    float2 ac = affl[c];
    ein[r][c] = fmaf(hin[ebase*64 + idx], ac.x, ac.y);
    Wl[r][c] = W[idx];
  }
  __syncthreads();
  const int c4 = t & 15, rs = t >> 4;
  const int cbase = c4 * 4;
  const int rbase = rs * 4;
  float acc[4][4];
  #pragma unroll
  for (int ii = 0; ii < 4; ++ii) {
    #pragma unroll
    for (int jj = 0; jj < 4; ++jj) acc[ii][jj] = bl[cbase + jj];
  }
  for (int cin = 0; cin < 64; cin += 4) {
    float4 fi[4];
    #pragma unroll
    for (int ii = 0; ii < 4; ++ii) fi[ii] = *(const float4*)&ein[rbase+ii][cin];
    #pragma unroll
    for (int q = 0; q < 4; ++q) {
      float4 wv = *(const float4*)&Wl[cin+q][cbase];
      #pragma unroll
      for (int ii = 0; ii < 4; ++ii) {
        float f = f4c(fi[ii], q);
        acc[ii][0] = fmaf(f, wv.x, acc[ii][0]);
        acc[ii][1] = fmaf(f, wv.y, acc[ii][1]);
        acc[ii][2] = fmaf(f, wv.z, acc[ii][2]);
        acc[ii][3] = fmaf(f, wv.w, acc[ii][3]);
      }
    }
  }
  double s[4] = {0,0,0,0}, ss[4] = {0,0,0,0};
  #pragma unroll
  for (int ii = 0; ii < 4; ++ii) {
    float4 h;
    h.x = fmaxf(acc[ii][0], 0.f); h.y = fmaxf(acc[ii][1], 0.f);
    h.z = fmaxf(acc[ii][2], 0.f); h.w = fmaxf(acc[ii][3], 0.f);
    *(float4*)&hout[(ebase + rbase + ii)*64 + cbase] = h;
    s[0]+=h.x; s[1]+=h.y; s[2]+=h.z; s[3]+=h.w;
    ss[0]+=(double)h.x*h.x; ss[1]+=(double)h.y*h.y;
    ss[2]+=(double)h.z*h.z; ss[3]+=(double)h.w*h.w;
  }
  #pragma unroll
  for (int jj = 0; jj < 4; ++jj) { redS[rs][cbase+jj] = s[jj]; redQ[rs][cbase+jj] = ss[jj]; }
  __syncthreads();
  if (t < 64) {
    double a = 0, bq = 0;
    #pragma unroll
    for (int r = 0; r < 16; ++r) { a += redS[r][t]; bq += redQ[r][t]; }
    psum[(size_t)blk*64 + t] = a;
    psq[(size_t)blk*64 + t] = bq;
  }
}

// ------------------------------------ max over k with BN affine (monotone)
__global__ void ec1_reduce_kernel(const float* __restrict__ h3,
    const float2* __restrict__ aff, float* __restrict__ x1) {
  int idx = blockIdx.x * 256 + threadIdx.x;
  if (idx >= NPT * 64) return;
  int p = idx >> 6, c = idx & 63;
  float mx = -FINF, mn = FINF;
  #pragma unroll
  for (int kk = 0; kk < KNN; ++kk) {
    float v = h3[((size_t)p*KNN + kk)*64 + c];
    mx = fmaxf(mx, v); mn = fminf(mn, v);
  }
  float2 ac = aff[c];
  x1[idx] = (ac.x >= 0.f) ? fmaf(ac.x, mx, ac.y) : fmaf(ac.x, mn, ac.y);
}

// ----------------------------- |x1|^2 per point (same fmaf order as before)
__global__ void sq_kernel(const float* __restrict__ x1, float* __restrict__ sqg) {
  int p = blockIdx.x * 256 + threadIdx.x;
  if (p >= NPT) return;
  const float* row = &x1[(size_t)p * 64];
  float s = 0.f;
  #pragma unroll
  for (int c = 0; c < 64; ++c) s = fmaf(row[c], row[c], s);
  sqg[p] = s;
}

// ---------------------------------------------------------------- knn (64-d)
// R7 structure (exact): j-range split in half per block; partial top-5 per
// half to scratch; exact lex-merge in knn2_merge_kernel.
__global__ __launch_bounds__(256) void knn2_kernel(const float* __restrict__ x1,
    const float* __restrict__ sqg, float* __restrict__ kpd, int* __restrict__ kpj) {
  __shared__ float xi[64][68];
  __shared__ float xjd[64][68];   // xj tile, then reused as distance tile
  const int b = blockIdx.x >> 5;
  const int it = (blockIdx.x >> 1) & 15;
  const int half = blockIdx.x & 1;
  const int t = threadIdx.x;
  const int ibase = it * 64;  // within batch

  {
    int r = t >> 4, c4 = (t & 15) * 4;
    #pragma unroll
    for (int rr = 0; rr < 4; ++rr) {
      float4 v = *(const float4*)&x1[((size_t)b*NP + ibase + r + 16*rr)*64 + c4];
      *(float4*)&xi[r + 16*rr][c4] = v;
    }
  }

  const int il = t >> 4, jl = t & 15;      // GEMM mapping
  const int row = t >> 2, ql = t & 3;      // selection mapping
  float si[4];
  #pragma unroll
  for (int ii = 0; ii < 4; ++ii) si[ii] = sqg[(size_t)b*NP + ibase + il*4 + ii];

  float d0=FINF,d1=FINF,d2=FINF,d3=FINF,d4=FINF;
  int j0=0x7fffffff,j1=0x7fffffff,j2=0x7fffffff,j3=0x7fffffff,j4=0x7fffffff;

  for (int jt = 0; jt < 8; ++jt) {
    const int jtg = half * 8 + jt;
    __syncthreads();   // xi staged (first iter) / previous selection done
    {
      int r = t >> 4, c4 = (t & 15) * 4;
      #pragma unroll
      for (int rr = 0; rr < 4; ++rr) {
        float4 v = *(const float4*)&x1[((size_t)b*NP + jtg*64 + r + 16*rr)*64 + c4];
        *(float4*)&xjd[r + 16*rr][c4] = v;
      }
    }
    __syncthreads();
    float acc[4][4];
    #pragma unroll
    for (int ii = 0; ii < 4; ++ii) {
      #pragma unroll
      for (int jj = 0; jj < 4; ++jj) acc[ii][jj] = 0.f;
    }
    for (int cin = 0; cin < 64; cin += 4) {
      float4 fi[4], fj[4];
      #pragma unroll
      for (int ii = 0; ii < 4; ++ii) fi[ii] = *(const float4*)&xi[il*4+ii][cin];
      #pragma unroll
      for (int jj = 0; jj < 4; ++jj) fj[jj] = *(const float4*)&xjd[jl + 16*jj][cin];
      #pragma unroll
      for (int q = 0; q < 4; ++q) {
        #pragma unroll
        for (int ii = 0; ii < 4; ++ii) {
          float f = f4c(fi[ii], q);
          acc[ii][0] = fmaf(f, f4c(fj[0],q), acc[ii][0]);
          acc[ii][1] = fmaf(f, f4c(fj[1],q), acc[ii][1]);
          acc[ii][2] = fmaf(f, f4c(fj[2],q), acc[ii][2]);
          acc[ii][3] = fmaf(f, f4c(fj[3],q), acc[ii][3]);
        }
      }
    }
    float sjv[4];
    #pragma unroll
    for (int jj = 0; jj < 4; ++jj) sjv[jj] = sqg[(size_t)b*NP + jtg*64 + jl + 16*jj];
    __syncthreads();    // everyone done reading xjd as features
    #pragma unroll
    for (int ii = 0; ii < 4; ++ii) {
      #pragma unroll
      for (int jj = 0; jj < 4; ++jj) {
        xjd[il*4+ii][jl + 16*jj] = fmaf(-2.f, acc[ii][jj], si[ii] + sjv[jj]);
      }
    }
    __syncthreads();
    const int jgbase = jtg*64 + ql*16;
    #pragma unroll
    for (int kk = 0; kk < 4; ++kk) {
      float4 v = *(const float4*)&xjd[row][ql*16 + 4*kk];
      insert5(d0,d1,d2,d3,d4, j0,j1,j2,j3,j4, v.x, jgbase + 4*kk + 0);
      insert5(d0,d1,d2,d3,d4, j0,j1,j2,j3,j4, v.y, jgbase + 4*kk + 1);
      insert5(d0,d1,d2,d3,d4, j0,j1,j2,j3,j4, v.z, jgbase + 4*kk + 2);
      insert5(d0,d1,d2,d3,d4, j0,j1,j2,j3,j4, v.w, jgbase + 4*kk + 3);
    }
  }

  #pragma unroll
  for (int m = 1; m <= 2; m <<= 1) {
    float e0 = __shfl_xor(d0, m, 4), e1 = __shfl_xor(d1, m, 4),
          e2 = __shfl_xor(d2, m, 4), e3 = __shfl_xor(d3, m, 4),
          e4 = __shfl_xor(d4, m, 4);
    int   k0 = __shfl_xor(j0, m, 4), k1 = __shfl_xor(j1, m, 4),
          k2 = __shfl_xor(j2, m, 4), k3 = __shfl_xor(j3, m, 4),
          k4 = __shfl_xor(j4, m, 4);
    insert5(d0,d1,d2,d3,d4, j0,j1,j2,j3,j4, e0, k0);
    insert5(d0,d1,d2,d3,d4, j0,j1,j2,j3,j4, e1, k1);
    insert5(d0,d1,d2,d3,d4, j0,j1,j2,j3,j4, e2, k2);
    insert5(d0,d1,d2,d3,d4, j0,j1,j2,j3,j4, e3, k3);
    insert5(d0,d1,d2,d3,d4, j0,j1,j2,j3,j4, e4, k4);
  }
  if (ql == 0) {
    const size_t orow = ((size_t)half*NPT + (size_t)b*NP + ibase + row) * KNN;
    kpd[orow+0] = d0; kpd[orow+1] = d1; kpd[orow+2] = d2; kpd[orow+3] = d3; kpd[orow+4] = d4;
    kpj[orow+0] = j0; kpj[orow+1] = j1; kpj[orow+2] = j2; kpj[orow+3] = j3; kpj[orow+4] = j4;
  }
}

// merge the two sorted half top-5 lists (exact: half0 j < half1 j)
__global__ void knn2_merge_kernel(const float* __restrict__ kpd,
    const int* __restrict__ kpj, int* __restrict__ knn_idx) {
  int r = blockIdx.x * 256 + threadIdx.x;
  if (r >= NPT) return;
  const int b = r >> 10;
  const size_t r0 = (size_t)r * KNN;
  const size_t r1 = ((size_t)NPT + r) * KNN;
  float d0 = kpd[r0+0], d1 = kpd[r0+1], d2 = kpd[r0+2], d3 = kpd[r0+3], d4 = kpd[r0+4];
  int   j0 = kpj[r0+0], j1 = kpj[r0+1], j2 = kpj[r0+2], j3 = kpj[r0+3], j4 = kpj[r0+4];
  #pragma unroll
  for (int s = 0; s < KNN; ++s) {
    insert5(d0,d1,d2,d3,d4, j0,j1,j2,j3,j4, kpd[r1+s], kpj[r1+s]);
  }
  knn_idx[r0+0] = b*NP + j0;
  knn_idx[r0+1] = b*NP + j1;
  knn_idx[r0+2] = b*NP + j2;
  knn_idx[r0+3] = b*NP + j3;
  knn_idx[r0+4] = b*NP + j4;
}

// --------------------- EdgeConv2 (128 -> 128) fp32 (exact) + k-max/min + stats
__global__ __launch_bounds__(256) void ec2_kernel(const float* __restrict__ x1,
    const int* __restrict__ knn_idx, const float* __restrict__ W,
    const float* __restrict__ bias, float* __restrict__ x2max,
    float* __restrict__ x2min, double* __restrict__ psum, double* __restrict__ psq) {
  __shared__ float e2[40][128];
  __shared__ double redS[8][128];
  __shared__ double redQ[8][128];
  const int blk = blockIdx.x, t = threadIdx.x;
  const int pbase = blk * 8;
  for (int idx = t; idx < 40*128; idx += 256) {
    int r = idx >> 7, c = idx & 127;
    int p = pbase + r / KNN;
    int kk = r % KNN;
    int j = knn_idx[(size_t)p*KNN + kk];
    float v;
    if (c < 64) v = x1[(size_t)p*64 + c];
    else {
      int cc = c - 64;
      v = x1[(size_t)j*64 + cc] - x1[(size_t)p*64 + cc];
    }
    e2[r][c] = v;
  }
  __syncthreads();
  const int c4 = t & 31, rs = t >> 5;
  const int cbase = c4 * 4;
  float4 bv = *(const float4*)&bias[cbase];
  float acc[5][4];
  #pragma unroll
  for (int kk = 0; kk < 5; ++kk) {
    acc[kk][0]=bv.x; acc[kk][1]=bv.y; acc[kk][2]=bv.z; acc[kk][3]=bv.w;
  }
  for (int cin = 0; cin < 128; cin += 4) {
    float4 fi[5];
    #pragma unroll
    for (int kk = 0; kk < 5; ++kk) fi[kk] = *(const float4*)&e2[rs*5+kk][cin];
    #pragma unroll
    for (int q = 0; q < 4; ++q) {
      float4 wv = *(const float4*)&W[(size_t)(cin+q)*128 + cbase];
      #pragma unroll
      for (int kk = 0; kk < 5; ++kk) {
        float f = f4c(fi[kk], q);
        acc[kk][0] = fmaf(f, wv.x, acc[kk][0]);
        acc[kk][1] = fmaf(f, wv.y, acc[kk][1]);
        acc[kk][2] = fmaf(f, wv.z, acc[kk][2]);
        acc[kk][3] = fmaf(f, wv.w, acc[kk][3]);
      }
    }
  }
  float mx[4] = {-FINF,-FINF,-FINF,-FINF}, mn[4] = {FINF,FINF,FINF,FINF};
  double s[4] = {0,0,0,0}, ss[4] = {0,0,0,0};
  #pragma unroll
  for (int kk = 0; kk < 5; ++kk) {
    #pragma unroll
    for (int jj = 0; jj < 4; ++jj) {
      float h = fmaxf(acc[kk][jj], 0.f);
      mx[jj] = fmaxf(mx[jj], h); mn[jj] = fminf(mn[jj], h);
      s[jj] += h; ss[jj] += (double)h * h;
    }
  }
  *(float4*)&x2max[((size_t)pbase + rs)*128 + cbase] = make_float4(mx[0],mx[1],mx[2],mx[3]);
  *(float4*)&x2min[((size_t)pbase + rs)*128 + cbase] = make_float4(mn[0],mn[1],mn[2],mn[3]);
  #pragma unroll
  for (int jj = 0; jj < 4; ++jj) { redS[rs][cbase+jj] = s[jj]; redQ[rs][cbase+jj] = ss[jj]; }
  __syncthreads();
  if (t < 128) {
    double a = 0, q2 = 0;
    #pragma unroll
    for (int r = 0; r < 8; ++r) { a += redS[r][t]; q2 += redQ[r][t]; }
    psum[(size_t)blk*128 + t] = a;
    psq[(size_t)blk*128 + t] = q2;
  }
}

__global__ void ec2_fin_kernel(const float* __restrict__ x2max,
    const float* __restrict__ x2min, const float2* __restrict__ aff,
    float* __restrict__ x2) {
  int idx = blockIdx.x*256 + threadIdx.x;
  if (idx >= NPT*128) return;
  int c = idx & 127;
  float2 ac = aff[c];
  x2[idx] = (ac.x >= 0.f) ? fmaf(ac.x, x2max[idx], ac.y) : fmaf(ac.x, x2min[idx], ac.y);
}

// ------------------- W[192][1024] f32 -> Wt[1024][192] bf16 (lin1 B-frags)
__global__ __launch_bounds__(256) void wt_kernel(const float* __restrict__ W,
                                                 ushort* __restrict__ Wt) {
  __shared__ ushort ls[64][192];
  const int cbase = blockIdx.x * 64;   // grid = 16
  const int t = threadIdx.x;
  for (int idx = t; idx < 192 * 64; idx += 256) {
    int cc = idx & 63, k = idx >> 6;
    ls[cc][k] = f2bf(W[(size_t)k * 1024 + cbase + cc]);
  }
  __syncthreads();
  const int c = t >> 2, part = (t & 3) * 48;
  #pragma unroll
  for (int i = 0; i < 6; ++i) {
    *(bf16x8*)&Wt[(size_t)(cbase + c) * 192 + part + i * 8] =
        *(const bf16x8*)&ls[c][part + i * 8];
  }
}

// ------------- Lin1 (192 -> 1024) bf16 MFMA, fused ReLU + stats + max/min
__global__ __launch_bounds__(256) void lin1_kernel(const float* __restrict__ x1,
    const float* __restrict__ x2, const ushort* __restrict__ Wt,
    const float* __restrict__ bias, double* __restrict__ psum,
    double* __restrict__ psq, float* __restrict__ pmax, float* __restrict__ pmin) {
  __shared__ ushort As[32 * 208];   // 32 rows x 192 bf16, stride 208
  const int blk = blockIdx.x, t = threadIdx.x;
  const int pbase = blk * 32;
  for (int idx = t; idx < 32 * 192; idx += 256) {
    int r = idx / 192, c = idx - r * 192;
    int p = pbase + r;
    float v = (c < 64) ? x1[(size_t)p * 64 + c] : x2[(size_t)p * 128 + (c - 64)];
    As[r * 208 + c] = f2bf(v);
  }
  __syncthreads();
  const int l = t & 63, w = t >> 6;
  const int lr = l & 15, lg = l >> 4;
  const int cbase = w * 256;
  f32x4 acc0[16], acc1[16];
  #pragma unroll
  for (int ct = 0; ct < 16; ++ct) {
    acc0[ct] = (f32x4){0.f, 0.f, 0.f, 0.f};
    acc1[ct] = (f32x4){0.f, 0.f, 0.f, 0.f};
  }
  #pragma unroll
  for (int ks = 0; ks < 6; ++ks) {
    const int k0 = ks * 32;
    bf16x8 a0 = *(const bf16x8*)&As[lr * 208 + k0 + lg * 8];
    bf16x8 a1 = *(const bf16x8*)&As[(16 + lr) * 208 + k0 + lg * 8];
    #pragma unroll
    for (int ct = 0; ct < 16; ++ct) {
      bf16x8 bv = *(const bf16x8*)&Wt[(size_t)(cbase + ct * 16 + lr) * 192 + k0 + lg * 8];
      acc0[ct] = __builtin_amdgcn_mfma_f32_16x16x32_bf16(a0, bv, acc0[ct], 0, 0, 0);
      acc1[ct] = __builtin_amdgcn_mfma_f32_16x16x32_bf16(a1, bv, acc1[ct], 0, 0, 0);
    }
  }
  #pragma unroll
  for (int ct = 0; ct < 16; ++ct) {
    const int c = cbase + ct * 16 + lr;
    const float bv = bias[c];
    double s = 0.0, ss = 0.0;
    float mx = -FINF, mn = FINF;
    #pragma unroll
    for (int i = 0; i < 4; ++i) {
      float h0 = fmaxf(acc0[ct][i] + bv, 0.f);
      float h1 = fmaxf(acc1[ct][i] + bv, 0.f);
      s += (double)h0 + (double)h1;
      ss += (double)h0 * h0 + (double)h1 * h1;
      mx = fmaxf(mx, fmaxf(h0, h1));
      mn = fminf(mn, fminf(h0, h1));
    }
    s  += __shfl_xor(s, 16);  ss += __shfl_xor(ss, 16);
    mx = fmaxf(mx, __shfl_xor(mx, 16)); mn = fminf(mn, __shfl_xor(mn, 16));
    s  += __shfl_xor(s, 32);  ss += __shfl_xor(ss, 32);
    mx = fmaxf(mx, __shfl_xor(mx, 32)); mn = fminf(mn, __shfl_xor(mn, 32));
    if (lg == 0) {
      psum[(size_t)blk * 1024 + c] = s;
      psq [(size_t)blk * 1024 + c] = ss;
      pmax[(size_t)blk * 1024 + c] = mx;
      pmin[(size_t)blk * 1024 + c] = mn;
    }
  }
}

// ----------------- lin1 BN+maxpool finalize (block per channel; 1024 partials)
__global__ __launch_bounds__(256) void lin1_fin_kernel(const double* __restrict__ psum,
    const double* __restrict__ psq, const float* __restrict__ pmax,
    const float* __restrict__ pmin, const float* __restrict__ g,
    const float* __restrict__ be, float* __restrict__ y) {
  __shared__ double rs[256];
  __shared__ double rq[256];
  __shared__ float smx[32][8];
  __shared__ float smn[32][8];
  __shared__ float sa[2];
  const int c = blockIdx.x;          // grid = 1024
  const int t = threadIdx.x;
  double s = 0.0, ss = 0.0;
  for (int i = t; i < 1024; i += 256) {
    s  += psum[(size_t)i*1024 + c];
    ss += psq [(size_t)i*1024 + c];
  }
  rs[t] = s; rq[t] = ss; __syncthreads();
  for (int off = 128; off > 0; off >>= 1) {
    if (t < off) { rs[t] += rs[t+off]; rq[t] += rq[t+off]; }
    __syncthreads();
  }
  if (t == 0) {
    double mean = rs[0] / 32768.0;
    double var = rq[0] / 32768.0 - mean*mean;
    var = var < 0.0 ? 0.0 : var;
    double inv = 1.0 / sqrt(var + 1e-5);
    sa[0] = (float)((double)g[c] * inv);
    sa[1] = (float)((double)be[c] - (double)g[c]*mean*inv);
  }
  {
    int b = t >> 3, q = t & 7;
    float mxv = -FINF, mnv = FINF;
    #pragma unroll
    for (int k = 0; k < 4; ++k) {
      int i = b*32 + q*4 + k;
      mxv = fmaxf(mxv, pmax[(size_t)i*1024 + c]);
      mnv = fminf(mnv, pmin[(size_t)i*1024 + c]);
    }
    smx[b][q] = mxv;
    smn[b][q] = mnv;
  }
  __syncthreads();
  if (t < 32) {
    float mxv = -FINF, mnv = FINF;
    #pragma unroll
    for (int q = 0; q < 8; ++q) { mxv = fmaxf(mxv, smx[t][q]); mnv = fminf(mnv, smn[t][q]); }
    float a = sa[0], off2 = sa[1];
    y[(size_t)t*1024 + c] = (a >= 0.f) ? fmaf(a, mxv, off2) : fmaf(a, mnv, off2);
  }
}

// ---------------------------------------------------------------- head MLP
__global__ __launch_bounds__(256) void head1_kernel(const float* __restrict__ y,
    const float* __restrict__ W, const float* __restrict__ bias, float* __restrict__ h5) {
  __shared__ float yr[1024];
  __shared__ float part[256];
  const int r = blockIdx.x >> 2;
  const int cseg = (blockIdx.x & 3) * 128;
  const int t = threadIdx.x;
  for (int i = t; i < 1024; i += 256) yr[i] = y[(size_t)r*1024 + i];
  __syncthreads();
  const int c = cseg + (t & 127);
  const int kh = t >> 7;
  const int kbase = kh * 512;
  float a0 = 0.f, a1 = 0.f, a2 = 0.f, a3 = 0.f;
  for (int cin = 0; cin < 512; cin += 4) {
    a0 = fmaf(yr[kbase+cin+0], W[(size_t)(kbase+cin+0)*512 + c], a0);
    a1 = fmaf(yr[kbase+cin+1], W[(size_t)(kbase+cin+1)*512 + c], a1);
    a2 = fmaf(yr[kbase+cin+2], W[(size_t)(kbase+cin+2)*512 + c], a2);
    a3 = fmaf(yr[kbase+cin+3], W[(size_t)(kbase+cin+3)*512 + c], a3);
  }
  part[t] = ((a0 + a1) + (a2 + a3));
  __syncthreads();
  if (t < 128) {
    float acc = bias[c] + part[t] + part[t + 128];
    h5[(size_t)r*512 + c] = fmaxf(acc, 0.f);
  }
}

__global__ void bn_rows_kernel(const float* __restrict__ h, int C, int R,
    const float* __restrict__ g, const float* __restrict__ be, float2* __restrict__ aff) {
  int c = blockIdx.x*256 + threadIdx.x;
  if (c >= C) return;
  double s = 0, ss = 0;
  for (int r = 0; r < R; ++r) {
    double v = (double)h[(size_t)r*C + c];
    s += v; ss += v*v;
  }
  double mean = s / (double)R;
  double var = ss / (double)R - mean*mean;
  var = var < 0.0 ? 0.0 : var;
  double inv = 1.0 / sqrt(var + 1e-5);
  float a = (float)((double)g[c] * inv);
  float off = (float)((double)be[c] - (double)g[c]*mean*inv);
  aff[c] = make_float2(a, off);
}

__global__ __launch_bounds__(256) void head2_kernel(const float* __restrict__ h5,
    const float2* __restrict__ aff, const float* __restrict__ W,
    const float* __restrict__ bias, float* __restrict__ h6) {
  __shared__ float hr[512];
  const int r = blockIdx.x;            // grid = 32
  const int t = threadIdx.x;
  for (int i = t; i < 512; i += 256) {
    float2 a = aff[i];
    hr[i] = fmaf(a.x, h5[(size_t)r*512 + i], a.y);
  }
  __syncthreads();
  const int c = t;
  float a0 = 0.f, a1 = 0.f, a2 = 0.f, a3 = 0.f;
  for (int cin = 0; cin < 512; cin += 4) {
    a0 = fmaf(hr[cin+0], W[(size_t)(cin+0)*256 + c], a0);
    a1 = fmaf(hr[cin+1], W[(size_t)(cin+1)*256 + c], a1);
    a2 = fmaf(hr[cin+2], W[(size_t)(cin+2)*256 + c], a2);
    a3 = fmaf(hr[cin+3], W[(size_t)(cin+3)*256 + c], a3);
  }
  float acc = bias[c] + ((a0 + a1) + (a2 + a3));
  h6[(size_t)r*256 + c] = fmaxf(acc, 0.f);
}

__global__ void head3_kernel(const float* __restrict__ h6, const float2* __restrict__ aff,
    const float* __restrict__ W, const float* __restrict__ bias, float* __restrict__ out) {
  int t = threadIdx.x;
  if (t >= 64) return;
  int r = t >> 1, c = t & 1;
  float acc = bias[c];
  for (int cin = 0; cin < 256; ++cin) {
    float2 a = aff[cin];
    acc = fmaf(fmaf(a.x, h6[(size_t)r*256 + cin], a.y), W[(size_t)cin*2 + c], acc);
  }
  out[(size_t)r*2 + c] = acc;
}

// ------------------------------------------------------------------ launcher
extern "C" void kernel_launch(void* const* d_in, const int* in_sizes, int n_in,
                              void* d_out, int out_size, void* d_ws, size_t ws_size,
                              hipStream_t stream) {
  (void)in_sizes; (void)n_in; (void)out_size; (void)ws_size;
  const float* pos    = (const float*)d_in[0];
  const float* c1_w1  = (const float*)d_in[2];
  const float* c1_b1  = (const float*)d_in[3];
  const float* c1_g1  = (const float*)d_in[4];
  const float* c1_be1 = (const float*)d_in[5];
  const float* c1_w2  = (const float*)d_in[6];
  const float* c1_b2  = (const float*)d_in[7];
  const float* c1_g2  = (const float*)d_in[8];
  const float* c1_be2 = (const float*)d_in[9];
  const float* c1_w3  = (const float*)d_in[10];
  const float* c1_b3  = (const float*)d_in[11];
  const float* c1_g3  = (const float*)d_in[12];
  const float* c1_be3 = (const float*)d_in[13];
  const float* c2_w1  = (const float*)d_in[14];
  const float* c2_b1  = (const float*)d_in[15];
  const float* c2_g1  = (const float*)d_in[16];
  const float* c2_be1 = (const float*)d_in[17];
  const float* l1_w   = (const float*)d_in[18];
  const float* l1_b   = (const float*)d_in[19];
  const float* l1_g   = (const float*)d_in[20];
  const float* l1_be  = (const float*)d_in[21];
  const float* m1_w   = (const float*)d_in[22];
  const float* m1_b   = (const float*)d_in[23];
  const float* m1_g   = (const float*)d_in[24];
  const float* m1_be  = (const float*)d_in[25];
  const float* m2_w   = (const float*)d_in[26];
  const float* m2_b   = (const float*)d_in[27];
  const float* m2_g   = (const float*)d_in[28];
  const float* m2_be  = (const float*)d_in[29];
  const float* m3_w   = (const float*)d_in[30];
  const float* m3_b   = (const float*)d_in[31];

  char* ws = (char*)d_ws;
  size_t off = 0;
  auto alloc = [&](size_t bytes) -> void* {
    void* p = ws + off;
    off += (bytes + 255) & ~(size_t)255;
    return p;
  };
  int*    idx1 = (int*)alloc((size_t)NE * 4);
  int*    idx2 = (int*)alloc((size_t)NE * 4);
  float*  x1   = (float*)alloc((size_t)NPT * 64 * 4);
  float*  x2   = (float*)alloc((size_t)NPT * 128 * 4);
  float*  hA   = (float*)alloc((size_t)NE * 64 * 4);
  float*  hB   = (float*)alloc((size_t)NE * 64 * 4);
  double* psum = (double*)alloc((size_t)1048576 * 8);
  double* psq  = (double*)alloc((size_t)1048576 * 8);
  float*  pmax = (float*)alloc((size_t)1048576 * 4);
  float*  pmin = (float*)alloc((size_t)1048576 * 4);
  float2* affA = (float2*)alloc(64 * 8);
  float2* affB = (float2*)alloc(64 * 8);
  float2* affC = (float2*)alloc(64 * 8);
  float2* aff2 = (float2*)alloc(128 * 8);
  float2* affM1 = (float2*)alloc(512 * 8);
  float2* affM2 = (float2*)alloc(256 * 8);
  float*  y    = (float*)alloc((size_t)NB * 1024 * 4);
  float*  h5   = (float*)alloc((size_t)NB * 512 * 4);
  float*  h6   = (float*)alloc((size_t)NB * 256 * 4);
  ushort* Wt   = (ushort*)alloc((size_t)1024 * 192 * 2);
  float*  sqg  = (float*)alloc((size_t)NPT * 4);
  float*  kpd  = (float*)alloc((size_t)2 * NPT * KNN * 4);
  int*    kpj  = (int*)alloc((size_t)2 * NPT * KNN * 4);
  float* x2max = hA;
  float* x2min = hA + (size_t)NPT * 128;

  // 0. weight conversion (lin1 only)
  wt_kernel<<<dim3(16), dim3(256), 0, stream>>>(l1_w, Wt);
  // 1. knn on positions
  knn1_kernel<<<dim3(NB*32), dim3(256), 0, stream>>>(pos, idx1);
  // 2. EdgeConv1 layer1
  ec1_l1_kernel<<<dim3(NE/64), dim3(256), 0, stream>>>(pos, idx1, c1_w1, c1_b1, hA, psum, psq);
  stats_reduce_kernel<<<dim3(64), dim3(256), 0, stream>>>(psum, psq, NE/64, 64, 1.0/NE, c1_g1, c1_be1, affA);
  // 3. layer2
  ec_l64_kernel<<<dim3(NE/64), dim3(256), 0, stream>>>(hA, affA, c1_w2, c1_b2, hB, psum, psq);
  stats_reduce_kernel<<<dim3(64), dim3(256), 0, stream>>>(psum, psq, NE/64, 64, 1.0/NE, c1_g2, c1_be2, affB);
  // 4. layer3
  ec_l64_kernel<<<dim3(NE/64), dim3(256), 0, stream>>>(hB, affB, c1_w3, c1_b3, hA, psum, psq);
  stats_reduce_kernel<<<dim3(64), dim3(256), 0, stream>>>(psum, psq, NE/64, 64, 1.0/NE, c1_g3, c1_be3, affC);
  // 5. max over k -> x1
  ec1_reduce_kernel<<<dim3(NPT*64/256), dim3(256), 0, stream>>>(hA, affC, x1);
  // 6. knn on features (sq precompute + j-split + exact merge)
  sq_kernel<<<dim3(NPT/256), dim3(256), 0, stream>>>(x1, sqg);
  knn2_kernel<<<dim3(NB*32), dim3(256), 0, stream>>>(x1, sqg, kpd, kpj);
  knn2_merge_kernel<<<dim3(NPT/256), dim3(256), 0, stream>>>(kpd, kpj, idx2);
  // 7. EdgeConv2 fp32 (exact; fused k-max/min)
  ec2_kernel<<<dim3(NPT/8), dim3(256), 0, stream>>>(x1, idx2, c2_w1, c2_b1, x2max, x2min, psum, psq);
  stats_reduce_kernel<<<dim3(128), dim3(256), 0, stream>>>(psum, psq, NPT/8, 128, 1.0/NE, c2_g1, c2_be1, aff2);
  ec2_fin_kernel<<<dim3(NPT*128/256), dim3(256), 0, stream>>>(x2max, x2min, aff2, x2);
  // 8. Lin1 bf16-MFMA fused
  lin1_kernel<<<dim3(NPT/32), dim3(256), 0, stream>>>(x1, x2, Wt, l1_b, psum, psq, pmax, pmin);
  lin1_fin_kernel<<<dim3(1024), dim3(256), 0, stream>>>(psum, psq, pmax, pmin, l1_g, l1_be, y);
  // 9. head
  head1_kernel<<<dim3(128), dim3(256), 0, stream>>>(y, m1_w, m1_b, h5);
  bn_rows_kernel<<<dim3(2), dim3(256), 0, stream>>>(h5, 512, NB, m1_g, m1_be, affM1);
  head2_kernel<<<dim3(32), dim3(256), 0, stream>>>(h5, affM1, m2_w, m2_b, h6);
  bn_rows_kernel<<<dim3(1), dim3(256), 0, stream>>>(h6, 256, NB, m2_g, m2_be, affM2);
  head3_kernel<<<dim3(1), dim3(64), 0, stream>>>(h6, affM2, m3_w, m3_b, (float*)d_out);
}

// Round 9
// 564.940 us; speedup vs baseline: 8.2370x; 1.0376x over previous
//
#include <hip/hip_runtime.h>

// DGCNN forward. R2: parallel stats. R3: spill-free knn2 selection.
// R4: knn1 8 lanes/query. R5: heads re-parallelized. R6: lin1 bf16 MFMA
// (absmax 0.039). R7: ec2 bf16 FAILED (serial bf16 GEMMs compound).
// R8: ec2 fp32 + knn2 j-split kept (586us).
// R9: ec2 fp32 restructured — 2 points/thread (16 pts/block): W-load per
// FLOP halved (was VALUBusy 46%, L2-latency bound at 4 loads per 160cy
// FMA); stats scratch aliased onto dead e2 LDS so occupancy stays
// 4 blocks/CU. Per-accumulator FMA order unchanged => bit-identical ec2.

#define NB 32
#define NP 1024
#define NPT 32768       // NB*NP
#define KNN 5
#define NE 163840       // NPT*KNN

#define FINF 3.402823466e+38f

typedef __attribute__((ext_vector_type(8))) short bf16x8;
typedef __attribute__((ext_vector_type(4))) float f32x4;

__device__ __forceinline__ bool lex_less(float da, int ja, float db, int jb) {
  return (da < db) || (da == db && ja < jb);
}

__device__ __forceinline__ float f4c(const float4& v, int q) {
  return q == 0 ? v.x : (q == 1 ? v.y : (q == 2 ? v.z : v.w));
}

// f32 -> bf16 (round-to-nearest-even)
__device__ __forceinline__ ushort f2bf(float f) {
  union { float f; unsigned u; } v; v.f = f;
  unsigned r = (v.u + 0x7FFFu + ((v.u >> 16) & 1u)) >> 16;
  return (ushort)r;
}

// insert (dd,jj) into sorted-ascending 5-list held as named scalars
__device__ __forceinline__ void insert5(float& d0, float& d1, float& d2, float& d3, float& d4,
                                        int& j0, int& j1, int& j2, int& j3, int& j4,
                                        float dd, int jj) {
  if (lex_less(dd, jj, d4, j4)) {
    bool L0 = lex_less(dd,jj,d0,j0), L1 = lex_less(dd,jj,d1,j1),
         L2 = lex_less(dd,jj,d2,j2), L3 = lex_less(dd,jj,d3,j3);
    d4 = L3 ? d3 : dd;              j4 = L3 ? j3 : jj;
    d3 = L3 ? (L2 ? d2 : dd) : d3;  j3 = L3 ? (L2 ? j2 : jj) : j3;
    d2 = L2 ? (L1 ? d1 : dd) : d2;  j2 = L2 ? (L1 ? j1 : jj) : j2;
    d1 = L1 ? (L0 ? d0 : dd) : d1;  j1 = L1 ? (L0 ? j0 : jj) : j1;
    d0 = L0 ? dd : d0;              j0 = L0 ? jj : j0;
  }
}

// ---------------------------------------------------------------- knn (3-d)
__global__ __launch_bounds__(256) void knn1_kernel(const float* __restrict__ pos,
                                                   int* __restrict__ knn_idx) {
  __shared__ float4 xs4[NP];    // (x, y, z, |x|^2)
  const int b = blockIdx.x >> 5;
  const int seg = blockIdx.x & 31;
  const int t = threadIdx.x;
  for (int i = t; i < NP; i += 256) {
    float x0 = pos[(size_t)b*NP*3 + i*3 + 0];
    float x1 = pos[(size_t)b*NP*3 + i*3 + 1];
    float x2 = pos[(size_t)b*NP*3 + i*3 + 2];
    float sq = __fadd_rn(__fadd_rn(__fmul_rn(x0,x0), __fmul_rn(x1,x1)), __fmul_rn(x2,x2));
    xs4[i] = make_float4(x0, x1, x2, sq);
  }
  __syncthreads();
  const int q = t >> 3;
  const int ql = t & 7;
  const int i = seg * 32 + q;
  const float4 xi = xs4[i];
  const float sqi = xi.w;
  float d0=FINF,d1=FINF,d2=FINF,d3=FINF,d4=FINF;
  int j0=0x7fffffff,j1=0x7fffffff,j2=0x7fffffff,j3=0x7fffffff,j4=0x7fffffff;
  for (int jj = 0; jj < NP/8; ++jj) {
    const int j = jj*8 + ql;
    float4 v = xs4[j];
    float dot = __fadd_rn(__fadd_rn(__fmul_rn(xi.x,v.x), __fmul_rn(xi.y,v.y)), __fmul_rn(xi.z,v.z));
    float dd = __fsub_rn(__fadd_rn(sqi, v.w), __fmul_rn(2.0f, dot));
    insert5(d0,d1,d2,d3,d4, j0,j1,j2,j3,j4, dd, j);
  }
  #pragma unroll
  for (int m = 1; m <= 4; m <<= 1) {
    float e0 = __shfl_xor(d0, m, 8), e1 = __shfl_xor(d1, m, 8),
          e2 = __shfl_xor(d2, m, 8), e3 = __shfl_xor(d3, m, 8),
          e4 = __shfl_xor(d4, m, 8);
    int   k0 = __shfl_xor(j0, m, 8), k1 = __shfl_xor(j1, m, 8),
          k2 = __shfl_xor(j2, m, 8), k3 = __shfl_xor(j3, m, 8),
          k4 = __shfl_xor(j4, m, 8);
    insert5(d0,d1,d2,d3,d4, j0,j1,j2,j3,j4, e0, k0);
    insert5(d0,d1,d2,d3,d4, j0,j1,j2,j3,j4, e1, k1);
    insert5(d0,d1,d2,d3,d4, j0,j1,j2,j3,j4, e2, k2);
    insert5(d0,d1,d2,d3,d4, j0,j1,j2,j3,j4, e3, k3);
    insert5(d0,d1,d2,d3,d4, j0,j1,j2,j3,j4, e4, k4);
  }
  if (ql == 0) {
    const size_t row = (size_t)b * NP + i;
    knn_idx[row*KNN+0] = b*NP + j0;
    knn_idx[row*KNN+1] = b*NP + j1;
    knn_idx[row*KNN+2] = b*NP + j2;
    knn_idx[row*KNN+3] = b*NP + j3;
    knn_idx[row*KNN+4] = b*NP + j4;
  }
}

// ------------------------------------------- EdgeConv1 layer1 (6 -> 64) + stats
__global__ __launch_bounds__(256) void ec1_l1_kernel(const float* __restrict__ pos,
    const int* __restrict__ knn_idx, const float* __restrict__ W,
    const float* __restrict__ bias, float* __restrict__ hout,
    double* __restrict__ psum, double* __restrict__ psq) {
  __shared__ float ef[64][6];
  __shared__ float Wl[6][64];
  __shared__ float bl[64];
  __shared__ double red[256];
  const int blk = blockIdx.x, t = threadIdx.x;
  const int ebase = blk * 64;
  if (t < 64) {
    int e = ebase + t;
    int ip = e / KNN;
    int jp = knn_idx[e];
    float a0 = pos[(size_t)ip*3+0], a1 = pos[(size_t)ip*3+1], a2 = pos[(size_t)ip*3+2];
    float c0 = pos[(size_t)jp*3+0], c1 = pos[(size_t)jp*3+1], c2 = pos[(size_t)jp*3+2];
    ef[t][0] = a0; ef[t][1] = a1; ef[t][2] = a2;
    ef[t][3] = c0 - a0; ef[t][4] = c1 - a1; ef[t][5] = c2 - a2;
    bl[t] = bias[t];
  }
  for (int idx = t; idx < 6*64; idx += 256) Wl[idx>>6][idx&63] = W[idx];
  __syncthreads();
  const int c = t & 63, rs = t >> 6;
  double s = 0.0, ss = 0.0;
  for (int r = rs; r < 64; r += 4) {
    float acc = bl[c];
    #pragma unroll
    for (int q = 0; q < 6; ++q) acc = fmaf(ef[r][q], Wl[q][c], acc);
    acc = fmaxf(acc, 0.0f);
    hout[(size_t)(ebase + r)*64 + c] = acc;
    s += acc; ss += (double)acc * (double)acc;
  }
  red[t] = s; __syncthreads();
  if (t < 64) psum[(size_t)blk*64 + t] = red[t] + red[t+64] + red[t+128] + red[t+192];
  __syncthreads();
  red[t] = ss; __syncthreads();
  if (t < 64) psq[(size_t)blk*64 + t] = red[t] + red[t+64] + red[t+128] + red[t+192];
}

// ------------------- BN stats -> per-channel affine (block per channel)
__global__ __launch_bounds__(256) void stats_reduce_kernel(const double* __restrict__ psum,
    const double* __restrict__ psq, int nblk, int C, double invN,
    const float* __restrict__ g, const float* __restrict__ be,
    float2* __restrict__ aff) {
  __shared__ double rs[256];
  __shared__ double rq[256];
  const int c = blockIdx.x;          // grid = C
  const int t = threadIdx.x;
  double s = 0.0, ss = 0.0;
  for (int i = t; i < nblk; i += 256) {
    s  += psum[(size_t)i*C + c];
    ss += psq [(size_t)i*C + c];
  }
  rs[t] = s; rq[t] = ss; __syncthreads();
  for (int off = 128; off > 0; off >>= 1) {
    if (t < off) { rs[t] += rs[t+off]; rq[t] += rq[t+off]; }
    __syncthreads();
  }
  if (t == 0) {
    double mean = rs[0] * invN;
    double var = rq[0] * invN - mean*mean;
    var = var < 0.0 ? 0.0 : var;
    double inv = 1.0 / sqrt(var + 1e-5);
    float a = (float)((double)g[c] * inv);
    float off2 = (float)((double)be[c] - (double)g[c] * mean * inv);
    aff[c] = make_float2(a, off2);
  }
}

// -------------------------------- EdgeConv1 layers 2/3 (64 -> 64) + stats
__global__ __launch_bounds__(256) void ec_l64_kernel(const float* __restrict__ hin,
    const float2* __restrict__ affprev, const float* __restrict__ W,
    const float* __restrict__ bias, float* __restrict__ hout,
    double* __restrict__ psum, double* __restrict__ psq) {
  __shared__ float ein[64][68];
  __shared__ float Wl[64][64];
  __shared__ float2 affl[64];
  __shared__ float bl[64];
  __shared__ double redS[16][64];
  __shared__ double redQ[16][64];
  const int blk = blockIdx.x, t = threadIdx.x;
  const size_t ebase = (size_t)blk * 64;
  if (t < 64) { affl[t] = affprev[t]; bl[t] = bias[t]; }
  __syncthreads();
  for (int idx = t; idx < 64*64; idx += 256) {
    int r = idx >> 6, c = idx & 63;
    float2 ac = affl[c];
    ein[r][c] = fmaf(hin[ebase*64 + idx], ac.x, ac.y);
    Wl[r][c] = W[idx];
  }
  __syncthreads();
  const int c4 = t & 15, rs = t >> 4;
  const int cbase = c4 * 4;
  const int rbase = rs * 4;
  float acc[4][4];
  #pragma unroll
  for (int ii = 0; ii < 4; ++ii) {
    #pragma unroll
    for (int jj = 0; jj < 4; ++jj) acc[ii][jj] = bl[cbase + jj];
  }
  for (int cin = 0; cin < 64; cin += 4) {
    float4 fi[4];
    #pragma unroll
    for (int ii = 0; ii < 4; ++ii) fi[ii] = *(const float4*)&ein[rbase+ii][cin];
    #pragma unroll
    for (int q = 0; q < 4; ++q) {
      float4 wv = *(const float4*)&Wl[cin+q][cbase];
      #pragma unroll
      for (int ii = 0; ii < 4; ++ii) {
        float f = f4c(fi[ii], q);
        acc[ii][0] = fmaf(f, wv.x, acc[ii][0]);
        acc[ii][1] = fmaf(f, wv.y, acc[ii][1]);
        acc[ii][2] = fmaf(f, wv.z, acc[ii][2]);
        acc[ii][3] = fmaf(f, wv.w, acc[ii][3]);
      }
    }
  }
  double s[4] = {0,0,0,0}, ss[4] = {0,0,0,0};
  #pragma unroll
  for (int ii = 0; ii < 4; ++ii) {
    float4 h;
    h.x = fmaxf(acc[ii][0], 0.f); h.y = fmaxf(acc[ii][1], 0.f);
    h.z = fmaxf(acc[ii][2], 0.f); h.w = fmaxf(acc[ii][3], 0.f);
    *(float4*)&hout[(ebase + rbase + ii)*64 + cbase] = h;
    s[0]+=h.x; s[1]+=h.y; s[2]+=h.z; s[3]+=h.w;
    ss[0]+=(double)h.x*h.x; ss[1]+=(double)h.y*h.y;
    ss[2]+=(double)h.z*h.z; ss[3]+=(double)h.w*h.w;
  }
  #pragma unroll
  for (int jj = 0; jj < 4; ++jj) { redS[rs][cbase+jj] = s[jj]; redQ[rs][cbase+jj] = ss[jj]; }
  __syncthreads();
  if (t < 64) {
    double a = 0, bq = 0;
    #pragma unroll
    for (int r = 0; r < 16; ++r) { a += redS[r][t]; bq += redQ[r][t]; }
    psum[(size_t)blk*64 + t] = a;
    psq[(size_t)blk*64 + t] = bq;
  }
}

// ------------------------------------ max over k with BN affine (monotone)
__global__ void ec1_reduce_kernel(const float* __restrict__ h3,
    const float2* __restrict__ aff, float* __restrict__ x1) {
  int idx = blockIdx.x * 256 + threadIdx.x;
  if (idx >= NPT * 64) return;
  int p = idx >> 6, c = idx & 63;
  float mx = -FINF, mn = FINF;
  #pragma unroll
  for (int kk = 0; kk < KNN; ++kk) {
    float v = h3[((size_t)p*KNN + kk)*64 + c];
    mx = fmaxf(mx, v); mn = fminf(mn, v);
  }
  float2 ac = aff[c];
  x1[idx] = (ac.x >= 0.f) ? fmaf(ac.x, mx, ac.y) : fmaf(ac.x, mn, ac.y);
}

// ----------------------------- |x1|^2 per point (same fmaf order as before)
__global__ void sq_kernel(const float* __restrict__ x1, float* __restrict__ sqg) {
  int p = blockIdx.x * 256 + threadIdx.x;
  if (p >= NPT) return;
  const float* row = &x1[(size_t)p * 64];
  float s = 0.f;
  #pragma unroll
  for (int c = 0; c < 64; ++c) s = fmaf(row[c], row[c], s);
  sqg[p] = s;
}

// ---------------------------------------------------------------- knn (64-d)
__global__ __launch_bounds__(256) void knn2_kernel(const float* __restrict__ x1,
    const float* __restrict__ sqg, float* __restrict__ kpd, int* __restrict__ kpj) {
  __shared__ float xi[64][68];
  __shared__ float xjd[64][68];   // xj tile, then reused as distance tile
  const int b = blockIdx.x >> 5;
  const int it = (blockIdx.x >> 1) & 15;
  const int half = blockIdx.x & 1;
  const int t = threadIdx.x;
  const int ibase = it * 64;  // within batch

  {
    int r = t >> 4, c4 = (t & 15) * 4;
    #pragma unroll
    for (int rr = 0; rr < 4; ++rr) {
      float4 v = *(const float4*)&x1[((size_t)b*NP + ibase + r + 16*rr)*64 + c4];
      *(float4*)&xi[r + 16*rr][c4] = v;
    }
  }

  const int il = t >> 4, jl = t & 15;      // GEMM mapping
  const int row = t >> 2, ql = t & 3;      // selection mapping
  float si[4];
  #pragma unroll
  for (int ii = 0; ii < 4; ++ii) si[ii] = sqg[(size_t)b*NP + ibase + il*4 + ii];

  float d0=FINF,d1=FINF,d2=FINF,d3=FINF,d4=FINF;
  int j0=0x7fffffff,j1=0x7fffffff,j2=0x7fffffff,j3=0x7fffffff,j4=0x7fffffff;

  for (int jt = 0; jt < 8; ++jt) {
    const int jtg = half * 8 + jt;
    __syncthreads();   // xi staged (first iter) / previous selection done
    {
      int r = t >> 4, c4 = (t & 15) * 4;
      #pragma unroll
      for (int rr = 0; rr < 4; ++rr) {
        float4 v = *(const float4*)&x1[((size_t)b*NP + jtg*64 + r + 16*rr)*64 + c4];
        *(float4*)&xjd[r + 16*rr][c4] = v;
      }
    }
    __syncthreads();
    float acc[4][4];
    #pragma unroll
    for (int ii = 0; ii < 4; ++ii) {
      #pragma unroll
      for (int jj = 0; jj < 4; ++jj) acc[ii][jj] = 0.f;
    }
    for (int cin = 0; cin < 64; cin += 4) {
      float4 fi[4], fj[4];
      #pragma unroll
      for (int ii = 0; ii < 4; ++ii) fi[ii] = *(const float4*)&xi[il*4+ii][cin];
      #pragma unroll
      for (int jj = 0; jj < 4; ++jj) fj[jj] = *(const float4*)&xjd[jl + 16*jj][cin];
      #pragma unroll
      for (int q = 0; q < 4; ++q) {
        #pragma unroll
        for (int ii = 0; ii < 4; ++ii) {
          float f = f4c(fi[ii], q);
          acc[ii][0] = fmaf(f, f4c(fj[0],q), acc[ii][0]);
          acc[ii][1] = fmaf(f, f4c(fj[1],q), acc[ii][1]);
          acc[ii][2] = fmaf(f, f4c(fj[2],q), acc[ii][2]);
          acc[ii][3] = fmaf(f, f4c(fj[3],q), acc[ii][3]);
        }
      }
    }
    float sjv[4];
    #pragma unroll
    for (int jj = 0; jj < 4; ++jj) sjv[jj] = sqg[(size_t)b*NP + jtg*64 + jl + 16*jj];
    __syncthreads();    // everyone done reading xjd as features
    #pragma unroll
    for (int ii = 0; ii < 4; ++ii) {
      #pragma unroll
      for (int jj = 0; jj < 4; ++jj) {
        xjd[il*4+ii][jl + 16*jj] = fmaf(-2.f, acc[ii][jj], si[ii] + sjv[jj]);
      }
    }
    __syncthreads();
    const int jgbase = jtg*64 + ql*16;
    #pragma unroll
    for (int kk = 0; kk < 4; ++kk) {
      float4 v = *(const float4*)&xjd[row][ql*16 + 4*kk];
      insert5(d0,d1,d2,d3,d4, j0,j1,j2,j3,j4, v.x, jgbase + 4*kk + 0);
      insert5(d0,d1,d2,d3,d4, j0,j1,j2,j3,j4, v.y, jgbase + 4*kk + 1);
      insert5(d0,d1,d2,d3,d4, j0,j1,j2,j3,j4, v.z, jgbase + 4*kk + 2);
      insert5(d0,d1,d2,d3,d4, j0,j1,j2,j3,j4, v.w, jgbase + 4*kk + 3);
    }
  }

  #pragma unroll
  for (int m = 1; m <= 2; m <<= 1) {
    float e0 = __shfl_xor(d0, m, 4), e1 = __shfl_xor(d1, m, 4),
          e2 = __shfl_xor(d2, m, 4), e3 = __shfl_xor(d3, m, 4),
          e4 = __shfl_xor(d4, m, 4);
    int   k0 = __shfl_xor(j0, m, 4), k1 = __shfl_xor(j1, m, 4),
          k2 = __shfl_xor(j2, m, 4), k3 = __shfl_xor(j3, m, 4),
          k4 = __shfl_xor(j4, m, 4);
    insert5(d0,d1,d2,d3,d4, j0,j1,j2,j3,j4, e0, k0);
    insert5(d0,d1,d2,d3,d4, j0,j1,j2,j3,j4, e1, k1);
    insert5(d0,d1,d2,d3,d4, j0,j1,j2,j3,j4, e2, k2);
    insert5(d0,d1,d2,d3,d4, j0,j1,j2,j3,j4, e3, k3);
    insert5(d0,d1,d2,d3,d4, j0,j1,j2,j3,j4, e4, k4);
  }
  if (ql == 0) {
    const size_t orow = ((size_t)half*NPT + (size_t)b*NP + ibase + row) * KNN;
    kpd[orow+0] = d0; kpd[orow+1] = d1; kpd[orow+2] = d2; kpd[orow+3] = d3; kpd[orow+4] = d4;
    kpj[orow+0] = j0; kpj[orow+1] = j1; kpj[orow+2] = j2; kpj[orow+3] = j3; kpj[orow+4] = j4;
  }
}

// merge the two sorted half top-5 lists (exact: half0 j < half1 j)
__global__ void knn2_merge_kernel(const float* __restrict__ kpd,
    const int* __restrict__ kpj, int* __restrict__ knn_idx) {
  int r = blockIdx.x * 256 + threadIdx.x;
  if (r >= NPT) return;
  const int b = r >> 10;
  const size_t r0 = (size_t)r * KNN;
  const size_t r1 = ((size_t)NPT + r) * KNN;
  float d0 = kpd[r0+0], d1 = kpd[r0+1], d2 = kpd[r0+2], d3 = kpd[r0+3], d4 = kpd[r0+4];
  int   j0 = kpj[r0+0], j1 = kpj[r0+1], j2 = kpj[r0+2], j3 = kpj[r0+3], j4 = kpj[r0+4];
  #pragma unroll
  for (int s = 0; s < KNN; ++s) {
    insert5(d0,d1,d2,d3,d4, j0,j1,j2,j3,j4, kpd[r1+s], kpj[r1+s]);
  }
  knn_idx[r0+0] = b*NP + j0;
  knn_idx[r0+1] = b*NP + j1;
  knn_idx[r0+2] = b*NP + j2;
  knn_idx[r0+3] = b*NP + j3;
  knn_idx[r0+4] = b*NP + j4;
}

// --------------- EdgeConv2 (128 -> 128) fp32, 2 points/thread (R9)
// 16 points/block, 80 edge rows in LDS; stats scratch aliases e2 after GEMM.
__global__ __launch_bounds__(256) void ec2_kernel(const float* __restrict__ x1,
    const int* __restrict__ knn_idx, const float* __restrict__ W,
    const float* __restrict__ bias, float* __restrict__ x2max,
    float* __restrict__ x2min, double* __restrict__ psum, double* __restrict__ psq) {
  __shared__ __align__(16) char smem[80 * 128 * 4];   // 40 KB
  float (*e2)[128] = (float (*)[128])smem;
  const int blk = blockIdx.x, t = threadIdx.x;   // grid = NPT/16
  const int pbase = blk * 16;
  for (int idx = t; idx < 80*128; idx += 256) {
    int r = idx >> 7, c = idx & 127;
    int p = pbase + r / KNN;
    int kk = r % KNN;
    int j = knn_idx[(size_t)p*KNN + kk];
    float v;
    if (c < 64) v = x1[(size_t)p*64 + c];
    else {
      int cc = c - 64;
      v = x1[(size_t)j*64 + cc] - x1[(size_t)p*64 + cc];
    }
    e2[r][c] = v;
  }
  __syncthreads();
  const int c4 = t & 31, pg = t >> 5;     // 8 point-groups x 2 points
  const int cbase = c4 * 4;
  const int r0 = pg * 10;                 // rows r0..r0+9 (2 points x 5 edges)
  float4 bv = *(const float4*)&bias[cbase];
  float acc[2][5][4];
  #pragma unroll
  for (int pt = 0; pt < 2; ++pt) {
    #pragma unroll
    for (int kk = 0; kk < 5; ++kk) {
      acc[pt][kk][0]=bv.x; acc[pt][kk][1]=bv.y; acc[pt][kk][2]=bv.z; acc[pt][kk][3]=bv.w;
    }
  }
  for (int cin = 0; cin < 128; cin += 4) {
    float4 wv0 = *(const float4*)&W[(size_t)(cin+0)*128 + cbase];
    float4 wv1 = *(const float4*)&W[(size_t)(cin+1)*128 + cbase];
    float4 wv2 = *(const float4*)&W[(size_t)(cin+2)*128 + cbase];
    float4 wv3 = *(const float4*)&W[(size_t)(cin+3)*128 + cbase];
    #pragma unroll
    for (int pt = 0; pt < 2; ++pt) {
      #pragma unroll
      for (int kk = 0; kk < 5; ++kk) {
        float4 f = *(const float4*)&e2[r0 + pt*5 + kk][cin];
        acc[pt][kk][0] = fmaf(f.x, wv0.x, acc[pt][kk][0]);
        acc[pt][kk][1] = fmaf(f.x, wv0.y, acc[pt][kk][1]);
        acc[pt][kk][2] = fmaf(f.x, wv0.z, acc[pt][kk][2]);
        acc[pt][kk][3] = fmaf(f.x, wv0.w, acc[pt][kk][3]);
        acc[pt][kk][0] = fmaf(f.y, wv1.x, acc[pt][kk][0]);
        acc[pt][kk][1] = fmaf(f.y, wv1.y, acc[pt][kk][1]);
        acc[pt][kk][2] = fmaf(f.y, wv1.z, acc[pt][kk][2]);
        acc[pt][kk][3] = fmaf(f.y, wv1.w, acc[pt][kk][3]);
        acc[pt][kk][0] = fmaf(f.z, wv2.x, acc[pt][kk][0]);
        acc[pt][kk][1] = fmaf(f.z, wv2.y, acc[pt][kk][1]);
        acc[pt][kk][2] = fmaf(f.z, wv2.z, acc[pt][kk][2]);
        acc[pt][kk][3] = fmaf(f.z, wv2.w, acc[pt][kk][3]);
        acc[pt][kk][0] = fmaf(f.w, wv3.x, acc[pt][kk][0]);
        acc[pt][kk][1] = fmaf(f.w, wv3.y, acc[pt][kk][1]);
        acc[pt][kk][2] = fmaf(f.w, wv3.z, acc[pt][kk][2]);
        acc[pt][kk][3] = fmaf(f.w, wv3.w, acc[pt][kk][3]);
      }
    }
  }
  __syncthreads();   // all e2 reads done; alias stats scratch onto smem
  double (*redS)[128] = (double (*)[128])smem;              // 8 KB
  double (*redQ)[128] = (double (*)[128])(smem + 8*128*8);  // 8 KB
  double s[4] = {0,0,0,0}, ss[4] = {0,0,0,0};
  #pragma unroll
  for (int pt = 0; pt < 2; ++pt) {
    float mx[4] = {-FINF,-FINF,-FINF,-FINF}, mn[4] = {FINF,FINF,FINF,FINF};
    #pragma unroll
    for (int kk = 0; kk < 5; ++kk) {
      #pragma unroll
      for (int jj = 0; jj < 4; ++jj) {
        float h = fmaxf(acc[pt][kk][jj], 0.f);
        mx[jj] = fmaxf(mx[jj], h); mn[jj] = fminf(mn[jj], h);
        s[jj] += h; ss[jj] += (double)h * h;
      }
    }
    *(float4*)&x2max[((size_t)pbase + pg*2 + pt)*128 + cbase] = make_float4(mx[0],mx[1],mx[2],mx[3]);
    *(float4*)&x2min[((size_t)pbase + pg*2 + pt)*128 + cbase] = make_float4(mn[0],mn[1],mn[2],mn[3]);
  }
  #pragma unroll
  for (int jj = 0; jj < 4; ++jj) { redS[pg][cbase+jj] = s[jj]; redQ[pg][cbase+jj] = ss[jj]; }
  __syncthreads();
  if (t < 128) {
    double a = 0, q2 = 0;
    #pragma unroll
    for (int r = 0; r < 8; ++r) { a += redS[r][t]; q2 += redQ[r][t]; }
    psum[(size_t)blk*128 + t] = a;
    psq[(size_t)blk*128 + t] = q2;
  }
}

__global__ void ec2_fin_kernel(const float* __restrict__ x2max,
    const float* __restrict__ x2min, const float2* __restrict__ aff,
    float* __restrict__ x2) {
  int idx = blockIdx.x*256 + threadIdx.x;
  if (idx >= NPT*128) return;
  int c = idx & 127;
  float2 ac = aff[c];
  x2[idx] = (ac.x >= 0.f) ? fmaf(ac.x, x2max[idx], ac.y) : fmaf(ac.x, x2min[idx], ac.y);
}

// ------------------- W[192][1024] f32 -> Wt[1024][192] bf16 (lin1 B-frags)
__global__ __launch_bounds__(256) void wt_kernel(const float* __restrict__ W,
                                                 ushort* __restrict__ Wt) {
  __shared__ ushort ls[64][192];
  const int cbase = blockIdx.x * 64;   // grid = 16
  const int t = threadIdx.x;
  for (int idx = t; idx < 192 * 64; idx += 256) {
    int cc = idx & 63, k = idx >> 6;
    ls[cc][k] = f2bf(W[(size_t)k * 1024 + cbase + cc]);
  }
  __syncthreads();
  const int c = t >> 2, part = (t & 3) * 48;
  #pragma unroll
  for (int i = 0; i < 6; ++i) {
    *(bf16x8*)&Wt[(size_t)(cbase + c) * 192 + part + i * 8] =
        *(const bf16x8*)&ls[c][part + i * 8];
  }
}

// ------------- Lin1 (192 -> 1024) bf16 MFMA, fused ReLU + stats + max/min
__global__ __launch_bounds__(256) void lin1_kernel(const float* __restrict__ x1,
    const float* __restrict__ x2, const ushort* __restrict__ Wt,
    const float* __restrict__ bias, double* __restrict__ psum,
    double* __restrict__ psq, float* __restrict__ pmax, float* __restrict__ pmin) {
  __shared__ ushort As[32 * 208];   // 32 rows x 192 bf16, stride 208
  const int blk = blockIdx.x, t = threadIdx.x;
  const int pbase = blk * 32;
  for (int idx = t; idx < 32 * 192; idx += 256) {
    int r = idx / 192, c = idx - r * 192;
    int p = pbase + r;
    float v = (c < 64) ? x1[(size_t)p * 64 + c] : x2[(size_t)p * 128 + (c - 64)];
    As[r * 208 + c] = f2bf(v);
  }
  __syncthreads();
  const int l = t & 63, w = t >> 6;
  const int lr = l & 15, lg = l >> 4;
  const int cbase = w * 256;
  f32x4 acc0[16], acc1[16];
  #pragma unroll
  for (int ct = 0; ct < 16; ++ct) {
    acc0[ct] = (f32x4){0.f, 0.f, 0.f, 0.f};
    acc1[ct] = (f32x4){0.f, 0.f, 0.f, 0.f};
  }
  #pragma unroll
  for (int ks = 0; ks < 6; ++ks) {
    const int k0 = ks * 32;
    bf16x8 a0 = *(const bf16x8*)&As[lr * 208 + k0 + lg * 8];
    bf16x8 a1 = *(const bf16x8*)&As[(16 + lr) * 208 + k0 + lg * 8];
    #pragma unroll
    for (int ct = 0; ct < 16; ++ct) {
      bf16x8 bv = *(const bf16x8*)&Wt[(size_t)(cbase + ct * 16 + lr) * 192 + k0 + lg * 8];
      acc0[ct] = __builtin_amdgcn_mfma_f32_16x16x32_bf16(a0, bv, acc0[ct], 0, 0, 0);
      acc1[ct] = __builtin_amdgcn_mfma_f32_16x16x32_bf16(a1, bv, acc1[ct], 0, 0, 0);
    }
  }
  #pragma unroll
  for (int ct = 0; ct < 16; ++ct) {
    const int c = cbase + ct * 16 + lr;
    const float bv = bias[c];
    double s = 0.0, ss = 0.0;
    float mx = -FINF, mn = FINF;
    #pragma unroll
    for (int i = 0; i < 4; ++i) {
      float h0 = fmaxf(acc0[ct][i] + bv, 0.f);
      float h1 = fmaxf(acc1[ct][i] + bv, 0.f);
      s += (double)h0 + (double)h1;
      ss += (double)h0 * h0 + (double)h1 * h1;
      mx = fmaxf(mx, fmaxf(h0, h1));
      mn = fminf(mn, fminf(h0, h1));
    }
    s  += __shfl_xor(s, 16);  ss += __shfl_xor(ss, 16);
    mx = fmaxf(mx, __shfl_xor(mx, 16)); mn = fminf(mn, __shfl_xor(mn, 16));
    s  += __shfl_xor(s, 32);  ss += __shfl_xor(ss, 32);
    mx = fmaxf(mx, __shfl_xor(mx, 32)); mn = fminf(mn, __shfl_xor(mn, 32));
    if (lg == 0) {
      psum[(size_t)blk * 1024 + c] = s;
      psq [(size_t)blk * 1024 + c] = ss;
      pmax[(size_t)blk * 1024 + c] = mx;
      pmin[(size_t)blk * 1024 + c] = mn;
    }
  }
}

// ----------------- lin1 BN+maxpool finalize (block per channel; 1024 partials)
__global__ __launch_bounds__(256) void lin1_fin_kernel(const double* __restrict__ psum,
    const double* __restrict__ psq, const float* __restrict__ pmax,
    const float* __restrict__ pmin, const float* __restrict__ g,
    const float* __restrict__ be, float* __restrict__ y) {
  __shared__ double rs[256];
  __shared__ double rq[256];
  __shared__ float smx[32][8];
  __shared__ float smn[32][8];
  __shared__ float sa[2];
  const int c = blockIdx.x;          // grid = 1024
  const int t = threadIdx.x;
  double s = 0.0, ss = 0.0;
  for (int i = t; i < 1024; i += 256) {
    s  += psum[(size_t)i*1024 + c];
    ss += psq [(size_t)i*1024 + c];
  }
  rs[t] = s; rq[t] = ss; __syncthreads();
  for (int off = 128; off > 0; off >>= 1) {
    if (t < off) { rs[t] += rs[t+off]; rq[t] += rq[t+off]; }
    __syncthreads();
  }
  if (t == 0) {
    double mean = rs[0] / 32768.0;
    double var = rq[0] / 32768.0 - mean*mean;
    var = var < 0.0 ? 0.0 : var;
    double inv = 1.0 / sqrt(var + 1e-5);
    sa[0] = (float)((double)g[c] * inv);
    sa[1] = (float)((double)be[c] - (double)g[c]*mean*inv);
  }
  {
    int b = t >> 3, q = t & 7;
    float mxv = -FINF, mnv = FINF;
    #pragma unroll
    for (int k = 0; k < 4; ++k) {
      int i = b*32 + q*4 + k;
      mxv = fmaxf(mxv, pmax[(size_t)i*1024 + c]);
      mnv = fminf(mnv, pmin[(size_t)i*1024 + c]);
    }
    smx[b][q] = mxv;
    smn[b][q] = mnv;
  }
  __syncthreads();
  if (t < 32) {
    float mxv = -FINF, mnv = FINF;
    #pragma unroll
    for (int q = 0; q < 8; ++q) { mxv = fmaxf(mxv, smx[t][q]); mnv = fminf(mnv, smn[t][q]); }
    float a = sa[0], off2 = sa[1];
    y[(size_t)t*1024 + c] = (a >= 0.f) ? fmaf(a, mxv, off2) : fmaf(a, mnv, off2);
  }
}

// ---------------------------------------------------------------- head MLP
__global__ __launch_bounds__(256) void head1_kernel(const float* __restrict__ y,
    const float* __restrict__ W, const float* __restrict__ bias, float* __restrict__ h5) {
  __shared__ float yr[1024];
  __shared__ float part[256];
  const int r = blockIdx.x >> 2;
  const int cseg = (blockIdx.x & 3) * 128;
  const int t = threadIdx.x;
  for (int i = t; i < 1024; i += 256) yr[i] = y[(size_t)r*1024 + i];
  __syncthreads();
  const int c = cseg + (t & 127);
  const int kh = t >> 7;
  const int kbase = kh * 512;
  float a0 = 0.f, a1 = 0.f, a2 = 0.f, a3 = 0.f;
  for (int cin = 0; cin < 512; cin += 4) {
    a0 = fmaf(yr[kbase+cin+0], W[(size_t)(kbase+cin+0)*512 + c], a0);
    a1 = fmaf(yr[kbase+cin+1], W[(size_t)(kbase+cin+1)*512 + c], a1);
    a2 = fmaf(yr[kbase+cin+2], W[(size_t)(kbase+cin+2)*512 + c], a2);
    a3 = fmaf(yr[kbase+cin+3], W[(size_t)(kbase+cin+3)*512 + c], a3);
  }
  part[t] = ((a0 + a1) + (a2 + a3));
  __syncthreads();
  if (t < 128) {
    float acc = bias[c] + part[t] + part[t + 128];
    h5[(size_t)r*512 + c] = fmaxf(acc, 0.f);
  }
}

__global__ void bn_rows_kernel(const float* __restrict__ h, int C, int R,
    const float* __restrict__ g, const float* __restrict__ be, float2* __restrict__ aff) {
  int c = blockIdx.x*256 + threadIdx.x;
  if (c >= C) return;
  double s = 0, ss = 0;
  for (int r = 0; r < R; ++r) {
    double v = (double)h[(size_t)r*C + c];
    s += v; ss += v*v;
  }
  double mean = s / (double)R;
  double var = ss / (double)R - mean*mean;
  var = var < 0.0 ? 0.0 : var;
  double inv = 1.0 / sqrt(var + 1e-5);
  float a = (float)((double)g[c] * inv);
  float off = (float)((double)be[c] - (double)g[c]*mean*inv);
  aff[c] = make_float2(a, off);
}

__global__ __launch_bounds__(256) void head2_kernel(const float* __restrict__ h5,
    const float2* __restrict__ aff, const float* __restrict__ W,
    const float* __restrict__ bias, float* __restrict__ h6) {
  __shared__ float hr[512];
  const int r = blockIdx.x;            // grid = 32
  const int t = threadIdx.x;
  for (int i = t; i < 512; i += 256) {
    float2 a = aff[i];
    hr[i] = fmaf(a.x, h5[(size_t)r*512 + i], a.y);
  }
  __syncthreads();
  const int c = t;
  float a0 = 0.f, a1 = 0.f, a2 = 0.f, a3 = 0.f;
  for (int cin = 0; cin < 512; cin += 4) {
    a0 = fmaf(hr[cin+0], W[(size_t)(cin+0)*256 + c], a0);
    a1 = fmaf(hr[cin+1], W[(size_t)(cin+1)*256 + c], a1);
    a2 = fmaf(hr[cin+2], W[(size_t)(cin+2)*256 + c], a2);
    a3 = fmaf(hr[cin+3], W[(size_t)(cin+3)*256 + c], a3);
  }
  float acc = bias[c] + ((a0 + a1) + (a2 + a3));
  h6[(size_t)r*256 + c] = fmaxf(acc, 0.f);
}

__global__ void head3_kernel(const float* __restrict__ h6, const float2* __restrict__ aff,
    const float* __restrict__ W, const float* __restrict__ bias, float* __restrict__ out) {
  int t = threadIdx.x;
  if (t >= 64) return;
  int r = t >> 1, c = t & 1;
  float acc = bias[c];
  for (int cin = 0; cin < 256; ++cin) {
    float2 a = aff[cin];
    acc = fmaf(fmaf(a.x, h6[(size_t)r*256 + cin], a.y), W[(size_t)cin*2 + c], acc);
  }
  out[(size_t)r*2 + c] = acc;
}

// ------------------------------------------------------------------ launcher
extern "C" void kernel_launch(void* const* d_in, const int* in_sizes, int n_in,
                              void* d_out, int out_size, void* d_ws, size_t ws_size,
                              hipStream_t stream) {
  (void)in_sizes; (void)n_in; (void)out_size; (void)ws_size;
  const float* pos    = (const float*)d_in[0];
  const float* c1_w1  = (const float*)d_in[2];
  const float* c1_b1  = (const float*)d_in[3];
  const float* c1_g1  = (const float*)d_in[4];
  const float* c1_be1 = (const float*)d_in[5];
  const float* c1_w2  = (const float*)d_in[6];
  const float* c1_b2  = (const float*)d_in[7];
  const float* c1_g2  = (const float*)d_in[8];
  const float* c1_be2 = (const float*)d_in[9];
  const float* c1_w3  = (const float*)d_in[10];
  const float* c1_b3  = (const float*)d_in[11];
  const float* c1_g3  = (const float*)d_in[12];
  const float* c1_be3 = (const float*)d_in[13];
  const float* c2_w1  = (const float*)d_in[14];
  const float* c2_b1  = (const float*)d_in[15];
  const float* c2_g1  = (const float*)d_in[16];
  const float* c2_be1 = (const float*)d_in[17];
  const float* l1_w   = (const float*)d_in[18];
  const float* l1_b   = (const float*)d_in[19];
  const float* l1_g   = (const float*)d_in[20];
  const float* l1_be  = (const float*)d_in[21];
  const float* m1_w   = (const float*)d_in[22];
  const float* m1_b   = (const float*)d_in[23];
  const float* m1_g   = (const float*)d_in[24];
  const float* m1_be  = (const float*)d_in[25];
  const float* m2_w   = (const float*)d_in[26];
  const float* m2_b   = (const float*)d_in[27];
  const float* m2_g   = (const float*)d_in[28];
  const float* m2_be  = (const float*)d_in[29];
  const float* m3_w   = (const float*)d_in[30];
  const float* m3_b   = (const float*)d_in[31];

  char* ws = (char*)d_ws;
  size_t off = 0;
  auto alloc = [&](size_t bytes) -> void* {
    void* p = ws + off;
    off += (bytes + 255) & ~(size_t)255;
    return p;
  };
  int*    idx1 = (int*)alloc((size_t)NE * 4);
  int*    idx2 = (int*)alloc((size_t)NE * 4);
  float*  x1   = (float*)alloc((size_t)NPT * 64 * 4);
  float*  x2   = (float*)alloc((size_t)NPT * 128 * 4);
  float*  hA   = (float*)alloc((size_t)NE * 64 * 4);
  float*  hB   = (float*)alloc((size_t)NE * 64 * 4);
  double* psum = (double*)alloc((size_t)1048576 * 8);
  double* psq  = (double*)alloc((size_t)1048576 * 8);
  float*  pmax = (float*)alloc((size_t)1048576 * 4);
  float*  pmin = (float*)alloc((size_t)1048576 * 4);
  float2* affA = (float2*)alloc(64 * 8);
  float2* affB = (float2*)alloc(64 * 8);
  float2* affC = (float2*)alloc(64 * 8);
  float2* aff2 = (float2*)alloc(128 * 8);
  float2* affM1 = (float2*)alloc(512 * 8);
  float2* affM2 = (float2*)alloc(256 * 8);
  float*  y    = (float*)alloc((size_t)NB * 1024 * 4);
  float*  h5   = (float*)alloc((size_t)NB * 512 * 4);
  float*  h6   = (float*)alloc((size_t)NB * 256 * 4);
  ushort* Wt   = (ushort*)alloc((size_t)1024 * 192 * 2);
  float*  sqg  = (float*)alloc((size_t)NPT * 4);
  float*  kpd  = (float*)alloc((size_t)2 * NPT * KNN * 4);
  int*    kpj  = (int*)alloc((size_t)2 * NPT * KNN * 4);
  float* x2max = hA;
  float* x2min = hA + (size_t)NPT * 128;

  // 0. weight conversion (lin1 only)
  wt_kernel<<<dim3(16), dim3(256), 0, stream>>>(l1_w, Wt);
  // 1. knn on positions
  knn1_kernel<<<dim3(NB*32), dim3(256), 0, stream>>>(pos, idx1);
  // 2. EdgeConv1 layer1
  ec1_l1_kernel<<<dim3(NE/64), dim3(256), 0, stream>>>(pos, idx1, c1_w1, c1_b1, hA, psum, psq);
  stats_reduce_kernel<<<dim3(64), dim3(256), 0, stream>>>(psum, psq, NE/64, 64, 1.0/NE, c1_g1, c1_be1, affA);
  // 3. layer2
  ec_l64_kernel<<<dim3(NE/64), dim3(256), 0, stream>>>(hA, affA, c1_w2, c1_b2, hB, psum, psq);
  stats_reduce_kernel<<<dim3(64), dim3(256), 0, stream>>>(psum, psq, NE/64, 64, 1.0/NE, c1_g2, c1_be2, affB);
  // 4. layer3
  ec_l64_kernel<<<dim3(NE/64), dim3(256), 0, stream>>>(hB, affB, c1_w3, c1_b3, hA, psum, psq);
  stats_reduce_kernel<<<dim3(64), dim3(256), 0, stream>>>(psum, psq, NE/64, 64, 1.0/NE, c1_g3, c1_be3, affC);
  // 5. max over k -> x1
  ec1_reduce_kernel<<<dim3(NPT*64/256), dim3(256), 0, stream>>>(hA, affC, x1);
  // 6. knn on features (sq precompute + j-split + exact merge)
  sq_kernel<<<dim3(NPT/256), dim3(256), 0, stream>>>(x1, sqg);
  knn2_kernel<<<dim3(NB*32), dim3(256), 0, stream>>>(x1, sqg, kpd, kpj);
  knn2_merge_kernel<<<dim3(NPT/256), dim3(256), 0, stream>>>(kpd, kpj, idx2);
  // 7. EdgeConv2 fp32, 2 pts/thread (R9; fused k-max/min)
  ec2_kernel<<<dim3(NPT/16), dim3(256), 0, stream>>>(x1, idx2, c2_w1, c2_b1, x2max, x2min, psum, psq);
  stats_reduce_kernel<<<dim3(128), dim3(256), 0, stream>>>(psum, psq, NPT/16, 128, 1.0/NE, c2_g1, c2_be1, aff2);
  ec2_fin_kernel<<<dim3(NPT*128/256), dim3(256), 0, stream>>>(x2max, x2min, aff2, x2);
  // 8. Lin1 bf16-MFMA fused
  lin1_kernel<<<dim3(NPT/32), dim3(256), 0, stream>>>(x1, x2, Wt, l1_b, psum, psq, pmax, pmin);
  lin1_fin_kernel<<<dim3(1024), dim3(256), 0, stream>>>(psum, psq, pmax, pmin, l1_g, l1_be, y);
  // 9. head
  head1_kernel<<<dim3(128), dim3(256), 0, stream>>>(y, m1_w, m1_b, h5);
  bn_rows_kernel<<<dim3(2), dim3(256), 0, stream>>>(h5, 512, NB, m1_g, m1_be, affM1);
  head2_kernel<<<dim3(32), dim3(256), 0, stream>>>(h5, affM1, m2_w, m2_b, h6);
  bn_rows_kernel<<<dim3(1), dim3(256), 0, stream>>>(h6, 256, NB, m2_g, m2_be, affM2);
  head3_kernel<<<dim3(1), dim3(64), 0, stream>>>(h6, affM2, m3_w, m3_b, (float*)d_out);
}